// Round 10
// baseline (981.978 us; speedup 1.0000x reference)
//
#include <hip/hip_runtime.h>

#define NN 50000
#define NE 200000
#define DD 128
#define GG 256
#define NITERS 2
#define NBINS 50176          // 196 * 256, >= NN
#define NPART 196

typedef unsigned short u16;
typedef unsigned int u32;
typedef __bf16 bf16x8 __attribute__((ext_vector_type(8)));
typedef float f32x4 __attribute__((ext_vector_type(4)));

union U16x8 { uint4 u; bf16x8 v; u16 s[8]; };

__device__ __forceinline__ u16 f2b(float f) {             // f32 -> bf16 bits, RNE
    u32 u = __float_as_uint(f);
    return (u16)((u + 0x7FFFu + ((u >> 16) & 1u)) >> 16);
}
__device__ __forceinline__ float b2f(u16 s) { return __uint_as_float(((u32)s) << 16); }

__device__ __forceinline__ uint2 pack4(const float* v) {
    uint2 r;
    r.x = (u32)f2b(v[0]) | ((u32)f2b(v[1]) << 16);
    r.y = (u32)f2b(v[2]) | ((u32)f2b(v[3]) << 16);
    return r;
}

// async global -> LDS, 16B per lane; lds must be the wave-uniform base slot
__device__ __forceinline__ void gload_lds16(const void* g, void* lds) {
    __builtin_amdgcn_global_load_lds((const __attribute__((address_space(1))) void*)g,
                                     (__attribute__((address_space(3))) void*)lds, 16, 0, 0);
}

// XCD-chunked bijective block swizzle (m204 form)
__device__ __forceinline__ int xcd_swz(int orig, int nwg) {
    int q = nwg >> 3, r = nwg & 7;
    int x = orig & 7, loc = orig >> 3;
    return (x < r ? x * (q + 1) : r * (q + 1) + (x - r) * q) + loc;
}

// ---------------------------------------------------------------------------
// expand_k: OUT[128 rows][cols c*128..] = epi(A[128][K] @ W + bias), c = blockIdx.y
// A staged ONCE in LDS; W fragments per-lane direct global loads; swapped
// MFMA operands -> each thread owns 4 consecutive out-cols of one row.
// EPI: 0 = bf16 store (ob, ldN=LDN); 1 = f32 of + bf16 ob (LDN=128);
//      2 = residual: of += , ob mirror (LDN=128).
// zf: optional f32 [M][128] buffer to zero-fill (block zeroes its
//     128-row x 32-col slice) -- folds the fi/fo memset into the P-pass.
// ---------------------------------------------------------------------------
template<int K, int NL, int EPI, bool RELU, int LDN>
__global__ __launch_bounds__(256) void expand_k(
    const u16* __restrict__ A, const uint4* __restrict__ wfrag,
    const float* __restrict__ bias, float* __restrict__ of, u16* __restrict__ ob,
    float* __restrict__ zf, int M)
{
    constexpr int KS = K / 32;
    __shared__ uint4 smem[K * 16];
    const int t = threadIdx.x, l = t & 63, wv = t >> 6;
    const int mh = wv >> 1, nh = wv & 1;
    const int mblk = blockIdx.x;
    const int c = blockIdx.y;

    #pragma unroll
    for (int i = 0; i < K / 16; ++i) {           // stage A once
        int s = t + 256 * i;
        int ln = s & 63, mt = (s >> 6) & 7, ksl = s >> 9;
        int row = mblk * 128 + mt * 16 + (ln & 15);
        if (row >= M) row = M - 1;
        int kk = ksl * 32 + (ln >> 4) * 8;
        gload_lds16(A + (size_t)row * K + kk, &smem[s - ln]);
    }
    if (zf) {                                    // zero-fill slice (overlaps staging)
        #pragma unroll
        for (int i = 0; i < 4; ++i) {
            int f = t + 256 * i;                 // float4 idx in [0,1024)
            int row = f >> 3, c4 = f & 7;
            int grow = mblk * 128 + row;
            if (grow < M) {
                float4 z; z.x = 0.f; z.y = 0.f; z.z = 0.f; z.w = 0.f;
                *(float4*)(zf + (size_t)grow * 128 + c * 32 + c4 * 4) = z;
            }
        }
    }
    __syncthreads();

    f32x4 acc[4][4] = {};
    #pragma unroll
    for (int ksl = 0; ksl < KS; ++ksl) {
        uint4 wa[4];
        #pragma unroll
        for (int mi = 0; mi < 4; ++mi)
            wa[mi] = wfrag[(size_t)((c * KS + ksl) * 8 + mh * 4 + mi) * 64 + l];
        bf16x8 bn[4];
        #pragma unroll
        for (int ni = 0; ni < 4; ++ni) { U16x8 u; u.u = smem[(ksl * 8 + nh * 4 + ni) * 64 + l]; bn[ni] = u.v; }
        #pragma unroll
        for (int mi = 0; mi < 4; ++mi) {
            U16x8 u; u.u = wa[mi];
            #pragma unroll
            for (int ni = 0; ni < 4; ++ni)
                acc[mi][ni] = __builtin_amdgcn_mfma_f32_16x16x32_bf16(u.v, bn[ni], acc[mi][ni], 0, 0, 0);
        }
    }
    float4 bb[4];
    #pragma unroll
    for (int mi = 0; mi < 4; ++mi) {
        if (bias) bb[mi] = *(const float4*)(bias + c * 128 + mh * 64 + mi * 16 + 4 * (l >> 4));
        else { bb[mi].x = 0.f; bb[mi].y = 0.f; bb[mi].z = 0.f; bb[mi].w = 0.f; }
    }
    #pragma unroll
    for (int ni = 0; ni < 4; ++ni) {
        int node = mblk * 128 + nh * 64 + ni * 16 + (l & 15);
        if (node >= M) continue;
        #pragma unroll
        for (int mi = 0; mi < 4; ++mi) {
            int col = c * 128 + mh * 64 + mi * 16 + 4 * (l >> 4);
            float v[4];
            const float* bf = &bb[mi].x;
            #pragma unroll
            for (int r = 0; r < 4; ++r) {
                v[r] = acc[mi][ni][r] + bf[r];
                if (RELU) v[r] = fmaxf(v[r], 0.f);
            }
            if (EPI == 0) {
                *(uint2*)(ob + (size_t)node * LDN + col) = pack4(v);
            } else {
                size_t a = (size_t)node * 128 + col;
                if (EPI == 2) {
                    float4 old = *(const float4*)(of + a);
                    v[0] += old.x; v[1] += old.y; v[2] += old.z; v[3] += old.w;
                }
                float4 s4; s4.x = v[0]; s4.y = v[1]; s4.z = v[2]; s4.w = v[3];
                *(float4*)(of + a) = s4;
                *(uint2*)(ob + a) = pack4(v);
            }
        }
    }
}

// ---------------------------------------------------------------------------
// outhead2_k: A-once non-swapped output-head GEMM2 + segment-max.
// Per 64-row block: stage Hout1[64][512] once (64 KB, ONE barrier), then for
// each of 8 col-chunks: W b-frags per-lane direct from packed file (same
// indexing as gemm_k staged frags), non-swapped MFMA -> rows register-
// resident -> sorted-run merge (8 rows/lane) before uint atomicMax.
// ---------------------------------------------------------------------------
__global__ __launch_bounds__(256) void outhead2_k(
    const u16* __restrict__ A, const uint4* __restrict__ wfrag,
    const float* __restrict__ bias, const int* __restrict__ bvec,
    float* __restrict__ gout, int M)
{
    __shared__ uint4 smem[4096];       // 64 rows x 512 K bf16 = 64 KB
    __shared__ int sb[64];
    const int t = threadIdx.x, l = t & 63, wv = t >> 6;
    const int mh = wv >> 1, nh = wv & 1;
    const int mblk = blockIdx.x;

    if (t < 64) {
        int r = mblk * 64 + t;
        sb[t] = (r < M) ? bvec[r] : -1;
    }
    #pragma unroll
    for (int i = 0; i < 16; ++i) {               // stage A once: [ksl16][mt4][64]
        int s = t + 256 * i;
        int ln = s & 63, mt = (s >> 6) & 3, ksl = s >> 8;
        int row = mblk * 64 + mt * 16 + (ln & 15);
        if (row >= M) row = M - 1;
        int kk = ksl * 32 + (ln >> 4) * 8;
        gload_lds16(A + (size_t)row * 512 + kk, &smem[s - ln]);
    }
    __syncthreads();

    #pragma unroll 1
    for (int c = 0; c < 8; ++c) {
        f32x4 acc[2][4] = {};   // [mi][ni]
        #pragma unroll
        for (int ks = 0; ks < 16; ++ks) {
            bf16x8 a[2];
            #pragma unroll
            for (int mi = 0; mi < 2; ++mi) { U16x8 u; u.u = smem[(ks * 4 + mh * 2 + mi) * 64 + l]; a[mi] = u.v; }
            #pragma unroll
            for (int ni = 0; ni < 4; ++ni) {
                U16x8 u; u.u = wfrag[(size_t)((c * 16 + ks) * 8 + nh * 4 + ni) * 64 + l];
                #pragma unroll
                for (int mi = 0; mi < 2; ++mi)
                    acc[mi][ni] = __builtin_amdgcn_mfma_f32_16x16x32_bf16(a[mi], u.v, acc[mi][ni], 0, 0, 0);
            }
        }
        #pragma unroll
        for (int ni = 0; ni < 4; ++ni) {
            int colg = c * 128 + nh * 64 + ni * 16 + (l & 15);
            float bc = bias[colg];
            float mv = 0.f; int cg = -1;
            #pragma unroll
            for (int mi = 0; mi < 2; ++mi)
                #pragma unroll
                for (int r = 0; r < 4; ++r) {
                    int lr = mh * 32 + mi * 16 + 4 * (l >> 4) + r;
                    int g = sb[lr];
                    float v = fmaxf(acc[mi][ni][r] + bc, 0.f);
                    if (g != cg) {
                        if (cg >= 0) atomicMax((u32*)(gout + (size_t)cg * 1024 + colg), __float_as_uint(mv));
                        cg = g; mv = v;
                    } else mv = fmaxf(mv, v);
                }
            if (cg >= 0) atomicMax((u32*)(gout + (size_t)cg * 1024 + colg), __float_as_uint(mv));
        }
    }
}

// ---------------------------------------------------------------------------
// Source functors for A-operand staging (gemm_k).
// ---------------------------------------------------------------------------
struct SrcEnc {             // node encoder input: emb_node[x[row]] (f32 -> bf16)
    static constexpr bool DIRECT = false;
    const float* emb; const int* xids;
    __device__ const void* gaddr(int, int) const { return nullptr; }
    __device__ bf16x8 operator()(int row, int kk) const {
        int n = xids[row];
        const float* p = emb + (size_t)n * 256 + kk;
        float4 f0 = *(const float4*)p, f1 = *(const float4*)(p + 4);
        U16x8 r;
        r.s[0]=f2b(f0.x); r.s[1]=f2b(f0.y); r.s[2]=f2b(f0.z); r.s[3]=f2b(f0.w);
        r.s[4]=f2b(f1.x); r.s[5]=f2b(f1.y); r.s[6]=f2b(f1.z); r.s[7]=f2b(f1.w);
        return r.v;
    }
};
struct SrcUpd {             // [nodes | fi/deg | fo/deg] (f32 -> bf16), K=384
    static constexpr bool DIRECT = false;
    const float* nodes; const float* fi; const float* fo; const int* deg;
    __device__ const void* gaddr(int, int) const { return nullptr; }
    __device__ bf16x8 operator()(int row, int kk) const {
        const float* s; float sc = 1.f;
        if (kk < 128) s = nodes + (size_t)row * 128 + kk;
        else {
            int d = deg[row];
            sc = d > 0 ? 1.f / (float)d : 0.f;
            s = (kk < 256) ? fi + (size_t)row * 128 + (kk - 128)
                           : fo + (size_t)row * 128 + (kk - 256);
        }
        float4 f0 = *(const float4*)s, f1 = *(const float4*)(s + 4);
        U16x8 r;
        r.s[0]=f2b(f0.x*sc); r.s[1]=f2b(f0.y*sc); r.s[2]=f2b(f0.z*sc); r.s[3]=f2b(f0.w*sc);
        r.s[4]=f2b(f1.x*sc); r.s[5]=f2b(f1.y*sc); r.s[6]=f2b(f1.z*sc); r.s[7]=f2b(f1.w*sc);
        return r.v;
    }
};

struct EpiArgs { float* of; u16* ob; const int* idx; int ldN; };

// ---------------------------------------------------------------------------
// gemm_k: non-swapped MFMA, computed A staging. EPI0: bf16 store via
// swizzled LDS bounce.
// ---------------------------------------------------------------------------
template<int KDIM, int NBLK, int EPI, bool RELU, class SRC>
__global__ __launch_bounds__(256) void gemm_k(SRC src, const uint4* __restrict__ wfrag,
                                              const float* __restrict__ bias,
                                              EpiArgs ea, int M)
{
    constexpr int KS = KDIM / 32;
    constexpr int NPANEL = KDIM / 64;
    __shared__ uint4 smem[2048];
    const int t = threadIdx.x;
    const int l = t & 63;
    const int wv = t >> 6;
    const int mh = wv >> 1, nh = wv & 1;
    const int ell = xcd_swz(blockIdx.x, gridDim.x);
    const int mblk = ell / NBLK, nblk = ell % NBLK;

    f32x4 acc[4][4] = {};

    for (int p = 0; p < NPANEL; ++p) {
        __syncthreads();
        #pragma unroll
        for (int i = 0; i < 4; ++i) {              // computed A panel
            int s = t + 256 * i;
            int ln = s & 63, mt = (s >> 6) & 7, ksl = s >> 9;
            int row = mblk * 128 + mt * 16 + (ln & 15);
            if (row >= M) row = M - 1;
            int kk = p * 64 + ksl * 32 + (ln >> 4) * 8;
            U16x8 u; u.v = src(row, kk);
            smem[s] = u.u;
        }
        {                                           // async W panel
            const uint4* wp = wfrag + (size_t)(nblk * KS + 2 * p) * 512;
            #pragma unroll
            for (int i = 0; i < 4; ++i) {
                int s = t + 256 * i;
                gload_lds16(wp + s, &smem[1024 + (s - (s & 63))]);
            }
        }
        __syncthreads();
        #pragma unroll
        for (int ksl = 0; ksl < 2; ++ksl) {
            bf16x8 a[4], b[4];
            #pragma unroll
            for (int mi = 0; mi < 4; ++mi) { U16x8 u; u.u = smem[(ksl*8 + mh*4 + mi)*64 + l]; a[mi] = u.v; }
            #pragma unroll
            for (int ni = 0; ni < 4; ++ni) { U16x8 u; u.u = smem[1024 + (ksl*8 + nh*4 + ni)*64 + l]; b[ni] = u.v; }
            #pragma unroll
            for (int mi = 0; mi < 4; ++mi)
                #pragma unroll
                for (int ni = 0; ni < 4; ++ni)
                    acc[mi][ni] = __builtin_amdgcn_mfma_f32_16x16x32_bf16(a[mi], b[ni], acc[mi][ni], 0, 0, 0);
        }
    }

    float bcol[4];
    #pragma unroll
    for (int ni = 0; ni < 4; ++ni)
        bcol[ni] = bias ? bias[nblk * 128 + nh * 64 + ni * 16 + (l & 15)] : 0.f;

    // EPI0: bf16 store via XOR-swizzled LDS bounce
    __syncthreads();
    u16* bn = (u16*)smem;
    #pragma unroll
    for (int mi = 0; mi < 4; ++mi)
        #pragma unroll
        for (int ni = 0; ni < 4; ++ni)
            #pragma unroll
            for (int r = 0; r < 4; ++r) {
                int rl = mh * 64 + mi * 16 + (l >> 4) * 4 + r;
                int cl = nh * 64 + ni * 16 + (l & 15);
                float v = acc[mi][ni][r] + bcol[ni];
                if (RELU) v = fmaxf(v, 0.f);
                int sx = (rl >> 2) & 7;
                bn[rl * 128 + ((((cl >> 3) ^ sx)) << 3) + (cl & 7)] = f2b(v);
            }
    __syncthreads();
    int row = t >> 1, half = t & 1;
    int grow = mblk * 128 + row;
    if (grow < M) {
        int sx = (row >> 2) & 7;
        uint4* dst = (uint4*)(ea.ob + (size_t)grow * ea.ldN + nblk * 128 + half * 64);
        const uint4* sp = ((const uint4*)bn) + row * 16;
        #pragma unroll
        for (int i = 0; i < 8; ++i) dst[i] = sp[(half * 8 + i) ^ sx];
    }
}

// ---------------------------------------------------------------------------
// Fused per-edge pipeline (edges pre-sorted by idxA) — unchanged from R6.
// ---------------------------------------------------------------------------
__global__ __launch_bounds__(256) void edge_fused(
    const u16* __restrict__ P, const float* __restrict__ T,
    const uint4* __restrict__ W2f, const float* __restrict__ b2,
    const uint4* __restrict__ W3f, const float* __restrict__ b3,
    const int* __restrict__ idxA, const int* __restrict__ idxB,
    const int* __restrict__ eattr, float* __restrict__ agg)
{
    __shared__ uint4 smA[2048];
    __shared__ int   sidx[3][128];
    __shared__ float sT[768];
    const int t = threadIdx.x;
    const int l = t & 63;
    const int wv = t >> 6;
    const int mh = wv >> 1, nh = wv & 1;
    const int base = xcd_swz(blockIdx.x, gridDim.x) * 128;

    if (t < 128) {
        int e = (base + t < NE) ? base + t : NE - 1;
        sidx[0][t] = idxA[e];
        sidx[1][t] = idxB[e];
        sidx[2][t] = eattr[e];
    }
    for (int i = t; i < 768; i += 256) sT[i] = T[i];
    __syncthreads();

    const int rt0 = wv * 16 + (l & 15);
    const int rt1 = (wv + 4) * 16 + (l & 15);
    const int klo = (l >> 4) * 8;
    const u16* pA[2] = { P + (size_t)sidx[0][rt0] * 512, P + (size_t)sidx[0][rt1] * 512 };
    const u16* pB[2] = { P + (size_t)sidx[1][rt0] * 512 + 256, P + (size_t)sidx[1][rt1] * 512 + 256 };
    const float* pT[2] = { sT + sidx[2][rt0] * 256, sT + sidx[2][rt1] * 256 };

    uint4 ra[4], rb[4];
    #pragma unroll
    for (int i = 0; i < 4; ++i) {
        int kk = (i >> 1) * 32 + klo;
        ra[i] = *(const uint4*)(pA[i & 1] + kk);
        rb[i] = *(const uint4*)(pB[i & 1] + kk);
    }

    f32x4 acc[4][4] = {};
    #pragma unroll
    for (int p = 0; p < 4; ++p) {
        #pragma unroll
        for (int i = 0; i < 4; ++i) {
            int kk = (i >> 1) * 32 + klo;
            U16x8 ua, ub, r;
            ua.u = ra[i]; ub.u = rb[i];
            const float* tb = pT[i & 1] + p * 64 + kk;
            #pragma unroll
            for (int j = 0; j < 8; ++j) {
                float v = b2f(ua.s[j]) + b2f(ub.s[j]) + tb[j];
                r.s[j] = f2b(fmaxf(v, 0.f));
            }
            smA[(p & 1) * 1024 + t + 256 * i] = r.u;
            if (p < 3) {
                int kn = (p + 1) * 64 + kk;
                ra[i] = *(const uint4*)(pA[i & 1] + kn);
                rb[i] = *(const uint4*)(pB[i & 1] + kn);
            }
        }
        asm volatile("s_waitcnt lgkmcnt(0)" ::: "memory");
        __builtin_amdgcn_s_barrier();
        uint4 bw[2][4];
        #pragma unroll
        for (int ksl = 0; ksl < 2; ++ksl)
            #pragma unroll
            for (int ni = 0; ni < 4; ++ni)
                bw[ksl][ni] = W2f[(size_t)((p * 2 + ksl) * 8 + nh * 4 + ni) * 64 + l];
        #pragma unroll
        for (int ksl = 0; ksl < 2; ++ksl) {
            bf16x8 a[4];
            #pragma unroll
            for (int mi = 0; mi < 4; ++mi) { U16x8 u; u.u = smA[(p & 1) * 1024 + (ksl*8 + mh*4 + mi)*64 + l]; a[mi] = u.v; }
            #pragma unroll
            for (int mi = 0; mi < 4; ++mi)
                #pragma unroll
                for (int ni = 0; ni < 4; ++ni) {
                    U16x8 u; u.u = bw[ksl][ni];
                    acc[mi][ni] = __builtin_amdgcn_mfma_f32_16x16x32_bf16(a[mi], u.v, acc[mi][ni], 0, 0, 0);
                }
        }
    }

    float bc2[4];
    #pragma unroll
    for (int ni = 0; ni < 4; ++ni) bc2[ni] = b2[nh * 64 + ni * 16 + (l & 15)];
    __builtin_amdgcn_s_barrier();
    u16* bn = (u16*)smA;
    #pragma unroll
    for (int mi = 0; mi < 4; ++mi)
        #pragma unroll
        for (int ni = 0; ni < 4; ++ni)
            #pragma unroll
            for (int r = 0; r < 4; ++r) {
                int rl = mh * 64 + mi * 16 + (l >> 4) * 4 + r;
                int cl = nh * 64 + ni * 16 + (l & 15);
                float v = fmaxf(acc[mi][ni][r] + bc2[ni], 0.f);
                int sx = (rl >> 2) & 7;
                bn[rl * 128 + (((cl >> 3) ^ sx) << 3) + (cl & 7)] = f2b(v);
            }
    asm volatile("s_waitcnt lgkmcnt(0)" ::: "memory");
    __builtin_amdgcn_s_barrier();

    f32x4 acc2[4][4] = {};
    #pragma unroll
    for (int ks = 0; ks < 4; ++ks) {
        uint4 bw[4];
        #pragma unroll
        for (int ni = 0; ni < 4; ++ni)
            bw[ni] = W3f[(size_t)(ks * 8 + nh * 4 + ni) * 64 + l];
        bf16x8 a[4];
        #pragma unroll
        for (int mi = 0; mi < 4; ++mi) {
            int rl = (mh * 4 + mi) * 16 + (l & 15);
            int c0 = ks * 32 + (l >> 4) * 8;
            int sx = (rl >> 2) & 7;
            U16x8 u; u.u = *(const uint4*)&bn[rl * 128 + (((c0 >> 3) ^ sx) << 3)];
            a[mi] = u.v;
        }
        #pragma unroll
        for (int mi = 0; mi < 4; ++mi)
            #pragma unroll
            for (int ni = 0; ni < 4; ++ni) {
                U16x8 u; u.u = bw[ni];
                acc2[mi][ni] = __builtin_amdgcn_mfma_f32_16x16x32_bf16(a[mi], u.v, acc2[mi][ni], 0, 0, 0);
            }
    }

    float bc3[4];
    #pragma unroll
    for (int ni = 0; ni < 4; ++ni) bc3[ni] = b3[nh * 64 + ni * 16 + (l & 15)];
    #pragma unroll
    for (int mi = 0; mi < 4; ++mi) {
        int rt4 = mh * 64 + mi * 16 + (l >> 4) * 4;
        int nd[4];
        #pragma unroll
        for (int r = 0; r < 4; ++r)
            nd[r] = (base + rt4 + r < NE) ? sidx[0][rt4 + r] : -1;
        #pragma unroll
        for (int ni = 0; ni < 4; ++ni) {
            int col = nh * 64 + ni * 16 + (l & 15);
            float mv = 0.f; int cg = -1;
            #pragma unroll
            for (int r = 0; r < 4; ++r) {
                float v = fmaxf(acc2[mi][ni][r] + bc3[ni], 0.f);
                if (nd[r] != cg) {
                    if (cg >= 0) atomicAdd(agg + (size_t)cg * 128 + col, mv);
                    cg = nd[r]; mv = v;
                } else mv += v;
            }
            if (cg >= 0) atomicAdd(agg + (size_t)cg * 128 + col, mv);
        }
    }
}

// ---------------------------------------------------------------------------
// Fused counting sort, both keys (parent=dst, child=src) in single launches.
// ---------------------------------------------------------------------------
__global__ void hist2_kernel(const int* __restrict__ dstI, const int* __restrict__ srcI,
                             int* __restrict__ hist)
{
    int i = blockIdx.x * 256 + threadIdx.x;
    if (i < NE) atomicAdd(&hist[dstI[i]], 1);
    else if (i < 2 * NE) atomicAdd(&hist[NBINS + srcI[i - NE]], 1);
}
__global__ void chunk_sum(const int* __restrict__ h, int* __restrict__ part)
{
    __shared__ int sh[256];
    int t = threadIdx.x, b = blockIdx.x;       // b in [0, 2*NPART)
    sh[t] = h[b * 256 + t];
    __syncthreads();
    for (int o = 128; o > 0; o >>= 1) { if (t < o) sh[t] += sh[t + o]; __syncthreads(); }
    if (t == 0) part[b] = sh[0];
}
__global__ void scan_part2(int* part)          // 2 blocks; per-half exclusive scan
{
    __shared__ int sh[256];
    int t = threadIdx.x, b = blockIdx.x;
    int* p = part + b * NPART;
    sh[t] = (t < NPART) ? p[t] : 0;
    __syncthreads();
    for (int o = 1; o < 256; o <<= 1) {
        int x = (t >= o) ? sh[t - o] : 0;
        __syncthreads(); sh[t] += x; __syncthreads();
    }
    if (t < NPART) p[t] = (t ? sh[t - 1] : 0) + b * NE;   // child half biased by NE
}
__global__ void mk_cursor(const int* __restrict__ h, const int* __restrict__ part,
                          int* __restrict__ cur)
{
    __shared__ int sh[256];
    int t = threadIdx.x, b = blockIdx.x;       // b in [0, 2*NPART)
    int v = h[b * 256 + t];
    sh[t] = v;
    __syncthreads();
    for (int o = 1; o < 256; o <<= 1) {
        int x = (t >= o) ? sh[t - o] : 0;
        __syncthreads(); sh[t] += x; __syncthreads();
    }
    cur[b * 256 + t] = part[b] + sh[t] - v;
}
__global__ void sort_scatter2(const int* __restrict__ dstI, const int* __restrict__ srcI,
                              const int* __restrict__ at, int* __restrict__ cur,
                              int* __restrict__ oA, int* __restrict__ oB, int* __restrict__ oC)
{
    int i = blockIdx.x * 256 + threadIdx.x;
    if (i < NE) {
        int k = dstI[i];
        int p = atomicAdd(&cur[k], 1);
        oA[p] = k; oB[p] = srcI[i]; oC[p] = at[i];
    } else if (i < 2 * NE) {
        int e = i - NE;
        int k = srcI[e];
        int p = atomicAdd(&cur[NBINS + k], 1);   // cursor pre-biased by NE
        oA[p] = k; oB[p] = dstI[e]; oC[p] = at[e];
    }
}

// ---------------------------------------------------------------------------
// Mega weight packer: all 15 pack jobs in one launch (constexpr job table).
// ---------------------------------------------------------------------------
struct PackPtrs { const float* p[13]; };

__global__ void pack_all(PackPtrs pp, uint4* __restrict__ frag)
{
    int tid = blockIdx.x * 256 + threadIdx.x;
    if (tid >= 126976) return;
    constexpr int NJ = 15;
    const int   start[NJ] = {0,4096,6144,10240,14336,18432,22528,26624,28672,32768,34816,47104,51200,53248,61440};
    const int   fbase[NJ] = {0,4096,6144,6144,14336,14336,22528,26624,28672,32768,34816,47104,51200,53248,61440};
    const short wsel [NJ] = {0,1,2,2,3,3,4,5,6,7,8,9,10,11,12};
    const short ldt  [NJ] = {128,128,256,256,256,256,128,128,128,128,256,128,128,512,1024};
    const short rot  [NJ] = {0,0,0,128,0,128,0,0,0,0,0,0,0,0,0};
    const short cot  [NJ] = {0,0,0,-256,0,-256,0,0,0,0,0,0,0,0,0};
    const short nbst [NJ] = {0,0,0,2,0,2,0,0,0,0,0,0,0,0,0};
    const short kst  [NJ] = {8,4,4,4,4,4,8,4,8,4,12,8,4,4,16};
    int j = 0;
    for (int i = NJ - 1; i >= 1; --i) if (tid >= start[i]) { j = i; break; }
    int rem = tid - start[j];
    int KS = kst[j];
    int nbrel = rem / (KS * 512);
    int r1 = rem % (KS * 512);
    int ks = r1 >> 9;
    int r2 = r1 & 511;
    int nt = r2 >> 6, l = r2 & 63;
    int nb = nbst[j] + nbrel;
    int k  = ks * 32 + (l >> 4) * 8;
    int ld = ldt[j];
    int col = nb * 128 + nt * 16 + (l & 15) + cot[j];
    const float* W = pp.p[wsel[j]];
    U16x8 u;
    #pragma unroll
    for (int jj = 0; jj < 8; ++jj) u.s[jj] = f2b(W[(size_t)(rot[j] + k + jj) * ld + col]);
    frag[fbase[j] + ((size_t)(nb * KS + ks) * 8 + nt) * 64 + l] = u.u;
}

// ---------------------------------------------------------------------------
// Edge-type tables, fused.
// ---------------------------------------------------------------------------
__global__ void enc_tab_kernel(const float* __restrict__ emb_edge,
                               const float* __restrict__ We1, const float* __restrict__ be1,
                               const float* __restrict__ We2, const float* __restrict__ be2,
                               const float* __restrict__ Wp1, const float* __restrict__ bp1,
                               const float* __restrict__ Wc1, const float* __restrict__ bc1,
                               float* __restrict__ Tp, float* __restrict__ Tc)
{
    __shared__ float h1[3][128];
    __shared__ float ea[3][128];
    const int t = threadIdx.x;   // 256
    if (t < 128) {
        for (int a = 0; a < 3; ++a) {
            float s = be1[t];
            for (int k = 0; k < 256; ++k) s = fmaf(emb_edge[a * 256 + k], We1[k * 128 + t], s);
            h1[a][t] = fmaxf(s, 0.f);
        }
    }
    __syncthreads();
    if (t < 128) {
        for (int a = 0; a < 3; ++a) {
            float s = be2[t];
            for (int k = 0; k < 128; ++k) s = fmaf(h1[a][k], We2[k * 128 + t], s);
            ea[a][t] = fmaxf(s, 0.f);
        }
    }
    __syncthreads();
    for (int a = 0; a < 3; ++a) {
        float sp = bp1[t], sc = bc1[t];
        for (int k = 0; k < 128; ++k) {
            float e = ea[a][k];
            sp = fmaf(e, Wp1[(size_t)(256 + k) * 256 + t], sp);
            sc = fmaf(e, Wc1[(size_t)(256 + k) * 256 + t], sc);
        }
        Tp[a * 256 + t] = sp;
        Tc[a * 256 + t] = sc;
    }
}

// ---------------------------------------------------------------------------
extern "C" void kernel_launch(void* const* d_in, const int* in_sizes, int n_in,
                              void* d_out, int out_size, void* d_ws, size_t ws_size,
                              hipStream_t stream)
{
    const int*   x          = (const int*)d_in[0];
    const int*   edge_index = (const int*)d_in[1];
    const int*   edge_attr  = (const int*)d_in[2];
    const int*   batch_vec  = (const int*)d_in[3];
    const float* emb_node   = (const float*)d_in[4];
    const float* Wn1 = (const float*)d_in[5];  const float* bn1 = (const float*)d_in[6];
    const float* Wn2 = (const float*)d_in[7];  const float* bn2 = (const float*)d_in[8];
    const float* emb_edge = (const float*)d_in[9];
    const float* We1 = (const float*)d_in[10]; const float* be1 = (const float*)d_in[11];
    const float* We2 = (const float*)d_in[12]; const float* be2 = (const float*)d_in[13];
    const float* Wp1 = (const float*)d_in[14]; const float* bp1 = (const float*)d_in[15];
    const float* Wp2 = (const float*)d_in[16]; const float* bp2 = (const float*)d_in[17];
    const float* Wp3 = (const float*)d_in[18]; const float* bp3 = (const float*)d_in[19];
    const float* Wc1 = (const float*)d_in[20]; const float* bc1 = (const float*)d_in[21];
    const float* Wc2 = (const float*)d_in[22]; const float* bc2 = (const float*)d_in[23];
    const float* Wc3 = (const float*)d_in[24]; const float* bc3 = (const float*)d_in[25];
    const float* Wf1 = (const float*)d_in[26]; const float* bf1 = (const float*)d_in[27];
    const float* Wf2 = (const float*)d_in[28]; const float* bf2 = (const float*)d_in[29];
    const float* Wf3 = (const float*)d_in[30]; const float* bf3 = (const float*)d_in[31];
    const float* Wo1 = (const float*)d_in[32]; const float* bo1 = (const float*)d_in[33];
    const float* Wo2 = (const float*)d_in[34]; const float* bo2 = (const float*)d_in[35];

    float* out = (float*)d_out;

    char* w = (char*)d_ws;
    auto alloc = [&](size_t bytes) { char* p = w; w += (bytes + 255) & ~(size_t)255; return p; };
    float* nodes   = (float*)alloc((size_t)NN * DD * 4);
    u16*   nodesbf = (u16*)  alloc((size_t)NN * DD * 2);
    float* fi      = (float*)alloc((size_t)NN * DD * 4);
    float* fo      = (float*)alloc((size_t)NN * DD * 4);   // contiguous after fi
    u16*   P       = (u16*)  alloc((size_t)NN * 512 * 2);
    u16*   h2      = (u16*)  alloc((size_t)NN * 384 * 2);
    float* Tp      = (float*)alloc(3 * 256 * 4);
    float* Tc      = (float*)alloc(3 * 256 * 4);
    uint4* frag    = (uint4*)alloc((size_t)126976 * 16);
    int* hist = (int*)alloc((size_t)2 * NBINS * 4);        // [dst | src]; src half = deg
    int* part = (int*)alloc((size_t)2 * NPART * 4);
    int* cur  = (int*)alloc((size_t)2 * NBINS * 4);
    int* sA   = (int*)alloc((size_t)2 * NE * 4);           // [parent | child]
    int* sB   = (int*)alloc((size_t)2 * NE * 4);
    int* sC   = (int*)alloc((size_t)2 * NE * 4);

    u16* He = h2;                      // [50k][128]
    u16* U1 = h2;                      // [50k][256]
    u16* U2 = h2 + (size_t)NN * 256;   // [50k][128]
    u16* Hout1 = P;                    // [50k][512]
    const int* degS = hist + NBINS;    // deg(src) as int

    uint4* Wn1f = frag;                // K256 N128
    uint4* Wn2f = Wn1f + 4096;         // K128 N128
    uint4* PWp  = Wn2f + 2048;         // K128 N512
    uint4* PWc  = PWp  + 8192;
    uint4* W2p  = PWc  + 8192;         // K256 N128
    uint4* W3p  = W2p  + 4096;         // K128 N128
    uint4* W2c  = W3p  + 2048;
    uint4* W3c  = W2c  + 4096;
    uint4* Wf1f = W3c  + 2048;         // K384 N256
    uint4* Wf2f = Wf1f + 12288;        // K256 N128
    uint4* Wf3f = Wf2f + 4096;         // K128 N128
    uint4* Wo1f = Wf3f + 2048;         // K128 N512
    uint4* Wo2f = Wo1f + 8192;         // K512 N1024

    const int* srcI = edge_index;
    const int* dstI = edge_index + NE;

    const int MB50 = (NN + 127) / 128;   // 391
    const int MBE  = (NE + 127) / 128;   // 1563
    const int MB64 = (NN + 63) / 64;     // 782

    // ---- prep --------------------------------------------------------------
    (void)hipMemsetAsync(d_out, 0, (size_t)out_size * 4, stream);
    (void)hipMemsetAsync(hist, 0, (size_t)2 * NBINS * 4, stream);

    PackPtrs pp;
    pp.p[0]=Wn1; pp.p[1]=Wn2; pp.p[2]=Wp1; pp.p[3]=Wc1; pp.p[4]=Wp2; pp.p[5]=Wp3;
    pp.p[6]=Wc2; pp.p[7]=Wc3; pp.p[8]=Wf1; pp.p[9]=Wf2; pp.p[10]=Wf3; pp.p[11]=Wo1; pp.p[12]=Wo2;
    pack_all<<<(126976 + 255) / 256, 256, 0, stream>>>(pp, frag);

    enc_tab_kernel<<<1, 256, 0, stream>>>(emb_edge, We1, be1, We2, be2,
                                          Wp1, bp1, Wc1, bc1, Tp, Tc);

    hist2_kernel<<<(2 * NE + 255) / 256, 256, 0, stream>>>(dstI, srcI, hist);
    chunk_sum<<<2 * NPART, 256, 0, stream>>>(hist, part);
    scan_part2<<<2, 256, 0, stream>>>(part);
    mk_cursor<<<2 * NPART, 256, 0, stream>>>(hist, part, cur);
    sort_scatter2<<<(2 * NE + 255) / 256, 256, 0, stream>>>(dstI, srcI, edge_attr, cur, sA, sB, sC);

    // ---- node encoder ------------------------------------------------------
    gemm_k<256, 1, 0, true, SrcEnc><<<MB50, 256, 0, stream>>>(
        SrcEnc{emb_node, x}, Wn1f, bn1, EpiArgs{nullptr, He, nullptr, 128}, NN);
    expand_k<128, 1, 1, true, 128><<<dim3(MB50, 1), 256, 0, stream>>>(
        He, Wn2f, bn2, nodes, nodesbf, nullptr, NN);

    // ---- message-passing iterations ---------------------------------------
    for (int it = 0; it < NITERS; ++it) {
        // parent: P-pass also zero-fills fi
        expand_k<128, 4, 0, false, 512><<<dim3(MB50, 4), 256, 0, stream>>>(
            nodesbf, PWp, nullptr, nullptr, P, fi, NN);
        edge_fused<<<MBE, 256, 0, stream>>>(P, Tp, W2p, bp2, W3p, bp3,
                                            sA, sB, sC, fi);

        // child: P-pass also zero-fills fo
        expand_k<128, 4, 0, false, 512><<<dim3(MB50, 4), 256, 0, stream>>>(
            nodesbf, PWc, nullptr, nullptr, P, fo, NN);
        edge_fused<<<MBE, 256, 0, stream>>>(P, Tc, W2c, bc2, W3c, bc3,
                                            sA + NE, sB + NE, sC + NE, fo);

        gemm_k<384, 2, 0, true, SrcUpd><<<MB50 * 2, 256, 0, stream>>>(
            SrcUpd{nodes, fi, fo, degS}, Wf1f, bf1, EpiArgs{nullptr, U1, nullptr, 256}, NN);
        expand_k<256, 1, 0, true, 128><<<dim3(MB50, 1), 256, 0, stream>>>(
            U1, Wf2f, bf2, nullptr, U2, nullptr, NN);
        expand_k<128, 1, 2, true, 128><<<dim3(MB50, 1), 256, 0, stream>>>(
            U2, Wf3f, bf3, nodes, nodesbf, nullptr, NN);
    }

    // ---- output head + global max pool -------------------------------------
    expand_k<128, 4, 0, true, 512><<<dim3(MB50, 4), 256, 0, stream>>>(
        nodesbf, Wo1f, bo1, nullptr, Hout1, nullptr, NN);
    outhead2_k<<<MB64, 256, 0, stream>>>(Hout1, Wo2f, bo2, batch_vec, out, NN);
}

// Round 11
// 912.290 us; speedup vs baseline: 1.0764x; 1.0764x over previous
//
#include <hip/hip_runtime.h>

#define NN 50000
#define NE 200000
#define DD 128
#define GG 256
#define NITERS 2
#define NBINS 50176          // 196 * 256, >= NN
#define NPART 196

typedef unsigned short u16;
typedef unsigned int u32;
typedef __bf16 bf16x8 __attribute__((ext_vector_type(8)));
typedef float f32x4 __attribute__((ext_vector_type(4)));

union U16x8 { uint4 u; bf16x8 v; u16 s[8]; };

__device__ __forceinline__ u16 f2b(float f) {             // f32 -> bf16 bits, RNE
    u32 u = __float_as_uint(f);
    return (u16)((u + 0x7FFFu + ((u >> 16) & 1u)) >> 16);
}
__device__ __forceinline__ float b2f(u16 s) { return __uint_as_float(((u32)s) << 16); }

__device__ __forceinline__ uint2 pack4(const float* v) {
    uint2 r;
    r.x = (u32)f2b(v[0]) | ((u32)f2b(v[1]) << 16);
    r.y = (u32)f2b(v[2]) | ((u32)f2b(v[3]) << 16);
    return r;
}

// async global -> LDS, 16B per lane; lds must be the wave-uniform base slot
__device__ __forceinline__ void gload_lds16(const void* g, void* lds) {
    __builtin_amdgcn_global_load_lds((const __attribute__((address_space(1))) void*)g,
                                     (__attribute__((address_space(3))) void*)lds, 16, 0, 0);
}

// XCD-chunked bijective block swizzle (m204 form)
__device__ __forceinline__ int xcd_swz(int orig, int nwg) {
    int q = nwg >> 3, r = nwg & 7;
    int x = orig & 7, loc = orig >> 3;
    return (x < r ? x * (q + 1) : r * (q + 1) + (x - r) * q) + loc;
}

// ---------------------------------------------------------------------------
// expand_k: OUT[128 rows][cols c*128..] = epi(A[128][K] @ W + bias), c = blockIdx.y
// A staged ONCE in LDS; W fragments per-lane direct global loads; swapped
// MFMA operands -> each thread owns 4 consecutive out-cols of one row.
// EPI: 0 = bf16 store (ob, ldN=LDN); 1 = f32 of + bf16 ob (LDN=128);
//      2 = residual: of += , ob mirror (LDN=128).
// zf: optional f32 [M][128] buffer to zero-fill (block zeroes its slice).
// ---------------------------------------------------------------------------
template<int K, int NL, int EPI, bool RELU, int LDN>
__global__ __launch_bounds__(256) void expand_k(
    const u16* __restrict__ A, const uint4* __restrict__ wfrag,
    const float* __restrict__ bias, float* __restrict__ of, u16* __restrict__ ob,
    float* __restrict__ zf, int M)
{
    constexpr int KS = K / 32;
    __shared__ uint4 smem[K * 16];
    const int t = threadIdx.x, l = t & 63, wv = t >> 6;
    const int mh = wv >> 1, nh = wv & 1;
    const int mblk = blockIdx.x;
    const int c = blockIdx.y;

    #pragma unroll
    for (int i = 0; i < K / 16; ++i) {           // stage A once
        int s = t + 256 * i;
        int ln = s & 63, mt = (s >> 6) & 7, ksl = s >> 9;
        int row = mblk * 128 + mt * 16 + (ln & 15);
        if (row >= M) row = M - 1;
        int kk = ksl * 32 + (ln >> 4) * 8;
        gload_lds16(A + (size_t)row * K + kk, &smem[s - ln]);
    }
    if (zf) {                                    // zero-fill slice (overlaps staging)
        #pragma unroll
        for (int i = 0; i < 4; ++i) {
            int f = t + 256 * i;                 // float4 idx in [0,1024)
            int row = f >> 3, c4 = f & 7;
            int grow = mblk * 128 + row;
            if (grow < M) {
                float4 z; z.x = 0.f; z.y = 0.f; z.z = 0.f; z.w = 0.f;
                *(float4*)(zf + (size_t)grow * 128 + c * 32 + c4 * 4) = z;
            }
        }
    }
    __syncthreads();

    f32x4 acc[4][4] = {};
    #pragma unroll
    for (int ksl = 0; ksl < KS; ++ksl) {
        uint4 wa[4];
        #pragma unroll
        for (int mi = 0; mi < 4; ++mi)
            wa[mi] = wfrag[(size_t)((c * KS + ksl) * 8 + mh * 4 + mi) * 64 + l];
        bf16x8 bn[4];
        #pragma unroll
        for (int ni = 0; ni < 4; ++ni) { U16x8 u; u.u = smem[(ksl * 8 + nh * 4 + ni) * 64 + l]; bn[ni] = u.v; }
        #pragma unroll
        for (int mi = 0; mi < 4; ++mi) {
            U16x8 u; u.u = wa[mi];
            #pragma unroll
            for (int ni = 0; ni < 4; ++ni)
                acc[mi][ni] = __builtin_amdgcn_mfma_f32_16x16x32_bf16(u.v, bn[ni], acc[mi][ni], 0, 0, 0);
        }
    }
    float4 bb[4];
    #pragma unroll
    for (int mi = 0; mi < 4; ++mi) {
        if (bias) bb[mi] = *(const float4*)(bias + c * 128 + mh * 64 + mi * 16 + 4 * (l >> 4));
        else { bb[mi].x = 0.f; bb[mi].y = 0.f; bb[mi].z = 0.f; bb[mi].w = 0.f; }
    }
    #pragma unroll
    for (int ni = 0; ni < 4; ++ni) {
        int node = mblk * 128 + nh * 64 + ni * 16 + (l & 15);
        if (node >= M) continue;
        #pragma unroll
        for (int mi = 0; mi < 4; ++mi) {
            int col = c * 128 + mh * 64 + mi * 16 + 4 * (l >> 4);
            float v[4];
            const float* bf = &bb[mi].x;
            #pragma unroll
            for (int r = 0; r < 4; ++r) {
                v[r] = acc[mi][ni][r] + bf[r];
                if (RELU) v[r] = fmaxf(v[r], 0.f);
            }
            if (EPI == 0) {
                *(uint2*)(ob + (size_t)node * LDN + col) = pack4(v);
            } else {
                size_t a = (size_t)node * 128 + col;
                if (EPI == 2) {
                    float4 old = *(const float4*)(of + a);
                    v[0] += old.x; v[1] += old.y; v[2] += old.z; v[3] += old.w;
                }
                float4 s4; s4.x = v[0]; s4.y = v[1]; s4.z = v[2]; s4.w = v[3];
                *(float4*)(of + a) = s4;
                *(uint2*)(ob + a) = pack4(v);
            }
        }
    }
}

// ---------------------------------------------------------------------------
// Source functors for A-operand staging (gemm_k).
// ---------------------------------------------------------------------------
struct SrcBf16 {            // plain bf16 row-major [M][K], async-staged
    static constexpr bool DIRECT = true;
    const u16* A; int K;
    __device__ const void* gaddr(int row, int kk) const { return A + (size_t)row * K + kk; }
    __device__ bf16x8 operator()(int row, int kk) const {
        U16x8 u; u.u = *(const uint4*)(A + (size_t)row * K + kk); return u.v;
    }
};
struct SrcEnc {             // node encoder input: emb_node[x[row]] (f32 -> bf16)
    static constexpr bool DIRECT = false;
    const float* emb; const int* xids;
    __device__ const void* gaddr(int, int) const { return nullptr; }
    __device__ bf16x8 operator()(int row, int kk) const {
        int n = xids[row];
        const float* p = emb + (size_t)n * 256 + kk;
        float4 f0 = *(const float4*)p, f1 = *(const float4*)(p + 4);
        U16x8 r;
        r.s[0]=f2b(f0.x); r.s[1]=f2b(f0.y); r.s[2]=f2b(f0.z); r.s[3]=f2b(f0.w);
        r.s[4]=f2b(f1.x); r.s[5]=f2b(f1.y); r.s[6]=f2b(f1.z); r.s[7]=f2b(f1.w);
        return r.v;
    }
};
struct SrcUpd {             // [nodes | fi/deg | fo/deg] (f32 -> bf16), K=384
    static constexpr bool DIRECT = false;
    const float* nodes; const float* fi; const float* fo; const int* deg;
    __device__ const void* gaddr(int, int) const { return nullptr; }
    __device__ bf16x8 operator()(int row, int kk) const {
        const float* s; float sc = 1.f;
        if (kk < 128) s = nodes + (size_t)row * 128 + kk;
        else {
            int d = deg[row];
            sc = d > 0 ? 1.f / (float)d : 0.f;
            s = (kk < 256) ? fi + (size_t)row * 128 + (kk - 128)
                           : fo + (size_t)row * 128 + (kk - 256);
        }
        float4 f0 = *(const float4*)s, f1 = *(const float4*)(s + 4);
        U16x8 r;
        r.s[0]=f2b(f0.x*sc); r.s[1]=f2b(f0.y*sc); r.s[2]=f2b(f0.z*sc); r.s[3]=f2b(f0.w*sc);
        r.s[4]=f2b(f1.x*sc); r.s[5]=f2b(f1.y*sc); r.s[6]=f2b(f1.z*sc); r.s[7]=f2b(f1.w*sc);
        return r.v;
    }
};

struct EpiArgs { float* of; u16* ob; const int* idx; int ldN; };

// ---------------------------------------------------------------------------
// gemm_k: non-swapped MFMA (C rows register-resident).
// WDIR=false: W panels staged async to LDS (32 KB total).
// WDIR=true : W fragments per-lane direct from global (16.5 KB LDS -> ~9
//             blocks/CU; latency hidden by TLP). Used for the out-head.
// EPI0: bf16 store via swizzled LDS bounce (requires !WDIR).
// EPI3: segment-max by sorted idx; ni-outer merge over 16 (mi,r) rows.
// ---------------------------------------------------------------------------
template<int KDIM, int NBLK, int EPI, bool RELU, bool WDIR, class SRC>
__global__ __launch_bounds__(256) void gemm_k(SRC src, const uint4* __restrict__ wfrag,
                                              const float* __restrict__ bias,
                                              EpiArgs ea, int M)
{
    constexpr int KS = KDIM / 32;
    constexpr int NPANEL = KDIM / 64;
    __shared__ uint4 smem[WDIR ? 1024 : 2048];
    const int t = threadIdx.x;
    const int l = t & 63;
    const int wv = t >> 6;
    const int mh = wv >> 1, nh = wv & 1;
    const int ell = xcd_swz(blockIdx.x, gridDim.x);
    const int mblk = ell / NBLK, nblk = ell % NBLK;

    f32x4 acc[4][4] = {};

    for (int p = 0; p < NPANEL; ++p) {
        __syncthreads();
        if constexpr (SRC::DIRECT) {
            #pragma unroll
            for (int i = 0; i < 4; ++i) {          // async A panel
                int s = t + 256 * i;
                int ln = s & 63, mt = (s >> 6) & 7, ksl = s >> 9;
                int row = mblk * 128 + mt * 16 + (ln & 15);
                if (row >= M) row = M - 1;
                int kk = p * 64 + ksl * 32 + (ln >> 4) * 8;
                gload_lds16(src.gaddr(row, kk), &smem[s - ln]);
            }
        } else {
            #pragma unroll
            for (int i = 0; i < 4; ++i) {          // computed A panel
                int s = t + 256 * i;
                int ln = s & 63, mt = (s >> 6) & 7, ksl = s >> 9;
                int row = mblk * 128 + mt * 16 + (ln & 15);
                if (row >= M) row = M - 1;
                int kk = p * 64 + ksl * 32 + (ln >> 4) * 8;
                U16x8 u; u.v = src(row, kk);
                smem[s] = u.u;
            }
        }
        if constexpr (!WDIR) {                      // async W panel
            const uint4* wp = wfrag + (size_t)(nblk * KS + 2 * p) * 512;
            #pragma unroll
            for (int i = 0; i < 4; ++i) {
                int s = t + 256 * i;
                gload_lds16(wp + s, &smem[1024 + (s - (s & 63))]);
            }
        }
        __syncthreads();
        #pragma unroll
        for (int ksl = 0; ksl < 2; ++ksl) {
            bf16x8 a[4], b[4];
            #pragma unroll
            for (int mi = 0; mi < 4; ++mi) { U16x8 u; u.u = smem[(ksl*8 + mh*4 + mi)*64 + l]; a[mi] = u.v; }
            if constexpr (WDIR) {
                #pragma unroll
                for (int ni = 0; ni < 4; ++ni) {
                    U16x8 u;
                    u.u = wfrag[(size_t)((nblk * KS + 2 * p + ksl) * 8 + nh * 4 + ni) * 64 + l];
                    b[ni] = u.v;
                }
            } else {
                #pragma unroll
                for (int ni = 0; ni < 4; ++ni) { U16x8 u; u.u = smem[1024 + (ksl*8 + nh*4 + ni)*64 + l]; b[ni] = u.v; }
            }
            #pragma unroll
            for (int mi = 0; mi < 4; ++mi)
                #pragma unroll
                for (int ni = 0; ni < 4; ++ni)
                    acc[mi][ni] = __builtin_amdgcn_mfma_f32_16x16x32_bf16(a[mi], b[ni], acc[mi][ni], 0, 0, 0);
        }
    }

    float bcol[4];
    #pragma unroll
    for (int ni = 0; ni < 4; ++ni)
        bcol[ni] = bias ? bias[nblk * 128 + nh * 64 + ni * 16 + (l & 15)] : 0.f;

    if constexpr (EPI == 0) {
        // bf16 store via XOR-swizzled LDS bounce
        __syncthreads();
        u16* bn = (u16*)smem;
        #pragma unroll
        for (int mi = 0; mi < 4; ++mi)
            #pragma unroll
            for (int ni = 0; ni < 4; ++ni)
                #pragma unroll
                for (int r = 0; r < 4; ++r) {
                    int rl = mh * 64 + mi * 16 + (l >> 4) * 4 + r;
                    int cl = nh * 64 + ni * 16 + (l & 15);
                    float v = acc[mi][ni][r] + bcol[ni];
                    if (RELU) v = fmaxf(v, 0.f);
                    int sx = (rl >> 2) & 7;
                    bn[rl * 128 + ((((cl >> 3) ^ sx)) << 3) + (cl & 7)] = f2b(v);
                }
        __syncthreads();
        int row = t >> 1, half = t & 1;
        int grow = mblk * 128 + row;
        if (grow < M) {
            int sx = (row >> 2) & 7;
            uint4* dst = (uint4*)(ea.ob + (size_t)grow * ea.ldN + nblk * 128 + half * 64);
            const uint4* sp = ((const uint4*)bn) + row * 16;
            #pragma unroll
            for (int i = 0; i < 8; ++i) dst[i] = sp[(half * 8 + i) ^ sx];
        }
    } else if constexpr (EPI == 3) {
        // segment-max: batch ids for this lane's 16 rows (within 64-row window)
        int g16[4][4];
        #pragma unroll
        for (int mi = 0; mi < 4; ++mi) {
            int rb = mblk * 128 + mh * 64 + mi * 16 + (l >> 4) * 4;
            #pragma unroll
            for (int r = 0; r < 4; ++r)
                g16[mi][r] = (rb + r < M) ? ea.idx[rb + r] : -1;
        }
        #pragma unroll
        for (int ni = 0; ni < 4; ++ni) {
            int colg = nblk * 128 + nh * 64 + ni * 16 + (l & 15);
            float mv = 0.f; int cg = -1;
            #pragma unroll
            for (int mi = 0; mi < 4; ++mi)
                #pragma unroll
                for (int r = 0; r < 4; ++r) {
                    float v = acc[mi][ni][r] + bcol[ni];
                    if (RELU) v = fmaxf(v, 0.f);
                    int g = g16[mi][r];
                    if (g != cg) {
                        if (cg >= 0) atomicMax((u32*)(ea.of + (size_t)cg * 1024 + colg), __float_as_uint(mv));
                        cg = g; mv = v;
                    } else mv = fmaxf(mv, v);
                }
            if (cg >= 0) atomicMax((u32*)(ea.of + (size_t)cg * 1024 + colg), __float_as_uint(mv));
        }
    }
}

// ---------------------------------------------------------------------------
// Fused per-edge pipeline (edges pre-sorted by idxA) — unchanged.
// ---------------------------------------------------------------------------
__global__ __launch_bounds__(256) void edge_fused(
    const u16* __restrict__ P, const float* __restrict__ T,
    const uint4* __restrict__ W2f, const float* __restrict__ b2,
    const uint4* __restrict__ W3f, const float* __restrict__ b3,
    const int* __restrict__ idxA, const int* __restrict__ idxB,
    const int* __restrict__ eattr, float* __restrict__ agg)
{
    __shared__ uint4 smA[2048];
    __shared__ int   sidx[3][128];
    __shared__ float sT[768];
    const int t = threadIdx.x;
    const int l = t & 63;
    const int wv = t >> 6;
    const int mh = wv >> 1, nh = wv & 1;
    const int base = xcd_swz(blockIdx.x, gridDim.x) * 128;

    if (t < 128) {
        int e = (base + t < NE) ? base + t : NE - 1;
        sidx[0][t] = idxA[e];
        sidx[1][t] = idxB[e];
        sidx[2][t] = eattr[e];
    }
    for (int i = t; i < 768; i += 256) sT[i] = T[i];
    __syncthreads();

    const int rt0 = wv * 16 + (l & 15);
    const int rt1 = (wv + 4) * 16 + (l & 15);
    const int klo = (l >> 4) * 8;
    const u16* pA[2] = { P + (size_t)sidx[0][rt0] * 512, P + (size_t)sidx[0][rt1] * 512 };
    const u16* pB[2] = { P + (size_t)sidx[1][rt0] * 512 + 256, P + (size_t)sidx[1][rt1] * 512 + 256 };
    const float* pT[2] = { sT + sidx[2][rt0] * 256, sT + sidx[2][rt1] * 256 };

    uint4 ra[4], rb[4];
    #pragma unroll
    for (int i = 0; i < 4; ++i) {
        int kk = (i >> 1) * 32 + klo;
        ra[i] = *(const uint4*)(pA[i & 1] + kk);
        rb[i] = *(const uint4*)(pB[i & 1] + kk);
    }

    f32x4 acc[4][4] = {};
    #pragma unroll
    for (int p = 0; p < 4; ++p) {
        #pragma unroll
        for (int i = 0; i < 4; ++i) {
            int kk = (i >> 1) * 32 + klo;
            U16x8 ua, ub, r;
            ua.u = ra[i]; ub.u = rb[i];
            const float* tb = pT[i & 1] + p * 64 + kk;
            #pragma unroll
            for (int j = 0; j < 8; ++j) {
                float v = b2f(ua.s[j]) + b2f(ub.s[j]) + tb[j];
                r.s[j] = f2b(fmaxf(v, 0.f));
            }
            smA[(p & 1) * 1024 + t + 256 * i] = r.u;
            if (p < 3) {
                int kn = (p + 1) * 64 + kk;
                ra[i] = *(const uint4*)(pA[i & 1] + kn);
                rb[i] = *(const uint4*)(pB[i & 1] + kn);
            }
        }
        asm volatile("s_waitcnt lgkmcnt(0)" ::: "memory");
        __builtin_amdgcn_s_barrier();
        uint4 bw[2][4];
        #pragma unroll
        for (int ksl = 0; ksl < 2; ++ksl)
            #pragma unroll
            for (int ni = 0; ni < 4; ++ni)
                bw[ksl][ni] = W2f[(size_t)((p * 2 + ksl) * 8 + nh * 4 + ni) * 64 + l];
        #pragma unroll
        for (int ksl = 0; ksl < 2; ++ksl) {
            bf16x8 a[4];
            #pragma unroll
            for (int mi = 0; mi < 4; ++mi) { U16x8 u; u.u = smA[(p & 1) * 1024 + (ksl*8 + mh*4 + mi)*64 + l]; a[mi] = u.v; }
            #pragma unroll
            for (int mi = 0; mi < 4; ++mi)
                #pragma unroll
                for (int ni = 0; ni < 4; ++ni) {
                    U16x8 u; u.u = bw[ksl][ni];
                    acc[mi][ni] = __builtin_amdgcn_mfma_f32_16x16x32_bf16(a[mi], u.v, acc[mi][ni], 0, 0, 0);
                }
        }
    }

    float bc2[4];
    #pragma unroll
    for (int ni = 0; ni < 4; ++ni) bc2[ni] = b2[nh * 64 + ni * 16 + (l & 15)];
    __builtin_amdgcn_s_barrier();
    u16* bn = (u16*)smA;
    #pragma unroll
    for (int mi = 0; mi < 4; ++mi)
        #pragma unroll
        for (int ni = 0; ni < 4; ++ni)
            #pragma unroll
            for (int r = 0; r < 4; ++r) {
                int rl = mh * 64 + mi * 16 + (l >> 4) * 4 + r;
                int cl = nh * 64 + ni * 16 + (l & 15);
                float v = fmaxf(acc[mi][ni][r] + bc2[ni], 0.f);
                int sx = (rl >> 2) & 7;
                bn[rl * 128 + (((cl >> 3) ^ sx) << 3) + (cl & 7)] = f2b(v);
            }
    asm volatile("s_waitcnt lgkmcnt(0)" ::: "memory");
    __builtin_amdgcn_s_barrier();

    f32x4 acc2[4][4] = {};
    #pragma unroll
    for (int ks = 0; ks < 4; ++ks) {
        uint4 bw[4];
        #pragma unroll
        for (int ni = 0; ni < 4; ++ni)
            bw[ni] = W3f[(size_t)(ks * 8 + nh * 4 + ni) * 64 + l];
        bf16x8 a[4];
        #pragma unroll
        for (int mi = 0; mi < 4; ++mi) {
            int rl = (mh * 4 + mi) * 16 + (l & 15);
            int c0 = ks * 32 + (l >> 4) * 8;
            int sx = (rl >> 2) & 7;
            U16x8 u; u.u = *(const uint4*)&bn[rl * 128 + (((c0 >> 3) ^ sx) << 3)];
            a[mi] = u.v;
        }
        #pragma unroll
        for (int mi = 0; mi < 4; ++mi)
            #pragma unroll
            for (int ni = 0; ni < 4; ++ni) {
                U16x8 u; u.u = bw[ni];
                acc2[mi][ni] = __builtin_amdgcn_mfma_f32_16x16x32_bf16(a[mi], u.v, acc2[mi][ni], 0, 0, 0);
            }
    }

    float bc3[4];
    #pragma unroll
    for (int ni = 0; ni < 4; ++ni) bc3[ni] = b3[nh * 64 + ni * 16 + (l & 15)];
    #pragma unroll
    for (int mi = 0; mi < 4; ++mi) {
        int rt4 = mh * 64 + mi * 16 + (l >> 4) * 4;
        int nd[4];
        #pragma unroll
        for (int r = 0; r < 4; ++r)
            nd[r] = (base + rt4 + r < NE) ? sidx[0][rt4 + r] : -1;
        #pragma unroll
        for (int ni = 0; ni < 4; ++ni) {
            int col = nh * 64 + ni * 16 + (l & 15);
            float mv = 0.f; int cg = -1;
            #pragma unroll
            for (int r = 0; r < 4; ++r) {
                float v = fmaxf(acc2[mi][ni][r] + bc3[ni], 0.f);
                if (nd[r] != cg) {
                    if (cg >= 0) atomicAdd(agg + (size_t)cg * 128 + col, mv);
                    cg = nd[r]; mv = v;
                } else mv += v;
            }
            if (cg >= 0) atomicAdd(agg + (size_t)cg * 128 + col, mv);
        }
    }
}

// ---------------------------------------------------------------------------
// Fused counting sort, both keys (parent=dst, child=src) in single launches.
// ---------------------------------------------------------------------------
__global__ void hist2_kernel(const int* __restrict__ dstI, const int* __restrict__ srcI,
                             int* __restrict__ hist)
{
    int i = blockIdx.x * 256 + threadIdx.x;
    if (i < NE) atomicAdd(&hist[dstI[i]], 1);
    else if (i < 2 * NE) atomicAdd(&hist[NBINS + srcI[i - NE]], 1);
}
__global__ void chunk_sum(const int* __restrict__ h, int* __restrict__ part)
{
    __shared__ int sh[256];
    int t = threadIdx.x, b = blockIdx.x;       // b in [0, 2*NPART)
    sh[t] = h[b * 256 + t];
    __syncthreads();
    for (int o = 128; o > 0; o >>= 1) { if (t < o) sh[t] += sh[t + o]; __syncthreads(); }
    if (t == 0) part[b] = sh[0];
}
__global__ void scan_part2(int* part)          // 2 blocks; per-half exclusive scan
{
    __shared__ int sh[256];
    int t = threadIdx.x, b = blockIdx.x;
    int* p = part + b * NPART;
    sh[t] = (t < NPART) ? p[t] : 0;
    __syncthreads();
    for (int o = 1; o < 256; o <<= 1) {
        int x = (t >= o) ? sh[t - o] : 0;
        __syncthreads(); sh[t] += x; __syncthreads();
    }
    if (t < NPART) p[t] = (t ? sh[t - 1] : 0) + b * NE;   // child half biased by NE
}
__global__ void mk_cursor(const int* __restrict__ h, const int* __restrict__ part,
                          int* __restrict__ cur)
{
    __shared__ int sh[256];
    int t = threadIdx.x, b = blockIdx.x;       // b in [0, 2*NPART)
    int v = h[b * 256 + t];
    sh[t] = v;
    __syncthreads();
    for (int o = 1; o < 256; o <<= 1) {
        int x = (t >= o) ? sh[t - o] : 0;
        __syncthreads(); sh[t] += x; __syncthreads();
    }
    cur[b * 256 + t] = part[b] + sh[t] - v;
}
__global__ void sort_scatter2(const int* __restrict__ dstI, const int* __restrict__ srcI,
                              const int* __restrict__ at, int* __restrict__ cur,
                              int* __restrict__ oA, int* __restrict__ oB, int* __restrict__ oC)
{
    int i = blockIdx.x * 256 + threadIdx.x;
    if (i < NE) {
        int k = dstI[i];
        int p = atomicAdd(&cur[k], 1);
        oA[p] = k; oB[p] = srcI[i]; oC[p] = at[i];
    } else if (i < 2 * NE) {
        int e = i - NE;
        int k = srcI[e];
        int p = atomicAdd(&cur[NBINS + k], 1);   // cursor pre-biased by NE
        oA[p] = k; oB[p] = dstI[e]; oC[p] = at[e];
    }
}

// ---------------------------------------------------------------------------
// Mega weight packer: all 15 pack jobs in one launch (constexpr job table).
// ---------------------------------------------------------------------------
struct PackPtrs { const float* p[13]; };

__global__ void pack_all(PackPtrs pp, uint4* __restrict__ frag)
{
    int tid = blockIdx.x * 256 + threadIdx.x;
    if (tid >= 126976) return;
    constexpr int NJ = 15;
    const int   start[NJ] = {0,4096,6144,10240,14336,18432,22528,26624,28672,32768,34816,47104,51200,53248,61440};
    const int   fbase[NJ] = {0,4096,6144,6144,14336,14336,22528,26624,28672,32768,34816,47104,51200,53248,61440};
    const short wsel [NJ] = {0,1,2,2,3,3,4,5,6,7,8,9,10,11,12};
    const short ldt  [NJ] = {128,128,256,256,256,256,128,128,128,128,256,128,128,512,1024};
    const short rot  [NJ] = {0,0,0,128,0,128,0,0,0,0,0,0,0,0,0};
    const short cot  [NJ] = {0,0,0,-256,0,-256,0,0,0,0,0,0,0,0,0};
    const short nbst [NJ] = {0,0,0,2,0,2,0,0,0,0,0,0,0,0,0};
    const short kst  [NJ] = {8,4,4,4,4,4,8,4,8,4,12,8,4,4,16};
    int j = 0;
    for (int i = NJ - 1; i >= 1; --i) if (tid >= start[i]) { j = i; break; }
    int rem = tid - start[j];
    int KS = kst[j];
    int nbrel = rem / (KS * 512);
    int r1 = rem % (KS * 512);
    int ks = r1 >> 9;
    int r2 = r1 & 511;
    int nt = r2 >> 6, l = r2 & 63;
    int nb = nbst[j] + nbrel;
    int k  = ks * 32 + (l >> 4) * 8;
    int ld = ldt[j];
    int col = nb * 128 + nt * 16 + (l & 15) + cot[j];
    const float* W = pp.p[wsel[j]];
    U16x8 u;
    #pragma unroll
    for (int jj = 0; jj < 8; ++jj) u.s[jj] = f2b(W[(size_t)(rot[j] + k + jj) * ld + col]);
    frag[fbase[j] + ((size_t)(nb * KS + ks) * 8 + nt) * 64 + l] = u.u;
}

// ---------------------------------------------------------------------------
// Edge-type tables, fused.
// ---------------------------------------------------------------------------
__global__ void enc_tab_kernel(const float* __restrict__ emb_edge,
                               const float* __restrict__ We1, const float* __restrict__ be1,
                               const float* __restrict__ We2, const float* __restrict__ be2,
                               const float* __restrict__ Wp1, const float* __restrict__ bp1,
                               const float* __restrict__ Wc1, const float* __restrict__ bc1,
                               float* __restrict__ Tp, float* __restrict__ Tc)
{
    __shared__ float h1[3][128];
    __shared__ float ea[3][128];
    const int t = threadIdx.x;   // 256
    if (t < 128) {
        for (int a = 0; a < 3; ++a) {
            float s = be1[t];
            for (int k = 0; k < 256; ++k) s = fmaf(emb_edge[a * 256 + k], We1[k * 128 + t], s);
            h1[a][t] = fmaxf(s, 0.f);
        }
    }
    __syncthreads();
    if (t < 128) {
        for (int a = 0; a < 3; ++a) {
            float s = be2[t];
            for (int k = 0; k < 128; ++k) s = fmaf(h1[a][k], We2[k * 128 + t], s);
            ea[a][t] = fmaxf(s, 0.f);
        }
    }
    __syncthreads();
    for (int a = 0; a < 3; ++a) {
        float sp = bp1[t], sc = bc1[t];
        for (int k = 0; k < 128; ++k) {
            float e = ea[a][k];
            sp = fmaf(e, Wp1[(size_t)(256 + k) * 256 + t], sp);
            sc = fmaf(e, Wc1[(size_t)(256 + k) * 256 + t], sc);
        }
        Tp[a * 256 + t] = sp;
        Tc[a * 256 + t] = sc;
    }
}

// ---------------------------------------------------------------------------
extern "C" void kernel_launch(void* const* d_in, const int* in_sizes, int n_in,
                              void* d_out, int out_size, void* d_ws, size_t ws_size,
                              hipStream_t stream)
{
    const int*   x          = (const int*)d_in[0];
    const int*   edge_index = (const int*)d_in[1];
    const int*   edge_attr  = (const int*)d_in[2];
    const int*   batch_vec  = (const int*)d_in[3];
    const float* emb_node   = (const float*)d_in[4];
    const float* Wn1 = (const float*)d_in[5];  const float* bn1 = (const float*)d_in[6];
    const float* Wn2 = (const float*)d_in[7];  const float* bn2 = (const float*)d_in[8];
    const float* emb_edge = (const float*)d_in[9];
    const float* We1 = (const float*)d_in[10]; const float* be1 = (const float*)d_in[11];
    const float* We2 = (const float*)d_in[12]; const float* be2 = (const float*)d_in[13];
    const float* Wp1 = (const float*)d_in[14]; const float* bp1 = (const float*)d_in[15];
    const float* Wp2 = (const float*)d_in[16]; const float* bp2 = (const float*)d_in[17];
    const float* Wp3 = (const float*)d_in[18]; const float* bp3 = (const float*)d_in[19];
    const float* Wc1 = (const float*)d_in[20]; const float* bc1 = (const float*)d_in[21];
    const float* Wc2 = (const float*)d_in[22]; const float* bc2 = (const float*)d_in[23];
    const float* Wc3 = (const float*)d_in[24]; const float* bc3 = (const float*)d_in[25];
    const float* Wf1 = (const float*)d_in[26]; const float* bf1 = (const float*)d_in[27];
    const float* Wf2 = (const float*)d_in[28]; const float* bf2 = (const float*)d_in[29];
    const float* Wf3 = (const float*)d_in[30]; const float* bf3 = (const float*)d_in[31];
    const float* Wo1 = (const float*)d_in[32]; const float* bo1 = (const float*)d_in[33];
    const float* Wo2 = (const float*)d_in[34]; const float* bo2 = (const float*)d_in[35];

    float* out = (float*)d_out;

    char* w = (char*)d_ws;
    auto alloc = [&](size_t bytes) { char* p = w; w += (bytes + 255) & ~(size_t)255; return p; };
    float* nodes   = (float*)alloc((size_t)NN * DD * 4);
    u16*   nodesbf = (u16*)  alloc((size_t)NN * DD * 2);
    float* fi      = (float*)alloc((size_t)NN * DD * 4);
    float* fo      = (float*)alloc((size_t)NN * DD * 4);   // contiguous after fi
    u16*   P       = (u16*)  alloc((size_t)NN * 512 * 2);
    u16*   h2      = (u16*)  alloc((size_t)NN * 384 * 2);
    float* Tp      = (float*)alloc(3 * 256 * 4);
    float* Tc      = (float*)alloc(3 * 256 * 4);
    uint4* frag    = (uint4*)alloc((size_t)126976 * 16);
    int* hist = (int*)alloc((size_t)2 * NBINS * 4);        // [dst | src]; src half = deg
    int* part = (int*)alloc((size_t)2 * NPART * 4);
    int* cur  = (int*)alloc((size_t)2 * NBINS * 4);
    int* sA   = (int*)alloc((size_t)2 * NE * 4);           // [parent | child]
    int* sB   = (int*)alloc((size_t)2 * NE * 4);
    int* sC   = (int*)alloc((size_t)2 * NE * 4);

    u16* He = h2;                      // [50k][128]
    u16* U1 = h2;                      // [50k][256]
    u16* U2 = h2 + (size_t)NN * 256;   // [50k][128]
    u16* Hout1 = P;                    // [50k][512]
    const int* degS = hist + NBINS;    // deg(src) as int

    uint4* Wn1f = frag;                // K256 N128
    uint4* Wn2f = Wn1f + 4096;         // K128 N128
    uint4* PWp  = Wn2f + 2048;         // K128 N512
    uint4* PWc  = PWp  + 8192;
    uint4* W2p  = PWc  + 8192;         // K256 N128
    uint4* W3p  = W2p  + 4096;         // K128 N128
    uint4* W2c  = W3p  + 2048;
    uint4* W3c  = W2c  + 4096;
    uint4* Wf1f = W3c  + 2048;         // K384 N256
    uint4* Wf2f = Wf1f + 12288;        // K256 N128
    uint4* Wf3f = Wf2f + 4096;         // K128 N128
    uint4* Wo1f = Wf3f + 2048;         // K128 N512
    uint4* Wo2f = Wo1f + 8192;         // K512 N1024

    const int* srcI = edge_index;
    const int* dstI = edge_index + NE;

    const int MB50 = (NN + 127) / 128;   // 391
    const int MBE  = (NE + 127) / 128;   // 1563

    // ---- prep --------------------------------------------------------------
    (void)hipMemsetAsync(d_out, 0, (size_t)out_size * 4, stream);
    (void)hipMemsetAsync(hist, 0, (size_t)2 * NBINS * 4, stream);

    PackPtrs pp;
    pp.p[0]=Wn1; pp.p[1]=Wn2; pp.p[2]=Wp1; pp.p[3]=Wc1; pp.p[4]=Wp2; pp.p[5]=Wp3;
    pp.p[6]=Wc2; pp.p[7]=Wc3; pp.p[8]=Wf1; pp.p[9]=Wf2; pp.p[10]=Wf3; pp.p[11]=Wo1; pp.p[12]=Wo2;
    pack_all<<<(126976 + 255) / 256, 256, 0, stream>>>(pp, frag);

    enc_tab_kernel<<<1, 256, 0, stream>>>(emb_edge, We1, be1, We2, be2,
                                          Wp1, bp1, Wc1, bc1, Tp, Tc);

    hist2_kernel<<<(2 * NE + 255) / 256, 256, 0, stream>>>(dstI, srcI, hist);
    chunk_sum<<<2 * NPART, 256, 0, stream>>>(hist, part);
    scan_part2<<<2, 256, 0, stream>>>(part);
    mk_cursor<<<2 * NPART, 256, 0, stream>>>(hist, part, cur);
    sort_scatter2<<<(2 * NE + 255) / 256, 256, 0, stream>>>(dstI, srcI, edge_attr, cur, sA, sB, sC);

    // ---- node encoder ------------------------------------------------------
    gemm_k<256, 1, 0, true, false, SrcEnc><<<MB50, 256, 0, stream>>>(
        SrcEnc{emb_node, x}, Wn1f, bn1, EpiArgs{nullptr, He, nullptr, 128}, NN);
    expand_k<128, 1, 1, true, 128><<<dim3(MB50, 1), 256, 0, stream>>>(
        He, Wn2f, bn2, nodes, nodesbf, nullptr, NN);

    // ---- message-passing iterations ---------------------------------------
    for (int it = 0; it < NITERS; ++it) {
        // parent: P-pass also zero-fills fi
        expand_k<128, 4, 0, false, 512><<<dim3(MB50, 4), 256, 0, stream>>>(
            nodesbf, PWp, nullptr, nullptr, P, fi, NN);
        edge_fused<<<MBE, 256, 0, stream>>>(P, Tp, W2p, bp2, W3p, bp3,
                                            sA, sB, sC, fi);

        // child: P-pass also zero-fills fo
        expand_k<128, 4, 0, false, 512><<<dim3(MB50, 4), 256, 0, stream>>>(
            nodesbf, PWc, nullptr, nullptr, P, fo, NN);
        edge_fused<<<MBE, 256, 0, stream>>>(P, Tc, W2c, bc2, W3c, bc3,
                                            sA + NE, sB + NE, sC + NE, fo);

        gemm_k<384, 2, 0, true, false, SrcUpd><<<MB50 * 2, 256, 0, stream>>>(
            SrcUpd{nodes, fi, fo, degS}, Wf1f, bf1, EpiArgs{nullptr, U1, nullptr, 256}, NN);
        expand_k<256, 1, 0, true, 128><<<dim3(MB50, 1), 256, 0, stream>>>(
            U1, Wf2f, bf2, nullptr, U2, nullptr, NN);
        expand_k<128, 1, 2, true, 128><<<dim3(MB50, 1), 256, 0, stream>>>(
            U2, Wf3f, bf3, nodes, nodesbf, nullptr, NN);
    }

    // ---- output head + global max pool -------------------------------------
    expand_k<128, 4, 0, true, 512><<<dim3(MB50, 4), 256, 0, stream>>>(
        nodesbf, Wo1f, bo1, nullptr, Hout1, nullptr, NN);
    gemm_k<512, 8, 3, true, true, SrcBf16><<<MB50 * 8, 256, 0, stream>>>(
        SrcBf16{Hout1, 512}, Wo2f, bo2, EpiArgs{out, nullptr, batch_vec, 1024}, NN);
}

// Round 12
// 903.866 us; speedup vs baseline: 1.0864x; 1.0093x over previous
//
#include <hip/hip_runtime.h>

#define NN 50000
#define NE 200000
#define DD 128
#define GG 256
#define NITERS 2
#define NBINS 50176          // 196 * 256, >= NN
#define NPART 196

typedef unsigned short u16;
typedef unsigned int u32;
typedef __bf16 bf16x8 __attribute__((ext_vector_type(8)));
typedef float f32x4 __attribute__((ext_vector_type(4)));

union U16x8 { uint4 u; bf16x8 v; u16 s[8]; };

__device__ __forceinline__ u16 f2b(float f) {             // f32 -> bf16 bits, RNE
    u32 u = __float_as_uint(f);
    return (u16)((u + 0x7FFFu + ((u >> 16) & 1u)) >> 16);
}
__device__ __forceinline__ float b2f(u16 s) { return __uint_as_float(((u32)s) << 16); }

__device__ __forceinline__ uint2 pack4(const float* v) {
    uint2 r;
    r.x = (u32)f2b(v[0]) | ((u32)f2b(v[1]) << 16);
    r.y = (u32)f2b(v[2]) | ((u32)f2b(v[3]) << 16);
    return r;
}

// async global -> LDS, 16B per lane; lds must be the wave-uniform base slot
__device__ __forceinline__ void gload_lds16(const void* g, void* lds) {
    __builtin_amdgcn_global_load_lds((const __attribute__((address_space(1))) void*)g,
                                     (__attribute__((address_space(3))) void*)lds, 16, 0, 0);
}

// XCD-chunked bijective block swizzle (m204 form)
__device__ __forceinline__ int xcd_swz(int orig, int nwg) {
    int q = nwg >> 3, r = nwg & 7;
    int x = orig & 7, loc = orig >> 3;
    return (x < r ? x * (q + 1) : r * (q + 1) + (x - r) * q) + loc;
}

// ---------------------------------------------------------------------------
// expand_k: OUT[128 rows][cols c*128..] = epi(A[128][K] @ W + bias), c = blockIdx.y
// A staged ONCE in LDS (only used with K=128 -> 32 KB); W fragments per-lane
// direct; swapped MFMA -> thread owns 4 consecutive out-cols of one row.
// EPI: 0 = bf16 store (ob, ldN=LDN); 1 = f32 of + bf16 ob (LDN=128);
//      2 = residual: of += , ob mirror (LDN=128).
// zf: optional f32 [M][128] buffer to zero-fill (block zeroes its slice).
// ---------------------------------------------------------------------------
template<int K, int NL, int EPI, bool RELU, int LDN>
__global__ __launch_bounds__(256) void expand_k(
    const u16* __restrict__ A, const uint4* __restrict__ wfrag,
    const float* __restrict__ bias, float* __restrict__ of, u16* __restrict__ ob,
    float* __restrict__ zf, int M)
{
    constexpr int KS = K / 32;
    __shared__ uint4 smem[K * 16];
    const int t = threadIdx.x, l = t & 63, wv = t >> 6;
    const int mh = wv >> 1, nh = wv & 1;
    const int mblk = blockIdx.x;
    const int c = blockIdx.y;

    #pragma unroll
    for (int i = 0; i < K / 16; ++i) {           // stage A once
        int s = t + 256 * i;
        int ln = s & 63, mt = (s >> 6) & 7, ksl = s >> 9;
        int row = mblk * 128 + mt * 16 + (ln & 15);
        if (row >= M) row = M - 1;
        int kk = ksl * 32 + (ln >> 4) * 8;
        gload_lds16(A + (size_t)row * K + kk, &smem[s - ln]);
    }
    if (zf) {                                    // zero-fill slice (overlaps staging)
        #pragma unroll
        for (int i = 0; i < 4; ++i) {
            int f = t + 256 * i;                 // float4 idx in [0,1024)
            int row = f >> 3, c4 = f & 7;
            int grow = mblk * 128 + row;
            if (grow < M) {
                float4 z; z.x = 0.f; z.y = 0.f; z.z = 0.f; z.w = 0.f;
                *(float4*)(zf + (size_t)grow * 128 + c * 32 + c4 * 4) = z;
            }
        }
    }
    __syncthreads();

    f32x4 acc[4][4] = {};
    #pragma unroll
    for (int ksl = 0; ksl < KS; ++ksl) {
        uint4 wa[4];
        #pragma unroll
        for (int mi = 0; mi < 4; ++mi)
            wa[mi] = wfrag[(size_t)((c * KS + ksl) * 8 + mh * 4 + mi) * 64 + l];
        bf16x8 bn[4];
        #pragma unroll
        for (int ni = 0; ni < 4; ++ni) { U16x8 u; u.u = smem[(ksl * 8 + nh * 4 + ni) * 64 + l]; bn[ni] = u.v; }
        #pragma unroll
        for (int mi = 0; mi < 4; ++mi) {
            U16x8 u; u.u = wa[mi];
            #pragma unroll
            for (int ni = 0; ni < 4; ++ni)
                acc[mi][ni] = __builtin_amdgcn_mfma_f32_16x16x32_bf16(u.v, bn[ni], acc[mi][ni], 0, 0, 0);
        }
    }
    float4 bb[4];
    #pragma unroll
    for (int mi = 0; mi < 4; ++mi) {
        if (bias) bb[mi] = *(const float4*)(bias + c * 128 + mh * 64 + mi * 16 + 4 * (l >> 4));
        else { bb[mi].x = 0.f; bb[mi].y = 0.f; bb[mi].z = 0.f; bb[mi].w = 0.f; }
    }
    #pragma unroll
    for (int ni = 0; ni < 4; ++ni) {
        int node = mblk * 128 + nh * 64 + ni * 16 + (l & 15);
        if (node >= M) continue;
        #pragma unroll
        for (int mi = 0; mi < 4; ++mi) {
            int col = c * 128 + mh * 64 + mi * 16 + 4 * (l >> 4);
            float v[4];
            const float* bf = &bb[mi].x;
            #pragma unroll
            for (int r = 0; r < 4; ++r) {
                v[r] = acc[mi][ni][r] + bf[r];
                if (RELU) v[r] = fmaxf(v[r], 0.f);
            }
            if (EPI == 0) {
                *(uint2*)(ob + (size_t)node * LDN + col) = pack4(v);
            } else {
                size_t a = (size_t)node * 128 + col;
                if (EPI == 2) {
                    float4 old = *(const float4*)(of + a);
                    v[0] += old.x; v[1] += old.y; v[2] += old.z; v[3] += old.w;
                }
                float4 s4; s4.x = v[0]; s4.y = v[1]; s4.z = v[2]; s4.w = v[3];
                *(float4*)(of + a) = s4;
                *(uint2*)(ob + a) = pack4(v);
            }
        }
    }
}

// ---------------------------------------------------------------------------
// Source functors for A-operand staging (gemm_k).
// ---------------------------------------------------------------------------
struct SrcBf16 {            // plain bf16 row-major [M][K], async-staged
    static constexpr bool DIRECT = true;
    const u16* A; int K;
    __device__ const void* gaddr(int row, int kk) const { return A + (size_t)row * K + kk; }
    __device__ bf16x8 operator()(int row, int kk) const {
        U16x8 u; u.u = *(const uint4*)(A + (size_t)row * K + kk); return u.v;
    }
};
struct SrcEnc {             // node encoder input: emb_node[x[row]] (f32 -> bf16)
    static constexpr bool DIRECT = false;
    const float* emb; const int* xids;
    __device__ const void* gaddr(int, int) const { return nullptr; }
    __device__ bf16x8 operator()(int row, int kk) const {
        int n = xids[row];
        const float* p = emb + (size_t)n * 256 + kk;
        float4 f0 = *(const float4*)p, f1 = *(const float4*)(p + 4);
        U16x8 r;
        r.s[0]=f2b(f0.x); r.s[1]=f2b(f0.y); r.s[2]=f2b(f0.z); r.s[3]=f2b(f0.w);
        r.s[4]=f2b(f1.x); r.s[5]=f2b(f1.y); r.s[6]=f2b(f1.z); r.s[7]=f2b(f1.w);
        return r.v;
    }
};
struct SrcUpd {             // [nodes | fi/deg | fo/deg] (f32 -> bf16), K=384
    static constexpr bool DIRECT = false;
    const float* nodes; const float* fi; const float* fo; const int* deg;
    __device__ const void* gaddr(int, int) const { return nullptr; }
    __device__ bf16x8 operator()(int row, int kk) const {
        const float* s; float sc = 1.f;
        if (kk < 128) s = nodes + (size_t)row * 128 + kk;
        else {
            int d = deg[row];
            sc = d > 0 ? 1.f / (float)d : 0.f;
            s = (kk < 256) ? fi + (size_t)row * 128 + (kk - 128)
                           : fo + (size_t)row * 128 + (kk - 256);
        }
        float4 f0 = *(const float4*)s, f1 = *(const float4*)(s + 4);
        U16x8 r;
        r.s[0]=f2b(f0.x*sc); r.s[1]=f2b(f0.y*sc); r.s[2]=f2b(f0.z*sc); r.s[3]=f2b(f0.w*sc);
        r.s[4]=f2b(f1.x*sc); r.s[5]=f2b(f1.y*sc); r.s[6]=f2b(f1.z*sc); r.s[7]=f2b(f1.w*sc);
        return r.v;
    }
};

struct EpiArgs { float* of; u16* ob; const int* idx; int ldN; };

// ---------------------------------------------------------------------------
// gemm_k: non-swapped MFMA (C rows register-resident); A + W staged to LDS
// (async for DIRECT sources). EPI0: bf16 store via swizzled LDS bounce.
// EPI3: segment-max by sorted idx; ni-outer merge over 16 (mi,r) rows.
// ---------------------------------------------------------------------------
template<int KDIM, int NBLK, int EPI, bool RELU, class SRC>
__global__ __launch_bounds__(256) void gemm_k(SRC src, const uint4* __restrict__ wfrag,
                                              const float* __restrict__ bias,
                                              EpiArgs ea, int M)
{
    constexpr int KS = KDIM / 32;
    constexpr int NPANEL = KDIM / 64;
    __shared__ uint4 smem[2048];
    const int t = threadIdx.x;
    const int l = t & 63;
    const int wv = t >> 6;
    const int mh = wv >> 1, nh = wv & 1;
    const int ell = xcd_swz(blockIdx.x, gridDim.x);
    const int mblk = ell / NBLK, nblk = ell % NBLK;

    f32x4 acc[4][4] = {};

    for (int p = 0; p < NPANEL; ++p) {
        __syncthreads();
        if constexpr (SRC::DIRECT) {
            #pragma unroll
            for (int i = 0; i < 4; ++i) {          // async A panel
                int s = t + 256 * i;
                int ln = s & 63, mt = (s >> 6) & 7, ksl = s >> 9;
                int row = mblk * 128 + mt * 16 + (ln & 15);
                if (row >= M) row = M - 1;
                int kk = p * 64 + ksl * 32 + (ln >> 4) * 8;
                gload_lds16(src.gaddr(row, kk), &smem[s - ln]);
            }
        } else {
            #pragma unroll
            for (int i = 0; i < 4; ++i) {          // computed A panel
                int s = t + 256 * i;
                int ln = s & 63, mt = (s >> 6) & 7, ksl = s >> 9;
                int row = mblk * 128 + mt * 16 + (ln & 15);
                if (row >= M) row = M - 1;
                int kk = p * 64 + ksl * 32 + (ln >> 4) * 8;
                U16x8 u; u.v = src(row, kk);
                smem[s] = u.u;
            }
        }
        {                                           // async W panel
            const uint4* wp = wfrag + (size_t)(nblk * KS + 2 * p) * 512;
            #pragma unroll
            for (int i = 0; i < 4; ++i) {
                int s = t + 256 * i;
                gload_lds16(wp + s, &smem[1024 + (s - (s & 63))]);
            }
        }
        __syncthreads();
        #pragma unroll
        for (int ksl = 0; ksl < 2; ++ksl) {
            bf16x8 a[4], b[4];
            #pragma unroll
            for (int mi = 0; mi < 4; ++mi) { U16x8 u; u.u = smem[(ksl*8 + mh*4 + mi)*64 + l]; a[mi] = u.v; }
            #pragma unroll
            for (int ni = 0; ni < 4; ++ni) { U16x8 u; u.u = smem[1024 + (ksl*8 + nh*4 + ni)*64 + l]; b[ni] = u.v; }
            #pragma unroll
            for (int mi = 0; mi < 4; ++mi)
                #pragma unroll
                for (int ni = 0; ni < 4; ++ni)
                    acc[mi][ni] = __builtin_amdgcn_mfma_f32_16x16x32_bf16(a[mi], b[ni], acc[mi][ni], 0, 0, 0);
        }
    }

    float bcol[4];
    #pragma unroll
    for (int ni = 0; ni < 4; ++ni)
        bcol[ni] = bias ? bias[nblk * 128 + nh * 64 + ni * 16 + (l & 15)] : 0.f;

    if constexpr (EPI == 0) {
        // bf16 store via XOR-swizzled LDS bounce
        __syncthreads();
        u16* bn = (u16*)smem;
        #pragma unroll
        for (int mi = 0; mi < 4; ++mi)
            #pragma unroll
            for (int ni = 0; ni < 4; ++ni)
                #pragma unroll
                for (int r = 0; r < 4; ++r) {
                    int rl = mh * 64 + mi * 16 + (l >> 4) * 4 + r;
                    int cl = nh * 64 + ni * 16 + (l & 15);
                    float v = acc[mi][ni][r] + bcol[ni];
                    if (RELU) v = fmaxf(v, 0.f);
                    int sx = (rl >> 2) & 7;
                    bn[rl * 128 + ((((cl >> 3) ^ sx)) << 3) + (cl & 7)] = f2b(v);
                }
        __syncthreads();
        int row = t >> 1, half = t & 1;
        int grow = mblk * 128 + row;
        if (grow < M) {
            int sx = (row >> 2) & 7;
            uint4* dst = (uint4*)(ea.ob + (size_t)grow * ea.ldN + nblk * 128 + half * 64);
            const uint4* sp = ((const uint4*)bn) + row * 16;
            #pragma unroll
            for (int i = 0; i < 8; ++i) dst[i] = sp[(half * 8 + i) ^ sx];
        }
    } else if constexpr (EPI == 3) {
        // segment-max: batch ids for this lane's 16 rows (within 64-row window)
        int g16[4][4];
        #pragma unroll
        for (int mi = 0; mi < 4; ++mi) {
            int rb = mblk * 128 + mh * 64 + mi * 16 + (l >> 4) * 4;
            #pragma unroll
            for (int r = 0; r < 4; ++r)
                g16[mi][r] = (rb + r < M) ? ea.idx[rb + r] : -1;
        }
        #pragma unroll
        for (int ni = 0; ni < 4; ++ni) {
            int colg = nblk * 128 + nh * 64 + ni * 16 + (l & 15);
            float mv = 0.f; int cg = -1;
            #pragma unroll
            for (int mi = 0; mi < 4; ++mi)
                #pragma unroll
                for (int r = 0; r < 4; ++r) {
                    float v = acc[mi][ni][r] + bcol[ni];
                    if (RELU) v = fmaxf(v, 0.f);
                    int g = g16[mi][r];
                    if (g != cg) {
                        if (cg >= 0) atomicMax((u32*)(ea.of + (size_t)cg * 1024 + colg), __float_as_uint(mv));
                        cg = g; mv = v;
                    } else mv = fmaxf(mv, v);
                }
            if (cg >= 0) atomicMax((u32*)(ea.of + (size_t)cg * 1024 + colg), __float_as_uint(mv));
        }
    }
}

// ---------------------------------------------------------------------------
// Fused per-edge pipeline (edges pre-sorted by idxA) — unchanged.
// ---------------------------------------------------------------------------
__global__ __launch_bounds__(256) void edge_fused(
    const u16* __restrict__ P, const float* __restrict__ T,
    const uint4* __restrict__ W2f, const float* __restrict__ b2,
    const uint4* __restrict__ W3f, const float* __restrict__ b3,
    const int* __restrict__ idxA, const int* __restrict__ idxB,
    const int* __restrict__ eattr, float* __restrict__ agg)
{
    __shared__ uint4 smA[2048];
    __shared__ int   sidx[3][128];
    __shared__ float sT[768];
    const int t = threadIdx.x;
    const int l = t & 63;
    const int wv = t >> 6;
    const int mh = wv >> 1, nh = wv & 1;
    const int base = xcd_swz(blockIdx.x, gridDim.x) * 128;

    if (t < 128) {
        int e = (base + t < NE) ? base + t : NE - 1;
        sidx[0][t] = idxA[e];
        sidx[1][t] = idxB[e];
        sidx[2][t] = eattr[e];
    }
    for (int i = t; i < 768; i += 256) sT[i] = T[i];
    __syncthreads();

    const int rt0 = wv * 16 + (l & 15);
    const int rt1 = (wv + 4) * 16 + (l & 15);
    const int klo = (l >> 4) * 8;
    const u16* pA[2] = { P + (size_t)sidx[0][rt0] * 512, P + (size_t)sidx[0][rt1] * 512 };
    const u16* pB[2] = { P + (size_t)sidx[1][rt0] * 512 + 256, P + (size_t)sidx[1][rt1] * 512 + 256 };
    const float* pT[2] = { sT + sidx[2][rt0] * 256, sT + sidx[2][rt1] * 256 };

    uint4 ra[4], rb[4];
    #pragma unroll
    for (int i = 0; i < 4; ++i) {
        int kk = (i >> 1) * 32 + klo;
        ra[i] = *(const uint4*)(pA[i & 1] + kk);
        rb[i] = *(const uint4*)(pB[i & 1] + kk);
    }

    f32x4 acc[4][4] = {};
    #pragma unroll
    for (int p = 0; p < 4; ++p) {
        #pragma unroll
        for (int i = 0; i < 4; ++i) {
            int kk = (i >> 1) * 32 + klo;
            U16x8 ua, ub, r;
            ua.u = ra[i]; ub.u = rb[i];
            const float* tb = pT[i & 1] + p * 64 + kk;
            #pragma unroll
            for (int j = 0; j < 8; ++j) {
                float v = b2f(ua.s[j]) + b2f(ub.s[j]) + tb[j];
                r.s[j] = f2b(fmaxf(v, 0.f));
            }
            smA[(p & 1) * 1024 + t + 256 * i] = r.u;
            if (p < 3) {
                int kn = (p + 1) * 64 + kk;
                ra[i] = *(const uint4*)(pA[i & 1] + kn);
                rb[i] = *(const uint4*)(pB[i & 1] + kn);
            }
        }
        asm volatile("s_waitcnt lgkmcnt(0)" ::: "memory");
        __builtin_amdgcn_s_barrier();
        uint4 bw[2][4];
        #pragma unroll
        for (int ksl = 0; ksl < 2; ++ksl)
            #pragma unroll
            for (int ni = 0; ni < 4; ++ni)
                bw[ksl][ni] = W2f[(size_t)((p * 2 + ksl) * 8 + nh * 4 + ni) * 64 + l];
        #pragma unroll
        for (int ksl = 0; ksl < 2; ++ksl) {
            bf16x8 a[4];
            #pragma unroll
            for (int mi = 0; mi < 4; ++mi) { U16x8 u; u.u = smA[(p & 1) * 1024 + (ksl*8 + mh*4 + mi)*64 + l]; a[mi] = u.v; }
            #pragma unroll
            for (int mi = 0; mi < 4; ++mi)
                #pragma unroll
                for (int ni = 0; ni < 4; ++ni) {
                    U16x8 u; u.u = bw[ksl][ni];
                    acc[mi][ni] = __builtin_amdgcn_mfma_f32_16x16x32_bf16(a[mi], u.v, acc[mi][ni], 0, 0, 0);
                }
        }
    }

    float bc2[4];
    #pragma unroll
    for (int ni = 0; ni < 4; ++ni) bc2[ni] = b2[nh * 64 + ni * 16 + (l & 15)];
    __builtin_amdgcn_s_barrier();
    u16* bn = (u16*)smA;
    #pragma unroll
    for (int mi = 0; mi < 4; ++mi)
        #pragma unroll
        for (int ni = 0; ni < 4; ++ni)
            #pragma unroll
            for (int r = 0; r < 4; ++r) {
                int rl = mh * 64 + mi * 16 + (l >> 4) * 4 + r;
                int cl = nh * 64 + ni * 16 + (l & 15);
                float v = fmaxf(acc[mi][ni][r] + bc2[ni], 0.f);
                int sx = (rl >> 2) & 7;
                bn[rl * 128 + (((cl >> 3) ^ sx) << 3) + (cl & 7)] = f2b(v);
            }
    asm volatile("s_waitcnt lgkmcnt(0)" ::: "memory");
    __builtin_amdgcn_s_barrier();

    f32x4 acc2[4][4] = {};
    #pragma unroll
    for (int ks = 0; ks < 4; ++ks) {
        uint4 bw[4];
        #pragma unroll
        for (int ni = 0; ni < 4; ++ni)
            bw[ni] = W3f[(size_t)(ks * 8 + nh * 4 + ni) * 64 + l];
        bf16x8 a[4];
        #pragma unroll
        for (int mi = 0; mi < 4; ++mi) {
            int rl = (mh * 4 + mi) * 16 + (l & 15);
            int c0 = ks * 32 + (l >> 4) * 8;
            int sx = (rl >> 2) & 7;
            U16x8 u; u.u = *(const uint4*)&bn[rl * 128 + (((c0 >> 3) ^ sx) << 3)];
            a[mi] = u.v;
        }
        #pragma unroll
        for (int mi = 0; mi < 4; ++mi)
            #pragma unroll
            for (int ni = 0; ni < 4; ++ni) {
                U16x8 u; u.u = bw[ni];
                acc2[mi][ni] = __builtin_amdgcn_mfma_f32_16x16x32_bf16(a[mi], u.v, acc2[mi][ni], 0, 0, 0);
            }
    }

    float bc3[4];
    #pragma unroll
    for (int ni = 0; ni < 4; ++ni) bc3[ni] = b3[nh * 64 + ni * 16 + (l & 15)];
    #pragma unroll
    for (int mi = 0; mi < 4; ++mi) {
        int rt4 = mh * 64 + mi * 16 + (l >> 4) * 4;
        int nd[4];
        #pragma unroll
        for (int r = 0; r < 4; ++r)
            nd[r] = (base + rt4 + r < NE) ? sidx[0][rt4 + r] : -1;
        #pragma unroll
        for (int ni = 0; ni < 4; ++ni) {
            int col = nh * 64 + ni * 16 + (l & 15);
            float mv = 0.f; int cg = -1;
            #pragma unroll
            for (int r = 0; r < 4; ++r) {
                float v = fmaxf(acc2[mi][ni][r] + bc3[ni], 0.f);
                if (nd[r] != cg) {
                    if (cg >= 0) atomicAdd(agg + (size_t)cg * 128 + col, mv);
                    cg = nd[r]; mv = v;
                } else mv += v;
            }
            if (cg >= 0) atomicAdd(agg + (size_t)cg * 128 + col, mv);
        }
    }
}

// ---------------------------------------------------------------------------
// Fused counting sort, both keys (parent=dst, child=src) in single launches.
// ---------------------------------------------------------------------------
__global__ void hist2_kernel(const int* __restrict__ dstI, const int* __restrict__ srcI,
                             int* __restrict__ hist)
{
    int i = blockIdx.x * 256 + threadIdx.x;
    if (i < NE) atomicAdd(&hist[dstI[i]], 1);
    else if (i < 2 * NE) atomicAdd(&hist[NBINS + srcI[i - NE]], 1);
}
__global__ void chunk_sum(const int* __restrict__ h, int* __restrict__ part)
{
    __shared__ int sh[256];
    int t = threadIdx.x, b = blockIdx.x;       // b in [0, 2*NPART)
    sh[t] = h[b * 256 + t];
    __syncthreads();
    for (int o = 128; o > 0; o >>= 1) { if (t < o) sh[t] += sh[t + o]; __syncthreads(); }
    if (t == 0) part[b] = sh[0];
}
__global__ void scan_part2(int* part)          // 2 blocks; per-half exclusive scan
{
    __shared__ int sh[256];
    int t = threadIdx.x, b = blockIdx.x;
    int* p = part + b * NPART;
    sh[t] = (t < NPART) ? p[t] : 0;
    __syncthreads();
    for (int o = 1; o < 256; o <<= 1) {
        int x = (t >= o) ? sh[t - o] : 0;
        __syncthreads(); sh[t] += x; __syncthreads();
    }
    if (t < NPART) p[t] = (t ? sh[t - 1] : 0) + b * NE;   // child half biased by NE
}
__global__ void mk_cursor(const int* __restrict__ h, const int* __restrict__ part,
                          int* __restrict__ cur)
{
    __shared__ int sh[256];
    int t = threadIdx.x, b = blockIdx.x;       // b in [0, 2*NPART)
    int v = h[b * 256 + t];
    sh[t] = v;
    __syncthreads();
    for (int o = 1; o < 256; o <<= 1) {
        int x = (t >= o) ? sh[t - o] : 0;
        __syncthreads(); sh[t] += x; __syncthreads();
    }
    cur[b * 256 + t] = part[b] + sh[t] - v;
}
__global__ void sort_scatter2(const int* __restrict__ dstI, const int* __restrict__ srcI,
                              const int* __restrict__ at, int* __restrict__ cur,
                              int* __restrict__ oA, int* __restrict__ oB, int* __restrict__ oC)
{
    int i = blockIdx.x * 256 + threadIdx.x;
    if (i < NE) {
        int k = dstI[i];
        int p = atomicAdd(&cur[k], 1);
        oA[p] = k; oB[p] = srcI[i]; oC[p] = at[i];
    } else if (i < 2 * NE) {
        int e = i - NE;
        int k = srcI[e];
        int p = atomicAdd(&cur[NBINS + k], 1);   // cursor pre-biased by NE
        oA[p] = k; oB[p] = dstI[e]; oC[p] = at[e];
    }
}

// ---------------------------------------------------------------------------
// Mega weight packer: all 15 pack jobs in one launch (constexpr job table).
// ---------------------------------------------------------------------------
struct PackPtrs { const float* p[13]; };

__global__ void pack_all(PackPtrs pp, uint4* __restrict__ frag)
{
    int tid = blockIdx.x * 256 + threadIdx.x;
    if (tid >= 126976) return;
    constexpr int NJ = 15;
    const int   start[NJ] = {0,4096,6144,10240,14336,18432,22528,26624,28672,32768,34816,47104,51200,53248,61440};
    const int   fbase[NJ] = {0,4096,6144,6144,14336,14336,22528,26624,28672,32768,34816,47104,51200,53248,61440};
    const short wsel [NJ] = {0,1,2,2,3,3,4,5,6,7,8,9,10,11,12};
    const short ldt  [NJ] = {128,128,256,256,256,256,128,128,128,128,256,128,128,512,1024};
    const short rot  [NJ] = {0,0,0,128,0,128,0,0,0,0,0,0,0,0,0};
    const short cot  [NJ] = {0,0,0,-256,0,-256,0,0,0,0,0,0,0,0,0};
    const short nbst [NJ] = {0,0,0,2,0,2,0,0,0,0,0,0,0,0,0};
    const short kst  [NJ] = {8,4,4,4,4,4,8,4,8,4,12,8,4,4,16};
    int j = 0;
    for (int i = NJ - 1; i >= 1; --i) if (tid >= start[i]) { j = i; break; }
    int rem = tid - start[j];
    int KS = kst[j];
    int nbrel = rem / (KS * 512);
    int r1 = rem % (KS * 512);
    int ks = r1 >> 9;
    int r2 = r1 & 511;
    int nt = r2 >> 6, l = r2 & 63;
    int nb = nbst[j] + nbrel;
    int k  = ks * 32 + (l >> 4) * 8;
    int ld = ldt[j];
    int col = nb * 128 + nt * 16 + (l & 15) + cot[j];
    const float* W = pp.p[wsel[j]];
    U16x8 u;
    #pragma unroll
    for (int jj = 0; jj < 8; ++jj) u.s[jj] = f2b(W[(size_t)(rot[j] + k + jj) * ld + col]);
    frag[fbase[j] + ((size_t)(nb * KS + ks) * 8 + nt) * 64 + l] = u.u;
}

// ---------------------------------------------------------------------------
// Edge-type tables, fused.
// ---------------------------------------------------------------------------
__global__ void enc_tab_kernel(const float* __restrict__ emb_edge,
                               const float* __restrict__ We1, const float* __restrict__ be1,
                               const float* __restrict__ We2, const float* __restrict__ be2,
                               const float* __restrict__ Wp1, const float* __restrict__ bp1,
                               const float* __restrict__ Wc1, const float* __restrict__ bc1,
                               float* __restrict__ Tp, float* __restrict__ Tc)
{
    __shared__ float h1[3][128];
    __shared__ float ea[3][128];
    const int t = threadIdx.x;   // 256
    if (t < 128) {
        for (int a = 0; a < 3; ++a) {
            float s = be1[t];
            for (int k = 0; k < 256; ++k) s = fmaf(emb_edge[a * 256 + k], We1[k * 128 + t], s);
            h1[a][t] = fmaxf(s, 0.f);
        }
    }
    __syncthreads();
    if (t < 128) {
        for (int a = 0; a < 3; ++a) {
            float s = be2[t];
            for (int k = 0; k < 128; ++k) s = fmaf(h1[a][k], We2[k * 128 + t], s);
            ea[a][t] = fmaxf(s, 0.f);
        }
    }
    __syncthreads();
    for (int a = 0; a < 3; ++a) {
        float sp = bp1[t], sc = bc1[t];
        for (int k = 0; k < 128; ++k) {
            float e = ea[a][k];
            sp = fmaf(e, Wp1[(size_t)(256 + k) * 256 + t], sp);
            sc = fmaf(e, Wc1[(size_t)(256 + k) * 256 + t], sc);
        }
        Tp[a * 256 + t] = sp;
        Tc[a * 256 + t] = sc;
    }
}

// ---------------------------------------------------------------------------
extern "C" void kernel_launch(void* const* d_in, const int* in_sizes, int n_in,
                              void* d_out, int out_size, void* d_ws, size_t ws_size,
                              hipStream_t stream)
{
    const int*   x          = (const int*)d_in[0];
    const int*   edge_index = (const int*)d_in[1];
    const int*   edge_attr  = (const int*)d_in[2];
    const int*   batch_vec  = (const int*)d_in[3];
    const float* emb_node   = (const float*)d_in[4];
    const float* Wn1 = (const float*)d_in[5];  const float* bn1 = (const float*)d_in[6];
    const float* Wn2 = (const float*)d_in[7];  const float* bn2 = (const float*)d_in[8];
    const float* emb_edge = (const float*)d_in[9];
    const float* We1 = (const float*)d_in[10]; const float* be1 = (const float*)d_in[11];
    const float* We2 = (const float*)d_in[12]; const float* be2 = (const float*)d_in[13];
    const float* Wp1 = (const float*)d_in[14]; const float* bp1 = (const float*)d_in[15];
    const float* Wp2 = (const float*)d_in[16]; const float* bp2 = (const float*)d_in[17];
    const float* Wp3 = (const float*)d_in[18]; const float* bp3 = (const float*)d_in[19];
    const float* Wc1 = (const float*)d_in[20]; const float* bc1 = (const float*)d_in[21];
    const float* Wc2 = (const float*)d_in[22]; const float* bc2 = (const float*)d_in[23];
    const float* Wc3 = (const float*)d_in[24]; const float* bc3 = (const float*)d_in[25];
    const float* Wf1 = (const float*)d_in[26]; const float* bf1 = (const float*)d_in[27];
    const float* Wf2 = (const float*)d_in[28]; const float* bf2 = (const float*)d_in[29];
    const float* Wf3 = (const float*)d_in[30]; const float* bf3 = (const float*)d_in[31];
    const float* Wo1 = (const float*)d_in[32]; const float* bo1 = (const float*)d_in[33];
    const float* Wo2 = (const float*)d_in[34]; const float* bo2 = (const float*)d_in[35];

    float* out = (float*)d_out;

    char* w = (char*)d_ws;
    auto alloc = [&](size_t bytes) { char* p = w; w += (bytes + 255) & ~(size_t)255; return p; };
    float* nodes   = (float*)alloc((size_t)NN * DD * 4);
    u16*   nodesbf = (u16*)  alloc((size_t)NN * DD * 2);
    float* fi      = (float*)alloc((size_t)NN * DD * 4);
    float* fo      = (float*)alloc((size_t)NN * DD * 4);   // contiguous after fi
    u16*   P       = (u16*)  alloc((size_t)NN * 512 * 2);
    u16*   h2      = (u16*)  alloc((size_t)NN * 384 * 2);
    float* Tp      = (float*)alloc(3 * 256 * 4);
    float* Tc      = (float*)alloc(3 * 256 * 4);
    uint4* frag    = (uint4*)alloc((size_t)126976 * 16);
    int* hist = (int*)alloc((size_t)2 * NBINS * 4);        // [dst | src]; src half = deg
    int* part = (int*)alloc((size_t)2 * NPART * 4);
    int* cur  = (int*)alloc((size_t)2 * NBINS * 4);
    int* sA   = (int*)alloc((size_t)2 * NE * 4);           // [parent | child]
    int* sB   = (int*)alloc((size_t)2 * NE * 4);
    int* sC   = (int*)alloc((size_t)2 * NE * 4);

    u16* He = h2;                      // [50k][128]
    u16* U1 = h2;                      // [50k][256]
    u16* U2 = h2 + (size_t)NN * 256;   // [50k][128]
    u16* Hout1 = P;                    // [50k][512]
    const int* degS = hist + NBINS;    // deg(src) as int

    uint4* Wn1f = frag;                // K256 N128
    uint4* Wn2f = Wn1f + 4096;         // K128 N128
    uint4* PWp  = Wn2f + 2048;         // K128 N512
    uint4* PWc  = PWp  + 8192;
    uint4* W2p  = PWc  + 8192;         // K256 N128
    uint4* W3p  = W2p  + 4096;         // K128 N128
    uint4* W2c  = W3p  + 2048;
    uint4* W3c  = W2c  + 4096;
    uint4* Wf1f = W3c  + 2048;         // K384 N256
    uint4* Wf2f = Wf1f + 12288;        // K256 N128
    uint4* Wf3f = Wf2f + 4096;         // K128 N128
    uint4* Wo1f = Wf3f + 2048;         // K128 N512
    uint4* Wo2f = Wo1f + 8192;         // K512 N1024

    const int* srcI = edge_index;
    const int* dstI = edge_index + NE;

    const int MB50 = (NN + 127) / 128;   // 391
    const int MBE  = (NE + 127) / 128;   // 1563

    // ---- prep --------------------------------------------------------------
    (void)hipMemsetAsync(d_out, 0, (size_t)out_size * 4, stream);
    (void)hipMemsetAsync(hist, 0, (size_t)2 * NBINS * 4, stream);

    PackPtrs pp;
    pp.p[0]=Wn1; pp.p[1]=Wn2; pp.p[2]=Wp1; pp.p[3]=Wc1; pp.p[4]=Wp2; pp.p[5]=Wp3;
    pp.p[6]=Wc2; pp.p[7]=Wc3; pp.p[8]=Wf1; pp.p[9]=Wf2; pp.p[10]=Wf3; pp.p[11]=Wo1; pp.p[12]=Wo2;
    pack_all<<<(126976 + 255) / 256, 256, 0, stream>>>(pp, frag);

    enc_tab_kernel<<<1, 256, 0, stream>>>(emb_edge, We1, be1, We2, be2,
                                          Wp1, bp1, Wc1, bc1, Tp, Tc);

    hist2_kernel<<<(2 * NE + 255) / 256, 256, 0, stream>>>(dstI, srcI, hist);
    chunk_sum<<<2 * NPART, 256, 0, stream>>>(hist, part);
    scan_part2<<<2, 256, 0, stream>>>(part);
    mk_cursor<<<2 * NPART, 256, 0, stream>>>(hist, part, cur);
    sort_scatter2<<<(2 * NE + 255) / 256, 256, 0, stream>>>(dstI, srcI, edge_attr, cur, sA, sB, sC);

    // ---- node encoder ------------------------------------------------------
    gemm_k<256, 1, 0, true, SrcEnc><<<MB50, 256, 0, stream>>>(
        SrcEnc{emb_node, x}, Wn1f, bn1, EpiArgs{nullptr, He, nullptr, 128}, NN);
    expand_k<128, 1, 1, true, 128><<<dim3(MB50, 1), 256, 0, stream>>>(
        He, Wn2f, bn2, nodes, nodesbf, nullptr, NN);

    // ---- message-passing iterations ---------------------------------------
    for (int it = 0; it < NITERS; ++it) {
        // parent: P-pass also zero-fills fi
        expand_k<128, 4, 0, false, 512><<<dim3(MB50, 4), 256, 0, stream>>>(
            nodesbf, PWp, nullptr, nullptr, P, fi, NN);
        edge_fused<<<MBE, 256, 0, stream>>>(P, Tp, W2p, bp2, W3p, bp3,
                                            sA, sB, sC, fi);

        // child: P-pass also zero-fills fo
        expand_k<128, 4, 0, false, 512><<<dim3(MB50, 4), 256, 0, stream>>>(
            nodesbf, PWc, nullptr, nullptr, P, fo, NN);
        edge_fused<<<MBE, 256, 0, stream>>>(P, Tc, W2c, bc2, W3c, bc3,
                                            sA + NE, sB + NE, sC + NE, fo);

        gemm_k<384, 2, 0, true, SrcUpd><<<MB50 * 2, 256, 0, stream>>>(
            SrcUpd{nodes, fi, fo, degS}, Wf1f, bf1, EpiArgs{nullptr, U1, nullptr, 256}, NN);
        gemm_k<256, 1, 0, true, SrcBf16><<<MB50, 256, 0, stream>>>(
            SrcBf16{U1, 256}, Wf2f, bf2, EpiArgs{nullptr, U2, nullptr, 128}, NN);
        expand_k<128, 1, 2, true, 128><<<dim3(MB50, 1), 256, 0, stream>>>(
            U2, Wf3f, bf3, nodes, nodesbf, nullptr, NN);
    }

    // ---- output head + global max pool -------------------------------------
    expand_k<128, 4, 0, true, 512><<<dim3(MB50, 4), 256, 0, stream>>>(
        nodesbf, Wo1f, bo1, nullptr, Hout1, nullptr, NN);
    gemm_k<512, 8, 3, true, SrcBf16><<<MB50 * 8, 256, 0, stream>>>(
        SrcBf16{Hout1, 512}, Wo2f, bo2, EpiArgs{out, nullptr, batch_vec, 1024}, NN);
}

// Round 13
// 807.402 us; speedup vs baseline: 1.2162x; 1.1195x over previous
//
#include <hip/hip_runtime.h>

#define NN 50000
#define NE 200000
#define DD 128
#define GG 256
#define NITERS 2
#define NBINS 50176          // 196 * 256, >= NN
#define NPART 196

typedef unsigned short u16;
typedef unsigned int u32;
typedef __bf16 bf16x8 __attribute__((ext_vector_type(8)));
typedef float f32x4 __attribute__((ext_vector_type(4)));

union U16x8 { uint4 u; bf16x8 v; u16 s[8]; };

__device__ __forceinline__ u16 f2b(float f) {             // f32 -> bf16 bits, RNE
    u32 u = __float_as_uint(f);
    return (u16)((u + 0x7FFFu + ((u >> 16) & 1u)) >> 16);
}
__device__ __forceinline__ float b2f(u16 s) { return __uint_as_float(((u32)s) << 16); }

__device__ __forceinline__ uint2 pack4(const float* v) {
    uint2 r;
    r.x = (u32)f2b(v[0]) | ((u32)f2b(v[1]) << 16);
    r.y = (u32)f2b(v[2]) | ((u32)f2b(v[3]) << 16);
    return r;
}

// async global -> LDS, 16B per lane; lds must be the wave-uniform base slot
__device__ __forceinline__ void gload_lds16(const void* g, void* lds) {
    __builtin_amdgcn_global_load_lds((const __attribute__((address_space(1))) void*)g,
                                     (__attribute__((address_space(3))) void*)lds, 16, 0, 0);
}

// XCD-chunked bijective block swizzle (m204 form)
__device__ __forceinline__ int xcd_swz(int orig, int nwg) {
    int q = nwg >> 3, r = nwg & 7;
    int x = orig & 7, loc = orig >> 3;
    return (x < r ? x * (q + 1) : r * (q + 1) + (x - r) * q) + loc;
}

// ---------------------------------------------------------------------------
// expand_k: OUT[128 rows][cols c*128..] = epi(A[128][K] @ W + bias), c = blockIdx.y
// A staged ONCE in LDS (K=128 -> 32 KB); W fragments per-lane direct; swapped
// MFMA -> thread owns 4 consecutive out-cols of one row.
// EPI: 0 = bf16 store (ob, ldN=LDN); 1 = f32 of + bf16 ob (LDN=128);
//      2 = residual: of += , ob mirror (LDN=128).
// zf: optional zero-fill of fi|fo slices: c<4 -> zf (fi), c>=4 -> zf+NN*128 (fo).
// ---------------------------------------------------------------------------
template<int K, int NL, int EPI, bool RELU, int LDN>
__global__ __launch_bounds__(256) void expand_k(
    const u16* __restrict__ A, const uint4* __restrict__ wfrag,
    const float* __restrict__ bias, float* __restrict__ of, u16* __restrict__ ob,
    float* __restrict__ zf, int M)
{
    constexpr int KS = K / 32;
    __shared__ uint4 smem[K * 16];
    const int t = threadIdx.x, l = t & 63, wv = t >> 6;
    const int mh = wv >> 1, nh = wv & 1;
    const int mblk = blockIdx.x;
    const int c = blockIdx.y;

    #pragma unroll
    for (int i = 0; i < K / 16; ++i) {           // stage A once
        int s = t + 256 * i;
        int ln = s & 63, mt = (s >> 6) & 7, ksl = s >> 9;
        int row = mblk * 128 + mt * 16 + (ln & 15);
        if (row >= M) row = M - 1;
        int kk = ksl * 32 + (ln >> 4) * 8;
        gload_lds16(A + (size_t)row * K + kk, &smem[s - ln]);
    }
    if (zf) {                                    // zero-fill slice (overlaps staging)
        float* zb = zf;
        int cz = c;
        if (cz >= 4) { zb += (size_t)NN * 128; cz -= 4; }
        #pragma unroll
        for (int i = 0; i < 4; ++i) {
            int f = t + 256 * i;                 // float4 idx in [0,1024)
            int row = f >> 3, c4 = f & 7;
            int grow = mblk * 128 + row;
            if (grow < M) {
                float4 z; z.x = 0.f; z.y = 0.f; z.z = 0.f; z.w = 0.f;
                *(float4*)(zb + (size_t)grow * 128 + cz * 32 + c4 * 4) = z;
            }
        }
    }
    __syncthreads();

    f32x4 acc[4][4] = {};
    #pragma unroll
    for (int ksl = 0; ksl < KS; ++ksl) {
        uint4 wa[4];
        #pragma unroll
        for (int mi = 0; mi < 4; ++mi)
            wa[mi] = wfrag[(size_t)((c * KS + ksl) * 8 + mh * 4 + mi) * 64 + l];
        bf16x8 bn[4];
        #pragma unroll
        for (int ni = 0; ni < 4; ++ni) { U16x8 u; u.u = smem[(ksl * 8 + nh * 4 + ni) * 64 + l]; bn[ni] = u.v; }
        #pragma unroll
        for (int mi = 0; mi < 4; ++mi) {
            U16x8 u; u.u = wa[mi];
            #pragma unroll
            for (int ni = 0; ni < 4; ++ni)
                acc[mi][ni] = __builtin_amdgcn_mfma_f32_16x16x32_bf16(u.v, bn[ni], acc[mi][ni], 0, 0, 0);
        }
    }
    float4 bb[4];
    #pragma unroll
    for (int mi = 0; mi < 4; ++mi) {
        if (bias) bb[mi] = *(const float4*)(bias + c * 128 + mh * 64 + mi * 16 + 4 * (l >> 4));
        else { bb[mi].x = 0.f; bb[mi].y = 0.f; bb[mi].z = 0.f; bb[mi].w = 0.f; }
    }
    #pragma unroll
    for (int ni = 0; ni < 4; ++ni) {
        int node = mblk * 128 + nh * 64 + ni * 16 + (l & 15);
        if (node >= M) continue;
        #pragma unroll
        for (int mi = 0; mi < 4; ++mi) {
            int col = c * 128 + mh * 64 + mi * 16 + 4 * (l >> 4);
            float v[4];
            const float* bf = &bb[mi].x;
            #pragma unroll
            for (int r = 0; r < 4; ++r) {
                v[r] = acc[mi][ni][r] + bf[r];
                if (RELU) v[r] = fmaxf(v[r], 0.f);
            }
            if (EPI == 0) {
                *(uint2*)(ob + (size_t)node * LDN + col) = pack4(v);
            } else {
                size_t a = (size_t)node * 128 + col;
                if (EPI == 2) {
                    float4 old = *(const float4*)(of + a);
                    v[0] += old.x; v[1] += old.y; v[2] += old.z; v[3] += old.w;
                }
                float4 s4; s4.x = v[0]; s4.y = v[1]; s4.z = v[2]; s4.w = v[3];
                *(float4*)(of + a) = s4;
                *(uint2*)(ob + a) = pack4(v);
            }
        }
    }
}

// ---------------------------------------------------------------------------
// Source functors for A-operand staging (gemm_k).
// ---------------------------------------------------------------------------
struct SrcBf16 {            // plain bf16 row-major [M][K], async-staged
    static constexpr bool DIRECT = true;
    const u16* A; int K;
    __device__ const void* gaddr(int row, int kk) const { return A + (size_t)row * K + kk; }
    __device__ bf16x8 operator()(int row, int kk) const {
        U16x8 u; u.u = *(const uint4*)(A + (size_t)row * K + kk); return u.v;
    }
};
struct SrcEnc {             // node encoder input: emb_node[x[row]] (f32 -> bf16)
    static constexpr bool DIRECT = false;
    const float* emb; const int* xids;
    __device__ const void* gaddr(int, int) const { return nullptr; }
    __device__ bf16x8 operator()(int row, int kk) const {
        int n = xids[row];
        const float* p = emb + (size_t)n * 256 + kk;
        float4 f0 = *(const float4*)p, f1 = *(const float4*)(p + 4);
        U16x8 r;
        r.s[0]=f2b(f0.x); r.s[1]=f2b(f0.y); r.s[2]=f2b(f0.z); r.s[3]=f2b(f0.w);
        r.s[4]=f2b(f1.x); r.s[5]=f2b(f1.y); r.s[6]=f2b(f1.z); r.s[7]=f2b(f1.w);
        return r.v;
    }
};
struct SrcUpd {             // [nodes | fi/deg | fo/deg] (f32 -> bf16), K=384
    static constexpr bool DIRECT = false;
    const float* nodes; const float* fi; const float* fo; const int* deg;
    __device__ const void* gaddr(int, int) const { return nullptr; }
    __device__ bf16x8 operator()(int row, int kk) const {
        const float* s; float sc = 1.f;
        if (kk < 128) s = nodes + (size_t)row * 128 + kk;
        else {
            int d = deg[row];
            sc = d > 0 ? 1.f / (float)d : 0.f;
            s = (kk < 256) ? fi + (size_t)row * 128 + (kk - 128)
                           : fo + (size_t)row * 128 + (kk - 256);
        }
        float4 f0 = *(const float4*)s, f1 = *(const float4*)(s + 4);
        U16x8 r;
        r.s[0]=f2b(f0.x*sc); r.s[1]=f2b(f0.y*sc); r.s[2]=f2b(f0.z*sc); r.s[3]=f2b(f0.w*sc);
        r.s[4]=f2b(f1.x*sc); r.s[5]=f2b(f1.y*sc); r.s[6]=f2b(f1.z*sc); r.s[7]=f2b(f1.w*sc);
        return r.v;
    }
};

struct EpiArgs { float* of; u16* ob; const int* idx; int ldN; };

// ---------------------------------------------------------------------------
// gemm_k: non-swapped MFMA (C rows register-resident); A + W staged to LDS.
// EPI0: bf16 store via swizzled LDS bounce.
// EPI3: segment-max by sorted idx; ni-outer merge over 16 (mi,r) rows.
// ---------------------------------------------------------------------------
template<int KDIM, int NBLK, int EPI, bool RELU, class SRC>
__global__ __launch_bounds__(256) void gemm_k(SRC src, const uint4* __restrict__ wfrag,
                                              const float* __restrict__ bias,
                                              EpiArgs ea, int M)
{
    constexpr int KS = KDIM / 32;
    constexpr int NPANEL = KDIM / 64;
    __shared__ uint4 smem[2048];
    const int t = threadIdx.x;
    const int l = t & 63;
    const int wv = t >> 6;
    const int mh = wv >> 1, nh = wv & 1;
    const int ell = xcd_swz(blockIdx.x, gridDim.x);
    const int mblk = ell / NBLK, nblk = ell % NBLK;

    f32x4 acc[4][4] = {};

    for (int p = 0; p < NPANEL; ++p) {
        __syncthreads();
        if constexpr (SRC::DIRECT) {
            #pragma unroll
            for (int i = 0; i < 4; ++i) {          // async A panel
                int s = t + 256 * i;
                int ln = s & 63, mt = (s >> 6) & 7, ksl = s >> 9;
                int row = mblk * 128 + mt * 16 + (ln & 15);
                if (row >= M) row = M - 1;
                int kk = p * 64 + ksl * 32 + (ln >> 4) * 8;
                gload_lds16(src.gaddr(row, kk), &smem[s - ln]);
            }
        } else {
            #pragma unroll
            for (int i = 0; i < 4; ++i) {          // computed A panel
                int s = t + 256 * i;
                int ln = s & 63, mt = (s >> 6) & 7, ksl = s >> 9;
                int row = mblk * 128 + mt * 16 + (ln & 15);
                if (row >= M) row = M - 1;
                int kk = p * 64 + ksl * 32 + (ln >> 4) * 8;
                U16x8 u; u.v = src(row, kk);
                smem[s] = u.u;
            }
        }
        {                                           // async W panel
            const uint4* wp = wfrag + (size_t)(nblk * KS + 2 * p) * 512;
            #pragma unroll
            for (int i = 0; i < 4; ++i) {
                int s = t + 256 * i;
                gload_lds16(wp + s, &smem[1024 + (s - (s & 63))]);
            }
        }
        __syncthreads();
        #pragma unroll
        for (int ksl = 0; ksl < 2; ++ksl) {
            bf16x8 a[4], b[4];
            #pragma unroll
            for (int mi = 0; mi < 4; ++mi) { U16x8 u; u.u = smem[(ksl*8 + mh*4 + mi)*64 + l]; a[mi] = u.v; }
            #pragma unroll
            for (int ni = 0; ni < 4; ++ni) { U16x8 u; u.u = smem[1024 + (ksl*8 + nh*4 + ni)*64 + l]; b[ni] = u.v; }
            #pragma unroll
            for (int mi = 0; mi < 4; ++mi)
                #pragma unroll
                for (int ni = 0; ni < 4; ++ni)
                    acc[mi][ni] = __builtin_amdgcn_mfma_f32_16x16x32_bf16(a[mi], b[ni], acc[mi][ni], 0, 0, 0);
        }
    }

    float bcol[4];
    #pragma unroll
    for (int ni = 0; ni < 4; ++ni)
        bcol[ni] = bias ? bias[nblk * 128 + nh * 64 + ni * 16 + (l & 15)] : 0.f;

    if constexpr (EPI == 0) {
        // bf16 store via XOR-swizzled LDS bounce
        __syncthreads();
        u16* bn = (u16*)smem;
        #pragma unroll
        for (int mi = 0; mi < 4; ++mi)
            #pragma unroll
            for (int ni = 0; ni < 4; ++ni)
                #pragma unroll
                for (int r = 0; r < 4; ++r) {
                    int rl = mh * 64 + mi * 16 + (l >> 4) * 4 + r;
                    int cl = nh * 64 + ni * 16 + (l & 15);
                    float v = acc[mi][ni][r] + bcol[ni];
                    if (RELU) v = fmaxf(v, 0.f);
                    int sx = (rl >> 2) & 7;
                    bn[rl * 128 + ((((cl >> 3) ^ sx)) << 3) + (cl & 7)] = f2b(v);
                }
        __syncthreads();
        int row = t >> 1, half = t & 1;
        int grow = mblk * 128 + row;
        if (grow < M) {
            int sx = (row >> 2) & 7;
            uint4* dst = (uint4*)(ea.ob + (size_t)grow * ea.ldN + nblk * 128 + half * 64);
            const uint4* sp = ((const uint4*)bn) + row * 16;
            #pragma unroll
            for (int i = 0; i < 8; ++i) dst[i] = sp[(half * 8 + i) ^ sx];
        }
    } else if constexpr (EPI == 3) {
        // segment-max: batch ids for this lane's 16 rows (within 64-row window)
        int g16[4][4];
        #pragma unroll
        for (int mi = 0; mi < 4; ++mi) {
            int rb = mblk * 128 + mh * 64 + mi * 16 + (l >> 4) * 4;
            #pragma unroll
            for (int r = 0; r < 4; ++r)
                g16[mi][r] = (rb + r < M) ? ea.idx[rb + r] : -1;
        }
        #pragma unroll
        for (int ni = 0; ni < 4; ++ni) {
            int colg = nblk * 128 + nh * 64 + ni * 16 + (l & 15);
            float mv = 0.f; int cg = -1;
            #pragma unroll
            for (int mi = 0; mi < 4; ++mi)
                #pragma unroll
                for (int r = 0; r < 4; ++r) {
                    float v = acc[mi][ni][r] + bcol[ni];
                    if (RELU) v = fmaxf(v, 0.f);
                    int g = g16[mi][r];
                    if (g != cg) {
                        if (cg >= 0) atomicMax((u32*)(ea.of + (size_t)cg * 1024 + colg), __float_as_uint(mv));
                        cg = g; mv = v;
                    } else mv = fmaxf(mv, v);
                }
            if (cg >= 0) atomicMax((u32*)(ea.of + (size_t)cg * 1024 + colg), __float_as_uint(mv));
        }
    }
}

// ---------------------------------------------------------------------------
// upd23: fused Wf2+Wf3: U2 = relu(U1@W2+b2) (LDS bounce), then
// nodes += relu(U2@W3+b3) with bf16 mirror. gemm_k-style K=256 phase,
// then barrier-free K=128 phase with per-lane-direct W3 (loads hoistable).
// ---------------------------------------------------------------------------
__global__ __launch_bounds__(256) void upd23(
    const u16* __restrict__ U1, const uint4* __restrict__ W2f,
    const float* __restrict__ b2, const uint4* __restrict__ W3f,
    const float* __restrict__ b3, float* __restrict__ nodes,
    u16* __restrict__ nodesbf, int M)
{
    __shared__ uint4 smem[2048];   // 32 KB
    const int t = threadIdx.x, l = t & 63, wv = t >> 6;
    const int mh = wv >> 1, nh = wv & 1;
    const int mblk = xcd_swz(blockIdx.x, gridDim.x);

    f32x4 acc[4][4] = {};
    for (int p = 0; p < 4; ++p) {              // K=256: 4 panels
        __syncthreads();
        #pragma unroll
        for (int i = 0; i < 4; ++i) {          // async A panel from U1
            int s = t + 256 * i;
            int ln = s & 63, mt = (s >> 6) & 7, ksl = s >> 9;
            int row = mblk * 128 + mt * 16 + (ln & 15);
            if (row >= M) row = M - 1;
            int kk = p * 64 + ksl * 32 + (ln >> 4) * 8;
            gload_lds16(U1 + (size_t)row * 256 + kk, &smem[s - ln]);
        }
        {                                       // async W2 panel
            const uint4* wp = W2f + (size_t)(2 * p) * 512;
            #pragma unroll
            for (int i = 0; i < 4; ++i) {
                int s = t + 256 * i;
                gload_lds16(wp + s, &smem[1024 + (s - (s & 63))]);
            }
        }
        __syncthreads();
        #pragma unroll
        for (int ksl = 0; ksl < 2; ++ksl) {
            bf16x8 a[4], b[4];
            #pragma unroll
            for (int mi = 0; mi < 4; ++mi) { U16x8 u; u.u = smem[(ksl*8 + mh*4 + mi)*64 + l]; a[mi] = u.v; }
            #pragma unroll
            for (int ni = 0; ni < 4; ++ni) { U16x8 u; u.u = smem[1024 + (ksl*8 + nh*4 + ni)*64 + l]; b[ni] = u.v; }
            #pragma unroll
            for (int mi = 0; mi < 4; ++mi)
                #pragma unroll
                for (int ni = 0; ni < 4; ++ni)
                    acc[mi][ni] = __builtin_amdgcn_mfma_f32_16x16x32_bf16(a[mi], b[ni], acc[mi][ni], 0, 0, 0);
        }
    }

    // bounce h2 = relu(acc + b2), swizzled row-major bf16 [128][128]
    float bc2[4];
    #pragma unroll
    for (int ni = 0; ni < 4; ++ni) bc2[ni] = b2[nh * 64 + ni * 16 + (l & 15)];
    __syncthreads();
    u16* bn = (u16*)smem;
    #pragma unroll
    for (int mi = 0; mi < 4; ++mi)
        #pragma unroll
        for (int ni = 0; ni < 4; ++ni)
            #pragma unroll
            for (int r = 0; r < 4; ++r) {
                int rl = mh * 64 + mi * 16 + (l >> 4) * 4 + r;
                int cl = nh * 64 + ni * 16 + (l & 15);
                float v = fmaxf(acc[mi][ni][r] + bc2[ni], 0.f);
                int sx = (rl >> 2) & 7;
                bn[rl * 128 + (((cl >> 3) ^ sx) << 3) + (cl & 7)] = f2b(v);
            }
    __syncthreads();

    // K=128 phase: W3 per-lane direct (no barriers -> loads hoist)
    f32x4 acc2[4][4] = {};
    #pragma unroll
    for (int ks = 0; ks < 4; ++ks) {
        uint4 bw[4];
        #pragma unroll
        for (int ni = 0; ni < 4; ++ni)
            bw[ni] = W3f[(size_t)(ks * 8 + nh * 4 + ni) * 64 + l];
        bf16x8 a[4];
        #pragma unroll
        for (int mi = 0; mi < 4; ++mi) {
            int rl = (mh * 4 + mi) * 16 + (l & 15);
            int c0 = ks * 32 + (l >> 4) * 8;
            int sx = (rl >> 2) & 7;
            U16x8 u; u.u = *(const uint4*)&bn[rl * 128 + (((c0 >> 3) ^ sx) << 3)];
            a[mi] = u.v;
        }
        #pragma unroll
        for (int mi = 0; mi < 4; ++mi)
            #pragma unroll
            for (int ni = 0; ni < 4; ++ni) {
                U16x8 u; u.u = bw[ni];
                acc2[mi][ni] = __builtin_amdgcn_mfma_f32_16x16x32_bf16(a[mi], u.v, acc2[mi][ni], 0, 0, 0);
            }
    }

    // residual epilogue: nodes += relu(acc2 + b3); nodesbf mirror
    float bc3[4];
    #pragma unroll
    for (int ni = 0; ni < 4; ++ni) bc3[ni] = b3[nh * 64 + ni * 16 + (l & 15)];
    #pragma unroll
    for (int mi = 0; mi < 4; ++mi)
        #pragma unroll
        for (int r = 0; r < 4; ++r) {
            int row = mblk * 128 + mh * 64 + mi * 16 + (l >> 4) * 4 + r;
            if (row >= M) continue;
            #pragma unroll
            for (int ni = 0; ni < 4; ++ni) {
                int col = nh * 64 + ni * 16 + (l & 15);
                size_t a = (size_t)row * 128 + col;
                float v = nodes[a] + fmaxf(acc2[mi][ni][r] + bc3[ni], 0.f);
                nodes[a] = v;
                nodesbf[a] = f2b(v);
            }
        }
}

// ---------------------------------------------------------------------------
// Fused per-edge pipeline (edges pre-sorted by idxA). blockIdx.y selects the
// parameter set (0 = parent, 1 = child) for the merged dispatch; ldP/base
// parameterize the P-slice layout (narrow [N][512] or wide [N][1024]).
// ---------------------------------------------------------------------------
struct EdgePar {
    const float* T; const uint4* W2f; const float* b2;
    const uint4* W3f; const float* b3;
    const int* iA; const int* iB; const int* iC;
    float* agg; int base;
};

__global__ __launch_bounds__(256) void edge_fused(
    const u16* __restrict__ P, int ldP, EdgePar e0, EdgePar e1)
{
    __shared__ uint4 smA[2048];
    __shared__ int   sidx[3][128];
    __shared__ float sT[768];
    const int t = threadIdx.x;
    const int l = t & 63;
    const int wv = t >> 6;
    const int mh = wv >> 1, nh = wv & 1;
    const int base = xcd_swz(blockIdx.x, gridDim.x) * 128;
    const EdgePar ep = (blockIdx.y == 0) ? e0 : e1;

    if (t < 128) {
        int e = (base + t < NE) ? base + t : NE - 1;
        sidx[0][t] = ep.iA[e];
        sidx[1][t] = ep.iB[e];
        sidx[2][t] = ep.iC[e];
    }
    for (int i = t; i < 768; i += 256) sT[i] = ep.T[i];
    __syncthreads();

    const int rt0 = wv * 16 + (l & 15);
    const int rt1 = (wv + 4) * 16 + (l & 15);
    const int klo = (l >> 4) * 8;
    const u16* pA[2] = { P + (size_t)sidx[0][rt0] * ldP + ep.base,
                         P + (size_t)sidx[0][rt1] * ldP + ep.base };
    const u16* pB[2] = { P + (size_t)sidx[1][rt0] * ldP + ep.base + 256,
                         P + (size_t)sidx[1][rt1] * ldP + ep.base + 256 };
    const float* pT[2] = { sT + sidx[2][rt0] * 256, sT + sidx[2][rt1] * 256 };

    uint4 ra[4], rb[4];
    #pragma unroll
    for (int i = 0; i < 4; ++i) {
        int kk = (i >> 1) * 32 + klo;
        ra[i] = *(const uint4*)(pA[i & 1] + kk);
        rb[i] = *(const uint4*)(pB[i & 1] + kk);
    }

    f32x4 acc[4][4] = {};
    #pragma unroll
    for (int p = 0; p < 4; ++p) {
        #pragma unroll
        for (int i = 0; i < 4; ++i) {
            int kk = (i >> 1) * 32 + klo;
            U16x8 ua, ub, r;
            ua.u = ra[i]; ub.u = rb[i];
            const float* tb = pT[i & 1] + p * 64 + kk;
            #pragma unroll
            for (int j = 0; j < 8; ++j) {
                float v = b2f(ua.s[j]) + b2f(ub.s[j]) + tb[j];
                r.s[j] = f2b(fmaxf(v, 0.f));
            }
            smA[(p & 1) * 1024 + t + 256 * i] = r.u;
            if (p < 3) {
                int kn = (p + 1) * 64 + kk;
                ra[i] = *(const uint4*)(pA[i & 1] + kn);
                rb[i] = *(const uint4*)(pB[i & 1] + kn);
            }
        }
        asm volatile("s_waitcnt lgkmcnt(0)" ::: "memory");
        __builtin_amdgcn_s_barrier();
        uint4 bw[2][4];
        #pragma unroll
        for (int ksl = 0; ksl < 2; ++ksl)
            #pragma unroll
            for (int ni = 0; ni < 4; ++ni)
                bw[ksl][ni] = ep.W2f[(size_t)((p * 2 + ksl) * 8 + nh * 4 + ni) * 64 + l];
        #pragma unroll
        for (int ksl = 0; ksl < 2; ++ksl) {
            bf16x8 a[4];
            #pragma unroll
            for (int mi = 0; mi < 4; ++mi) { U16x8 u; u.u = smA[(p & 1) * 1024 + (ksl*8 + mh*4 + mi)*64 + l]; a[mi] = u.v; }
            #pragma unroll
            for (int mi = 0; mi < 4; ++mi)
                #pragma unroll
                for (int ni = 0; ni < 4; ++ni) {
                    U16x8 u; u.u = bw[ksl][ni];
                    acc[mi][ni] = __builtin_amdgcn_mfma_f32_16x16x32_bf16(a[mi], u.v, acc[mi][ni], 0, 0, 0);
                }
        }
    }

    float bc2[4];
    #pragma unroll
    for (int ni = 0; ni < 4; ++ni) bc2[ni] = ep.b2[nh * 64 + ni * 16 + (l & 15)];
    __builtin_amdgcn_s_barrier();
    u16* bn = (u16*)smA;
    #pragma unroll
    for (int mi = 0; mi < 4; ++mi)
        #pragma unroll
        for (int ni = 0; ni < 4; ++ni)
            #pragma unroll
            for (int r = 0; r < 4; ++r) {
                int rl = mh * 64 + mi * 16 + (l >> 4) * 4 + r;
                int cl = nh * 64 + ni * 16 + (l & 15);
                float v = fmaxf(acc[mi][ni][r] + bc2[ni], 0.f);
                int sx = (rl >> 2) & 7;
                bn[rl * 128 + (((cl >> 3) ^ sx) << 3) + (cl & 7)] = f2b(v);
            }
    asm volatile("s_waitcnt lgkmcnt(0)" ::: "memory");
    __builtin_amdgcn_s_barrier();

    f32x4 acc2[4][4] = {};
    #pragma unroll
    for (int ks = 0; ks < 4; ++ks) {
        uint4 bw[4];
        #pragma unroll
        for (int ni = 0; ni < 4; ++ni)
            bw[ni] = ep.W3f[(size_t)(ks * 8 + nh * 4 + ni) * 64 + l];
        bf16x8 a[4];
        #pragma unroll
        for (int mi = 0; mi < 4; ++mi) {
            int rl = (mh * 4 + mi) * 16 + (l & 15);
            int c0 = ks * 32 + (l >> 4) * 8;
            int sx = (rl >> 2) & 7;
            U16x8 u; u.u = *(const uint4*)&bn[rl * 128 + (((c0 >> 3) ^ sx) << 3)];
            a[mi] = u.v;
        }
        #pragma unroll
        for (int mi = 0; mi < 4; ++mi)
            #pragma unroll
            for (int ni = 0; ni < 4; ++ni) {
                U16x8 u; u.u = bw[ni];
                acc2[mi][ni] = __builtin_amdgcn_mfma_f32_16x16x32_bf16(a[mi], u.v, acc2[mi][ni], 0, 0, 0);
            }
    }

    float bc3[4];
    #pragma unroll
    for (int ni = 0; ni < 4; ++ni) bc3[ni] = ep.b3[nh * 64 + ni * 16 + (l & 15)];
    #pragma unroll
    for (int mi = 0; mi < 4; ++mi) {
        int rt4 = mh * 64 + mi * 16 + (l >> 4) * 4;
        int nd[4];
        #pragma unroll
        for (int r = 0; r < 4; ++r)
            nd[r] = (base + rt4 + r < NE) ? sidx[0][rt4 + r] : -1;
        #pragma unroll
        for (int ni = 0; ni < 4; ++ni) {
            int col = nh * 64 + ni * 16 + (l & 15);
            float mv = 0.f; int cg = -1;
            #pragma unroll
            for (int r = 0; r < 4; ++r) {
                float v = fmaxf(acc2[mi][ni][r] + bc3[ni], 0.f);
                if (nd[r] != cg) {
                    if (cg >= 0) atomicAdd(ep.agg + (size_t)cg * 128 + col, mv);
                    cg = nd[r]; mv = v;
                } else mv += v;
            }
            if (cg >= 0) atomicAdd(ep.agg + (size_t)cg * 128 + col, mv);
        }
    }
}

// ---------------------------------------------------------------------------
// Fused counting sort, both keys (parent=dst, child=src).
// ---------------------------------------------------------------------------
__global__ void hist2_kernel(const int* __restrict__ dstI, const int* __restrict__ srcI,
                             int* __restrict__ hist)
{
    int i = blockIdx.x * 256 + threadIdx.x;
    if (i < NE) atomicAdd(&hist[dstI[i]], 1);
    else if (i < 2 * NE) atomicAdd(&hist[NBINS + srcI[i - NE]], 1);
}
__global__ void chunk_sum(const int* __restrict__ h, int* __restrict__ part)
{
    __shared__ int sh[256];
    int t = threadIdx.x, b = blockIdx.x;
    sh[t] = h[b * 256 + t];
    __syncthreads();
    for (int o = 128; o > 0; o >>= 1) { if (t < o) sh[t] += sh[t + o]; __syncthreads(); }
    if (t == 0) part[b] = sh[0];
}
__global__ void scan_part2(int* part)
{
    __shared__ int sh[256];
    int t = threadIdx.x, b = blockIdx.x;
    int* p = part + b * NPART;
    sh[t] = (t < NPART) ? p[t] : 0;
    __syncthreads();
    for (int o = 1; o < 256; o <<= 1) {
        int x = (t >= o) ? sh[t - o] : 0;
        __syncthreads(); sh[t] += x; __syncthreads();
    }
    if (t < NPART) p[t] = (t ? sh[t - 1] : 0) + b * NE;
}
__global__ void mk_cursor(const int* __restrict__ h, const int* __restrict__ part,
                          int* __restrict__ cur)
{
    __shared__ int sh[256];
    int t = threadIdx.x, b = blockIdx.x;
    int v = h[b * 256 + t];
    sh[t] = v;
    __syncthreads();
    for (int o = 1; o < 256; o <<= 1) {
        int x = (t >= o) ? sh[t - o] : 0;
        __syncthreads(); sh[t] += x; __syncthreads();
    }
    cur[b * 256 + t] = part[b] + sh[t] - v;
}
__global__ void sort_scatter2(const int* __restrict__ dstI, const int* __restrict__ srcI,
                              const int* __restrict__ at, int* __restrict__ cur,
                              int* __restrict__ oA, int* __restrict__ oB, int* __restrict__ oC)
{
    int i = blockIdx.x * 256 + threadIdx.x;
    if (i < NE) {
        int k = dstI[i];
        int p = atomicAdd(&cur[k], 1);
        oA[p] = k; oB[p] = srcI[i]; oC[p] = at[i];
    } else if (i < 2 * NE) {
        int e = i - NE;
        int k = srcI[e];
        int p = atomicAdd(&cur[NBINS + k], 1);
        oA[p] = k; oB[p] = dstI[e]; oC[p] = at[e];
    }
}

// ---------------------------------------------------------------------------
// Mega weight packer: all 15 pack jobs in one launch.
// ---------------------------------------------------------------------------
struct PackPtrs { const float* p[13]; };

__global__ void pack_all(PackPtrs pp, uint4* __restrict__ frag)
{
    int tid = blockIdx.x * 256 + threadIdx.x;
    if (tid >= 126976) return;
    constexpr int NJ = 15;
    const int   start[NJ] = {0,4096,6144,10240,14336,18432,22528,26624,28672,32768,34816,47104,51200,53248,61440};
    const int   fbase[NJ] = {0,4096,6144,6144,14336,14336,22528,26624,28672,32768,34816,47104,51200,53248,61440};
    const short wsel [NJ] = {0,1,2,2,3,3,4,5,6,7,8,9,10,11,12};
    const short ldt  [NJ] = {128,128,256,256,256,256,128,128,128,128,256,128,128,512,1024};
    const short rot  [NJ] = {0,0,0,128,0,128,0,0,0,0,0,0,0,0,0};
    const short cot  [NJ] = {0,0,0,-256,0,-256,0,0,0,0,0,0,0,0,0};
    const short nbst [NJ] = {0,0,0,2,0,2,0,0,0,0,0,0,0,0,0};
    const short kst  [NJ] = {8,4,4,4,4,4,8,4,8,4,12,8,4,4,16};
    int j = 0;
    for (int i = NJ - 1; i >= 1; --i) if (tid >= start[i]) { j = i; break; }
    int rem = tid - start[j];
    int KS = kst[j];
    int nbrel = rem / (KS * 512);
    int r1 = rem % (KS * 512);
    int ks = r1 >> 9;
    int r2 = r1 & 511;
    int nt = r2 >> 6, l = r2 & 63;
    int nb = nbst[j] + nbrel;
    int k  = ks * 32 + (l >> 4) * 8;
    int ld = ldt[j];
    int col = nb * 128 + nt * 16 + (l & 15) + cot[j];
    const float* W = pp.p[wsel[j]];
    U16x8 u;
    #pragma unroll
    for (int jj = 0; jj < 8; ++jj) u.s[jj] = f2b(W[(size_t)(rot[j] + k + jj) * ld + col]);
    frag[fbase[j] + ((size_t)(nb * KS + ks) * 8 + nt) * 64 + l] = u.u;
}

// ---------------------------------------------------------------------------
// Edge-type tables, fused.
// ---------------------------------------------------------------------------
__global__ void enc_tab_kernel(const float* __restrict__ emb_edge,
                               const float* __restrict__ We1, const float* __restrict__ be1,
                               const float* __restrict__ We2, const float* __restrict__ be2,
                               const float* __restrict__ Wp1, const float* __restrict__ bp1,
                               const float* __restrict__ Wc1, const float* __restrict__ bc1,
                               float* __restrict__ Tp, float* __restrict__ Tc)
{
    __shared__ float h1[3][128];
    __shared__ float ea[3][128];
    const int t = threadIdx.x;   // 256
    if (t < 128) {
        for (int a = 0; a < 3; ++a) {
            float s = be1[t];
            for (int k = 0; k < 256; ++k) s = fmaf(emb_edge[a * 256 + k], We1[k * 128 + t], s);
            h1[a][t] = fmaxf(s, 0.f);
        }
    }
    __syncthreads();
    if (t < 128) {
        for (int a = 0; a < 3; ++a) {
            float s = be2[t];
            for (int k = 0; k < 128; ++k) s = fmaf(h1[a][k], We2[k * 128 + t], s);
            ea[a][t] = fmaxf(s, 0.f);
        }
    }
    __syncthreads();
    for (int a = 0; a < 3; ++a) {
        float sp = bp1[t], sc = bc1[t];
        for (int k = 0; k < 128; ++k) {
            float e = ea[a][k];
            sp = fmaf(e, Wp1[(size_t)(256 + k) * 256 + t], sp);
            sc = fmaf(e, Wc1[(size_t)(256 + k) * 256 + t], sc);
        }
        Tp[a * 256 + t] = sp;
        Tc[a * 256 + t] = sc;
    }
}

// ---------------------------------------------------------------------------
extern "C" void kernel_launch(void* const* d_in, const int* in_sizes, int n_in,
                              void* d_out, int out_size, void* d_ws, size_t ws_size,
                              hipStream_t stream)
{
    const int*   x          = (const int*)d_in[0];
    const int*   edge_index = (const int*)d_in[1];
    const int*   edge_attr  = (const int*)d_in[2];
    const int*   batch_vec  = (const int*)d_in[3];
    const float* emb_node   = (const float*)d_in[4];
    const float* Wn1 = (const float*)d_in[5];  const float* bn1 = (const float*)d_in[6];
    const float* Wn2 = (const float*)d_in[7];  const float* bn2 = (const float*)d_in[8];
    const float* emb_edge = (const float*)d_in[9];
    const float* We1 = (const float*)d_in[10]; const float* be1 = (const float*)d_in[11];
    const float* We2 = (const float*)d_in[12]; const float* be2 = (const float*)d_in[13];
    const float* Wp1 = (const float*)d_in[14]; const float* bp1 = (const float*)d_in[15];
    const float* Wp2 = (const float*)d_in[16]; const float* bp2 = (const float*)d_in[17];
    const float* Wp3 = (const float*)d_in[18]; const float* bp3 = (const float*)d_in[19];
    const float* Wc1 = (const float*)d_in[20]; const float* bc1 = (const float*)d_in[21];
    const float* Wc2 = (const float*)d_in[22]; const float* bc2 = (const float*)d_in[23];
    const float* Wc3 = (const float*)d_in[24]; const float* bc3 = (const float*)d_in[25];
    const float* Wf1 = (const float*)d_in[26]; const float* bf1 = (const float*)d_in[27];
    const float* Wf2 = (const float*)d_in[28]; const float* bf2 = (const float*)d_in[29];
    const float* Wf3 = (const float*)d_in[30]; const float* bf3 = (const float*)d_in[31];
    const float* Wo1 = (const float*)d_in[32]; const float* bo1 = (const float*)d_in[33];
    const float* Wo2 = (const float*)d_in[34]; const float* bo2 = (const float*)d_in[35];

    float* out = (float*)d_out;

    auto al = [](size_t b) { return (b + 255) & ~(size_t)255; };
    // fixed allocations (everything except P)
    size_t fixed = al((size_t)NN*DD*4) + al((size_t)NN*DD*2) + al((size_t)NN*DD*4)
                 + al((size_t)NN*DD*4) + al((size_t)NN*256*2) + 2*al(3*256*4)
                 + al((size_t)126976*16) + 2*al((size_t)2*NBINS*4) + al((size_t)2*NPART*4)
                 + 3*al((size_t)2*NE*4);
    const bool wide = ws_size >= fixed + al((size_t)NN * 1024 * 2);

    char* w = (char*)d_ws;
    auto alloc = [&](size_t bytes) { char* p = w; w += (bytes + 255) & ~(size_t)255; return p; };
    float* nodes   = (float*)alloc((size_t)NN * DD * 4);
    u16*   nodesbf = (u16*)  alloc((size_t)NN * DD * 2);
    float* fi      = (float*)alloc((size_t)NN * DD * 4);
    float* fo      = (float*)alloc((size_t)NN * DD * 4);   // contiguous after fi
    u16*   P       = (u16*)  alloc((size_t)NN * (wide ? 1024 : 512) * 2);
    u16*   h2      = (u16*)  alloc((size_t)NN * 256 * 2);  // He / U1
    float* Tp      = (float*)alloc(3 * 256 * 4);
    float* Tc      = (float*)alloc(3 * 256 * 4);
    uint4* frag    = (uint4*)alloc((size_t)126976 * 16);
    int* hist = (int*)alloc((size_t)2 * NBINS * 4);        // [dst | src]; src half = deg
    int* part = (int*)alloc((size_t)2 * NPART * 4);
    int* cur  = (int*)alloc((size_t)2 * NBINS * 4);
    int* sA   = (int*)alloc((size_t)2 * NE * 4);           // [parent | child]
    int* sB   = (int*)alloc((size_t)2 * NE * 4);
    int* sC   = (int*)alloc((size_t)2 * NE * 4);

    u16* He = h2;                      // [50k][128]
    u16* U1 = h2;                      // [50k][256]
    u16* Hout1 = P;                    // [50k][512] (P contents dead by then)
    const int* degS = hist + NBINS;    // deg(src) as int

    uint4* Wn1f = frag;                // K256 N128
    uint4* Wn2f = Wn1f + 4096;         // K128 N128
    uint4* PWp  = Wn2f + 2048;         // K128 N512
    uint4* PWc  = PWp  + 8192;         // (contiguous after PWp)
    uint4* W2p  = PWc  + 8192;         // K256 N128
    uint4* W3p  = W2p  + 4096;         // K128 N128
    uint4* W2c  = W3p  + 2048;
    uint4* W3c  = W2c  + 4096;
    uint4* Wf1f = W3c  + 2048;         // K384 N256
    uint4* Wf2f = Wf1f + 12288;        // K256 N128
    uint4* Wf3f = Wf2f + 4096;         // K128 N128
    uint4* Wo1f = Wf3f + 2048;         // K128 N512
    uint4* Wo2f = Wo1f + 8192;         // K512 N1024

    const int* srcI = edge_index;
    const int* dstI = edge_index + NE;

    const int MB50 = (NN + 127) / 128;   // 391
    const int MBE  = (NE + 127) / 128;   // 1563

    // ---- prep --------------------------------------------------------------
    (void)hipMemsetAsync(d_out, 0, (size_t)out_size * 4, stream);
    (void)hipMemsetAsync(hist, 0, (size_t)2 * NBINS * 4, stream);

    PackPtrs pp;
    pp.p[0]=Wn1; pp.p[1]=Wn2; pp.p[2]=Wp1; pp.p[3]=Wc1; pp.p[4]=Wp2; pp.p[5]=Wp3;
    pp.p[6]=Wc2; pp.p[7]=Wc3; pp.p[8]=Wf1; pp.p[9]=Wf2; pp.p[10]=Wf3; pp.p[11]=Wo1; pp.p[12]=Wo2;
    pack_all<<<(126976 + 255) / 256, 256, 0, stream>>>(pp, frag);

    enc_tab_kernel<<<1, 256, 0, stream>>>(emb_edge, We1, be1, We2, be2,
                                          Wp1, bp1, Wc1, bc1, Tp, Tc);

    hist2_kernel<<<(2 * NE + 255) / 256, 256, 0, stream>>>(dstI, srcI, hist);
    chunk_sum<<<2 * NPART, 256, 0, stream>>>(hist, part);
    scan_part2<<<2, 256, 0, stream>>>(part);
    mk_cursor<<<2 * NPART, 256, 0, stream>>>(hist, part, cur);
    sort_scatter2<<<(2 * NE + 255) / 256, 256, 0, stream>>>(dstI, srcI, edge_attr, cur, sA, sB, sC);

    // ---- node encoder ------------------------------------------------------
    gemm_k<256, 1, 0, true, SrcEnc><<<MB50, 256, 0, stream>>>(
        SrcEnc{emb_node, x}, Wn1f, bn1, EpiArgs{nullptr, He, nullptr, 128}, NN);
    expand_k<128, 1, 1, true, 128><<<dim3(MB50, 1), 256, 0, stream>>>(
        He, Wn2f, bn2, nodes, nodesbf, nullptr, NN);

    EdgePar epP = { Tp, W2p, bp2, W3p, bp3, sA,      sB,      sC,      fi, 0 };
    EdgePar epC = { Tc, W2c, bc2, W3c, bc3, sA + NE, sB + NE, sC + NE, fo, wide ? 512 : 0 };

    // ---- message-passing iterations ---------------------------------------
    for (int it = 0; it < NITERS; ++it) {
        if (wide) {
            // one P5-pass (zeroes fi+fo) + one merged edge dispatch
            expand_k<128, 8, 0, false, 1024><<<dim3(MB50, 8), 256, 0, stream>>>(
                nodesbf, PWp, nullptr, nullptr, P, fi, NN);
            edge_fused<<<dim3(MBE, 2), 256, 0, stream>>>(P, 1024, epP, epC);
        } else {
            expand_k<128, 4, 0, false, 512><<<dim3(MB50, 4), 256, 0, stream>>>(
                nodesbf, PWp, nullptr, nullptr, P, fi, NN);
            edge_fused<<<dim3(MBE, 1), 256, 0, stream>>>(P, 512, epP, epP);
            expand_k<128, 4, 0, false, 512><<<dim3(MB50, 4), 256, 0, stream>>>(
                nodesbf, PWc, nullptr, nullptr, P, fo, NN);
            EdgePar epC2 = epC;
            edge_fused<<<dim3(MBE, 1), 256, 0, stream>>>(P, 512, epC2, epC2);
        }

        gemm_k<384, 2, 0, true, SrcUpd><<<MB50 * 2, 256, 0, stream>>>(
            SrcUpd{nodes, fi, fo, degS}, Wf1f, bf1, EpiArgs{nullptr, U1, nullptr, 256}, NN);
        upd23<<<MB50, 256, 0, stream>>>(U1, Wf2f, bf2, Wf3f, bf3, nodes, nodesbf, NN);
    }

    // ---- output head + global max pool -------------------------------------
    expand_k<128, 4, 0, true, 512><<<dim3(MB50, 4), 256, 0, stream>>>(
        nodesbf, Wo1f, bo1, nullptr, Hout1, nullptr, NN);
    gemm_k<512, 8, 3, true, SrcBf16><<<MB50 * 8, 256, 0, stream>>>(
        SrcBf16{Hout1, 512}, Wo2f, bo2, EpiArgs{out, nullptr, batch_vec, 1024}, NN);
}

// Round 14
// 805.433 us; speedup vs baseline: 1.2192x; 1.0024x over previous
//
#include <hip/hip_runtime.h>

#define NN 50000
#define NE 200000
#define DD 128
#define GG 256
#define NITERS 2
#define NBINS 50176          // 196 * 256, >= NN
#define NPART 196

typedef unsigned short u16;
typedef unsigned int u32;
typedef __bf16 bf16x8 __attribute__((ext_vector_type(8)));
typedef float f32x4 __attribute__((ext_vector_type(4)));

union U16x8 { uint4 u; bf16x8 v; u16 s[8]; };

__device__ __forceinline__ u16 f2b(float f) {             // f32 -> bf16 bits, RNE (manual)
    u32 u = __float_as_uint(f);
    return (u16)((u + 0x7FFFu + ((u >> 16) & 1u)) >> 16);
}
__device__ __forceinline__ u16 f2bn(float f) {            // native HW cvt (RNE)
    union { __bf16 b; u16 s; } u; u.b = (__bf16)f; return u.s;
}
__device__ __forceinline__ float b2f(u16 s) { return __uint_as_float(((u32)s) << 16); }

__device__ __forceinline__ uint2 pack4(const float* v) {
    uint2 r;
    r.x = (u32)f2bn(v[0]) | ((u32)f2bn(v[1]) << 16);
    r.y = (u32)f2bn(v[2]) | ((u32)f2bn(v[3]) << 16);
    return r;
}

// async global -> LDS, 16B per lane; lds must be the wave-uniform base slot
__device__ __forceinline__ void gload_lds16(const void* g, void* lds) {
    __builtin_amdgcn_global_load_lds((const __attribute__((address_space(1))) void*)g,
                                     (__attribute__((address_space(3))) void*)lds, 16, 0, 0);
}

// XCD-chunked bijective block swizzle (m204 form)
__device__ __forceinline__ int xcd_swz(int orig, int nwg) {
    int q = nwg >> 3, r = nwg & 7;
    int x = orig & 7, loc = orig >> 3;
    return (x < r ? x * (q + 1) : r * (q + 1) + (x - r) * q) + loc;
}

// ---------------------------------------------------------------------------
// expand_k: OUT[128 rows][cols c*128..] = epi(A[128][K] @ W + bias), c = blockIdx.y
// ---------------------------------------------------------------------------
template<int K, int NL, int EPI, bool RELU, int LDN>
__global__ __launch_bounds__(256) void expand_k(
    const u16* __restrict__ A, const uint4* __restrict__ wfrag,
    const float* __restrict__ bias, float* __restrict__ of, u16* __restrict__ ob,
    float* __restrict__ zf, int M)
{
    constexpr int KS = K / 32;
    __shared__ uint4 smem[K * 16];
    const int t = threadIdx.x, l = t & 63, wv = t >> 6;
    const int mh = wv >> 1, nh = wv & 1;
    const int mblk = blockIdx.x;
    const int c = blockIdx.y;

    #pragma unroll
    for (int i = 0; i < K / 16; ++i) {           // stage A once
        int s = t + 256 * i;
        int ln = s & 63, mt = (s >> 6) & 7, ksl = s >> 9;
        int row = mblk * 128 + mt * 16 + (ln & 15);
        if (row >= M) row = M - 1;
        int kk = ksl * 32 + (ln >> 4) * 8;
        gload_lds16(A + (size_t)row * K + kk, &smem[s - ln]);
    }
    if (zf) {                                    // zero-fill slice (overlaps staging)
        float* zb = zf;
        int cz = c;
        if (cz >= 4) { zb += (size_t)NN * 128; cz -= 4; }
        #pragma unroll
        for (int i = 0; i < 4; ++i) {
            int f = t + 256 * i;                 // float4 idx in [0,1024)
            int row = f >> 3, c4 = f & 7;
            int grow = mblk * 128 + row;
            if (grow < M) {
                float4 z; z.x = 0.f; z.y = 0.f; z.z = 0.f; z.w = 0.f;
                *(float4*)(zb + (size_t)grow * 128 + cz * 32 + c4 * 4) = z;
            }
        }
    }
    __syncthreads();

    f32x4 acc[4][4] = {};
    #pragma unroll
    for (int ksl = 0; ksl < KS; ++ksl) {
        uint4 wa[4];
        #pragma unroll
        for (int mi = 0; mi < 4; ++mi)
            wa[mi] = wfrag[(size_t)((c * KS + ksl) * 8 + mh * 4 + mi) * 64 + l];
        bf16x8 bn[4];
        #pragma unroll
        for (int ni = 0; ni < 4; ++ni) { U16x8 u; u.u = smem[(ksl * 8 + nh * 4 + ni) * 64 + l]; bn[ni] = u.v; }
        #pragma unroll
        for (int mi = 0; mi < 4; ++mi) {
            U16x8 u; u.u = wa[mi];
            #pragma unroll
            for (int ni = 0; ni < 4; ++ni)
                acc[mi][ni] = __builtin_amdgcn_mfma_f32_16x16x32_bf16(u.v, bn[ni], acc[mi][ni], 0, 0, 0);
        }
    }
    float4 bb[4];
    #pragma unroll
    for (int mi = 0; mi < 4; ++mi) {
        if (bias) bb[mi] = *(const float4*)(bias + c * 128 + mh * 64 + mi * 16 + 4 * (l >> 4));
        else { bb[mi].x = 0.f; bb[mi].y = 0.f; bb[mi].z = 0.f; bb[mi].w = 0.f; }
    }
    #pragma unroll
    for (int ni = 0; ni < 4; ++ni) {
        int node = mblk * 128 + nh * 64 + ni * 16 + (l & 15);
        if (node >= M) continue;
        #pragma unroll
        for (int mi = 0; mi < 4; ++mi) {
            int col = c * 128 + mh * 64 + mi * 16 + 4 * (l >> 4);
            float v[4];
            const float* bf = &bb[mi].x;
            #pragma unroll
            for (int r = 0; r < 4; ++r) {
                v[r] = acc[mi][ni][r] + bf[r];
                if (RELU) v[r] = fmaxf(v[r], 0.f);
            }
            if (EPI == 0) {
                *(uint2*)(ob + (size_t)node * LDN + col) = pack4(v);
            } else {
                size_t a = (size_t)node * 128 + col;
                if (EPI == 2) {
                    float4 old = *(const float4*)(of + a);
                    v[0] += old.x; v[1] += old.y; v[2] += old.z; v[3] += old.w;
                }
                float4 s4; s4.x = v[0]; s4.y = v[1]; s4.z = v[2]; s4.w = v[3];
                *(float4*)(of + a) = s4;
                *(uint2*)(ob + a) = pack4(v);
            }
        }
    }
}

// ---------------------------------------------------------------------------
// Source functors for A-operand staging (gemm_k).
// ---------------------------------------------------------------------------
struct SrcBf16 {            // plain bf16 row-major [M][K], async-staged
    static constexpr bool DIRECT = true;
    const u16* A; int K;
    __device__ const void* gaddr(int row, int kk) const { return A + (size_t)row * K + kk; }
    __device__ bf16x8 operator()(int row, int kk) const {
        U16x8 u; u.u = *(const uint4*)(A + (size_t)row * K + kk); return u.v;
    }
};
struct SrcEnc {             // node encoder input: emb_node[x[row]] (f32 -> bf16)
    static constexpr bool DIRECT = false;
    const float* emb; const int* xids;
    __device__ const void* gaddr(int, int) const { return nullptr; }
    __device__ bf16x8 operator()(int row, int kk) const {
        int n = xids[row];
        const float* p = emb + (size_t)n * 256 + kk;
        float4 f0 = *(const float4*)p, f1 = *(const float4*)(p + 4);
        U16x8 r;
        r.s[0]=f2b(f0.x); r.s[1]=f2b(f0.y); r.s[2]=f2b(f0.z); r.s[3]=f2b(f0.w);
        r.s[4]=f2b(f1.x); r.s[5]=f2b(f1.y); r.s[6]=f2b(f1.z); r.s[7]=f2b(f1.w);
        return r.v;
    }
};
struct SrcUpd {             // [nodes | fi/deg | fo/deg] (f32 -> bf16), K=384
    static constexpr bool DIRECT = false;
    const float* nodes; const float* fi; const float* fo; const int* deg;
    __device__ const void* gaddr(int, int) const { return nullptr; }
    __device__ bf16x8 operator()(int row, int kk) const {
        const float* s; float sc = 1.f;
        if (kk < 128) s = nodes + (size_t)row * 128 + kk;
        else {
            int d = deg[row];
            sc = d > 0 ? 1.f / (float)d : 0.f;
            s = (kk < 256) ? fi + (size_t)row * 128 + (kk - 128)
                           : fo + (size_t)row * 128 + (kk - 256);
        }
        float4 f0 = *(const float4*)s, f1 = *(const float4*)(s + 4);
        U16x8 r;
        r.s[0]=f2b(f0.x*sc); r.s[1]=f2b(f0.y*sc); r.s[2]=f2b(f0.z*sc); r.s[3]=f2b(f0.w*sc);
        r.s[4]=f2b(f1.x*sc); r.s[5]=f2b(f1.y*sc); r.s[6]=f2b(f1.z*sc); r.s[7]=f2b(f1.w*sc);
        return r.v;
    }
};

struct EpiArgs { float* of; u16* ob; const int* idx; int ldN; };

// ---------------------------------------------------------------------------
// gemm_k: non-swapped MFMA (C rows register-resident); A + W staged to LDS.
// ---------------------------------------------------------------------------
template<int KDIM, int NBLK, int EPI, bool RELU, class SRC>
__global__ __launch_bounds__(256) void gemm_k(SRC src, const uint4* __restrict__ wfrag,
                                              const float* __restrict__ bias,
                                              EpiArgs ea, int M)
{
    constexpr int KS = KDIM / 32;
    constexpr int NPANEL = KDIM / 64;
    __shared__ uint4 smem[2048];
    const int t = threadIdx.x;
    const int l = t & 63;
    const int wv = t >> 6;
    const int mh = wv >> 1, nh = wv & 1;
    const int ell = xcd_swz(blockIdx.x, gridDim.x);
    const int mblk = ell / NBLK, nblk = ell % NBLK;

    f32x4 acc[4][4] = {};

    for (int p = 0; p < NPANEL; ++p) {
        __syncthreads();
        if constexpr (SRC::DIRECT) {
            #pragma unroll
            for (int i = 0; i < 4; ++i) {          // async A panel
                int s = t + 256 * i;
                int ln = s & 63, mt = (s >> 6) & 7, ksl = s >> 9;
                int row = mblk * 128 + mt * 16 + (ln & 15);
                if (row >= M) row = M - 1;
                int kk = p * 64 + ksl * 32 + (ln >> 4) * 8;
                gload_lds16(src.gaddr(row, kk), &smem[s - ln]);
            }
        } else {
            #pragma unroll
            for (int i = 0; i < 4; ++i) {          // computed A panel
                int s = t + 256 * i;
                int ln = s & 63, mt = (s >> 6) & 7, ksl = s >> 9;
                int row = mblk * 128 + mt * 16 + (ln & 15);
                if (row >= M) row = M - 1;
                int kk = p * 64 + ksl * 32 + (ln >> 4) * 8;
                U16x8 u; u.v = src(row, kk);
                smem[s] = u.u;
            }
        }
        {                                           // async W panel
            const uint4* wp = wfrag + (size_t)(nblk * KS + 2 * p) * 512;
            #pragma unroll
            for (int i = 0; i < 4; ++i) {
                int s = t + 256 * i;
                gload_lds16(wp + s, &smem[1024 + (s - (s & 63))]);
            }
        }
        __syncthreads();
        #pragma unroll
        for (int ksl = 0; ksl < 2; ++ksl) {
            bf16x8 a[4], b[4];
            #pragma unroll
            for (int mi = 0; mi < 4; ++mi) { U16x8 u; u.u = smem[(ksl*8 + mh*4 + mi)*64 + l]; a[mi] = u.v; }
            #pragma unroll
            for (int ni = 0; ni < 4; ++ni) { U16x8 u; u.u = smem[1024 + (ksl*8 + nh*4 + ni)*64 + l]; b[ni] = u.v; }
            #pragma unroll
            for (int mi = 0; mi < 4; ++mi)
                #pragma unroll
                for (int ni = 0; ni < 4; ++ni)
                    acc[mi][ni] = __builtin_amdgcn_mfma_f32_16x16x32_bf16(a[mi], b[ni], acc[mi][ni], 0, 0, 0);
        }
    }

    float bcol[4];
    #pragma unroll
    for (int ni = 0; ni < 4; ++ni)
        bcol[ni] = bias ? bias[nblk * 128 + nh * 64 + ni * 16 + (l & 15)] : 0.f;

    if constexpr (EPI == 0) {
        // bf16 store via XOR-swizzled LDS bounce
        __syncthreads();
        u16* bn = (u16*)smem;
        #pragma unroll
        for (int mi = 0; mi < 4; ++mi)
            #pragma unroll
            for (int ni = 0; ni < 4; ++ni)
                #pragma unroll
                for (int r = 0; r < 4; ++r) {
                    int rl = mh * 64 + mi * 16 + (l >> 4) * 4 + r;
                    int cl = nh * 64 + ni * 16 + (l & 15);
                    float v = acc[mi][ni][r] + bcol[ni];
                    if (RELU) v = fmaxf(v, 0.f);
                    int sx = (rl >> 2) & 7;
                    bn[rl * 128 + ((((cl >> 3) ^ sx)) << 3) + (cl & 7)] = f2b(v);
                }
        __syncthreads();
        int row = t >> 1, half = t & 1;
        int grow = mblk * 128 + row;
        if (grow < M) {
            int sx = (row >> 2) & 7;
            uint4* dst = (uint4*)(ea.ob + (size_t)grow * ea.ldN + nblk * 128 + half * 64);
            const uint4* sp = ((const uint4*)bn) + row * 16;
            #pragma unroll
            for (int i = 0; i < 8; ++i) dst[i] = sp[(half * 8 + i) ^ sx];
        }
    } else if constexpr (EPI == 3) {
        // segment-max: batch ids for this lane's 16 rows (within 64-row window)
        int g16[4][4];
        #pragma unroll
        for (int mi = 0; mi < 4; ++mi) {
            int rb = mblk * 128 + mh * 64 + mi * 16 + (l >> 4) * 4;
            #pragma unroll
            for (int r = 0; r < 4; ++r)
                g16[mi][r] = (rb + r < M) ? ea.idx[rb + r] : -1;
        }
        #pragma unroll
        for (int ni = 0; ni < 4; ++ni) {
            int colg = nblk * 128 + nh * 64 + ni * 16 + (l & 15);
            float mv = 0.f; int cg = -1;
            #pragma unroll
            for (int mi = 0; mi < 4; ++mi)
                #pragma unroll
                for (int r = 0; r < 4; ++r) {
                    float v = acc[mi][ni][r] + bcol[ni];
                    if (RELU) v = fmaxf(v, 0.f);
                    int g = g16[mi][r];
                    if (g != cg) {
                        if (cg >= 0) atomicMax((u32*)(ea.of + (size_t)cg * 1024 + colg), __float_as_uint(mv));
                        cg = g; mv = v;
                    } else mv = fmaxf(mv, v);
                }
            if (cg >= 0) atomicMax((u32*)(ea.of + (size_t)cg * 1024 + colg), __float_as_uint(mv));
        }
    }
}

// ---------------------------------------------------------------------------
// upd23: fused Wf2+Wf3 with conflict-free bounce swizzle (sx = rl&7) and
// native bf16 casts in the bounce.
// ---------------------------------------------------------------------------
__global__ __launch_bounds__(256) void upd23(
    const u16* __restrict__ U1, const uint4* __restrict__ W2f,
    const float* __restrict__ b2, const uint4* __restrict__ W3f,
    const float* __restrict__ b3, float* __restrict__ nodes,
    u16* __restrict__ nodesbf, int M)
{
    __shared__ uint4 smem[2048];   // 32 KB
    const int t = threadIdx.x, l = t & 63, wv = t >> 6;
    const int mh = wv >> 1, nh = wv & 1;
    const int mblk = xcd_swz(blockIdx.x, gridDim.x);

    f32x4 acc[4][4] = {};
    for (int p = 0; p < 4; ++p) {              // K=256: 4 panels
        __syncthreads();
        #pragma unroll
        for (int i = 0; i < 4; ++i) {          // async A panel from U1
            int s = t + 256 * i;
            int ln = s & 63, mt = (s >> 6) & 7, ksl = s >> 9;
            int row = mblk * 128 + mt * 16 + (ln & 15);
            if (row >= M) row = M - 1;
            int kk = p * 64 + ksl * 32 + (ln >> 4) * 8;
            gload_lds16(U1 + (size_t)row * 256 + kk, &smem[s - ln]);
        }
        {                                       // async W2 panel
            const uint4* wp = W2f + (size_t)(2 * p) * 512;
            #pragma unroll
            for (int i = 0; i < 4; ++i) {
                int s = t + 256 * i;
                gload_lds16(wp + s, &smem[1024 + (s - (s & 63))]);
            }
        }
        __syncthreads();
        #pragma unroll
        for (int ksl = 0; ksl < 2; ++ksl) {
            bf16x8 a[4], b[4];
            #pragma unroll
            for (int mi = 0; mi < 4; ++mi) { U16x8 u; u.u = smem[(ksl*8 + mh*4 + mi)*64 + l]; a[mi] = u.v; }
            #pragma unroll
            for (int ni = 0; ni < 4; ++ni) { U16x8 u; u.u = smem[1024 + (ksl*8 + nh*4 + ni)*64 + l]; b[ni] = u.v; }
            #pragma unroll
            for (int mi = 0; mi < 4; ++mi)
                #pragma unroll
                for (int ni = 0; ni < 4; ++ni)
                    acc[mi][ni] = __builtin_amdgcn_mfma_f32_16x16x32_bf16(a[mi], b[ni], acc[mi][ni], 0, 0, 0);
        }
    }

    // bounce h2 = relu(acc + b2), swizzled row-major bf16 [128][128], sx=rl&7
    float bc2[4];
    #pragma unroll
    for (int ni = 0; ni < 4; ++ni) bc2[ni] = b2[nh * 64 + ni * 16 + (l & 15)];
    __syncthreads();
    u16* bn = (u16*)smem;
    #pragma unroll
    for (int mi = 0; mi < 4; ++mi)
        #pragma unroll
        for (int ni = 0; ni < 4; ++ni)
            #pragma unroll
            for (int r = 0; r < 4; ++r) {
                int rl = mh * 64 + mi * 16 + (l >> 4) * 4 + r;
                int cl = nh * 64 + ni * 16 + (l & 15);
                float v = fmaxf(acc[mi][ni][r] + bc2[ni], 0.f);
                int sx = rl & 7;
                bn[rl * 128 + (((cl >> 3) ^ sx) << 3) + (cl & 7)] = f2bn(v);
            }
    __syncthreads();

    // K=128 phase: W3 per-lane direct (no barriers -> loads hoist)
    f32x4 acc2[4][4] = {};
    #pragma unroll
    for (int ks = 0; ks < 4; ++ks) {
        uint4 bw[4];
        #pragma unroll
        for (int ni = 0; ni < 4; ++ni)
            bw[ni] = W3f[(size_t)(ks * 8 + nh * 4 + ni) * 64 + l];
        bf16x8 a[4];
        #pragma unroll
        for (int mi = 0; mi < 4; ++mi) {
            int rl = (mh * 4 + mi) * 16 + (l & 15);
            int c0 = ks * 32 + (l >> 4) * 8;
            int sx = rl & 7;
            U16x8 u; u.u = *(const uint4*)&bn[rl * 128 + (((c0 >> 3) ^ sx) << 3)];
            a[mi] = u.v;
        }
        #pragma unroll
        for (int mi = 0; mi < 4; ++mi)
            #pragma unroll
            for (int ni = 0; ni < 4; ++ni) {
                U16x8 u; u.u = bw[ni];
                acc2[mi][ni] = __builtin_amdgcn_mfma_f32_16x16x32_bf16(a[mi], u.v, acc2[mi][ni], 0, 0, 0);
            }
    }

    // residual epilogue: nodes += relu(acc2 + b3); nodesbf mirror
    float bc3[4];
    #pragma unroll
    for (int ni = 0; ni < 4; ++ni) bc3[ni] = b3[nh * 64 + ni * 16 + (l & 15)];
    #pragma unroll
    for (int mi = 0; mi < 4; ++mi)
        #pragma unroll
        for (int r = 0; r < 4; ++r) {
            int row = mblk * 128 + mh * 64 + mi * 16 + (l >> 4) * 4 + r;
            if (row >= M) continue;
            #pragma unroll
            for (int ni = 0; ni < 4; ++ni) {
                int col = nh * 64 + ni * 16 + (l & 15);
                size_t a = (size_t)row * 128 + col;
                float v = nodes[a] + fmaxf(acc2[mi][ni][r] + bc3[ni], 0.f);
                nodes[a] = v;
                nodesbf[a] = f2bn(v);
            }
        }
}

// ---------------------------------------------------------------------------
// Fused per-edge pipeline (edges pre-sorted by idxA). blockIdx.y selects the
// parameter set. sT padded to stride 264 (bank spread); bounce swizzle sx=rl&7;
// native bf16 casts in assemble.
// ---------------------------------------------------------------------------
struct EdgePar {
    const float* T; const uint4* W2f; const float* b2;
    const uint4* W3f; const float* b3;
    const int* iA; const int* iB; const int* iC;
    float* agg; int base;
};

__global__ __launch_bounds__(256) void edge_fused(
    const u16* __restrict__ P, int ldP, EdgePar e0, EdgePar e1)
{
    __shared__ uint4 smA[2048];
    __shared__ int   sidx[3][128];
    __shared__ float sT[792];          // 3 x 264 (stride-264 pads banks)
    const int t = threadIdx.x;
    const int l = t & 63;
    const int wv = t >> 6;
    const int mh = wv >> 1, nh = wv & 1;
    const int base = xcd_swz(blockIdx.x, gridDim.x) * 128;
    const EdgePar ep = (blockIdx.y == 0) ? e0 : e1;

    if (t < 128) {
        int e = (base + t < NE) ? base + t : NE - 1;
        sidx[0][t] = ep.iA[e];
        sidx[1][t] = ep.iB[e];
        sidx[2][t] = ep.iC[e];
    }
    for (int i = t; i < 792; i += 256) {
        int a = i / 264, j = i - a * 264;
        sT[i] = (j < 256) ? ep.T[a * 256 + j] : 0.f;
    }
    __syncthreads();

    const int rt0 = wv * 16 + (l & 15);
    const int rt1 = (wv + 4) * 16 + (l & 15);
    const int klo = (l >> 4) * 8;
    const u16* pA[2] = { P + (size_t)sidx[0][rt0] * ldP + ep.base,
                         P + (size_t)sidx[0][rt1] * ldP + ep.base };
    const u16* pB[2] = { P + (size_t)sidx[1][rt0] * ldP + ep.base + 256,
                         P + (size_t)sidx[1][rt1] * ldP + ep.base + 256 };
    const float* pT[2] = { sT + sidx[2][rt0] * 264, sT + sidx[2][rt1] * 264 };

    uint4 ra[4], rb[4];
    #pragma unroll
    for (int i = 0; i < 4; ++i) {
        int kk = (i >> 1) * 32 + klo;
        ra[i] = *(const uint4*)(pA[i & 1] + kk);
        rb[i] = *(const uint4*)(pB[i & 1] + kk);
    }

    f32x4 acc[4][4] = {};
    #pragma unroll
    for (int p = 0; p < 4; ++p) {
        #pragma unroll
        for (int i = 0; i < 4; ++i) {
            int kk = (i >> 1) * 32 + klo;
            U16x8 ua, ub, r;
            ua.u = ra[i]; ub.u = rb[i];
            const float* tb = pT[i & 1] + p * 64 + kk;
            #pragma unroll
            for (int j = 0; j < 8; ++j) {
                float v = b2f(ua.s[j]) + b2f(ub.s[j]) + tb[j];
                r.v[j] = (__bf16)fmaxf(v, 0.f);
            }
            smA[(p & 1) * 1024 + t + 256 * i] = r.u;
            if (p < 3) {
                int kn = (p + 1) * 64 + kk;
                ra[i] = *(const uint4*)(pA[i & 1] + kn);
                rb[i] = *(const uint4*)(pB[i & 1] + kn);
            }
        }
        asm volatile("s_waitcnt lgkmcnt(0)" ::: "memory");
        __builtin_amdgcn_s_barrier();
        uint4 bw[2][4];
        #pragma unroll
        for (int ksl = 0; ksl < 2; ++ksl)
            #pragma unroll
            for (int ni = 0; ni < 4; ++ni)
                bw[ksl][ni] = ep.W2f[(size_t)((p * 2 + ksl) * 8 + nh * 4 + ni) * 64 + l];
        #pragma unroll
        for (int ksl = 0; ksl < 2; ++ksl) {
            bf16x8 a[4];
            #pragma unroll
            for (int mi = 0; mi < 4; ++mi) { U16x8 u; u.u = smA[(p & 1) * 1024 + (ksl*8 + mh*4 + mi)*64 + l]; a[mi] = u.v; }
            #pragma unroll
            for (int mi = 0; mi < 4; ++mi)
                #pragma unroll
                for (int ni = 0; ni < 4; ++ni) {
                    U16x8 u; u.u = bw[ksl][ni];
                    acc[mi][ni] = __builtin_amdgcn_mfma_f32_16x16x32_bf16(a[mi], u.v, acc[mi][ni], 0, 0, 0);
                }
        }
    }

    float bc2[4];
    #pragma unroll
    for (int ni = 0; ni < 4; ++ni) bc2[ni] = ep.b2[nh * 64 + ni * 16 + (l & 15)];
    __builtin_amdgcn_s_barrier();
    u16* bn = (u16*)smA;
    #pragma unroll
    for (int mi = 0; mi < 4; ++mi)
        #pragma unroll
        for (int ni = 0; ni < 4; ++ni)
            #pragma unroll
            for (int r = 0; r < 4; ++r) {
                int rl = mh * 64 + mi * 16 + (l >> 4) * 4 + r;
                int cl = nh * 64 + ni * 16 + (l & 15);
                float v = fmaxf(acc[mi][ni][r] + bc2[ni], 0.f);
                int sx = rl & 7;
                bn[rl * 128 + (((cl >> 3) ^ sx) << 3) + (cl & 7)] = f2bn(v);
            }
    asm volatile("s_waitcnt lgkmcnt(0)" ::: "memory");
    __builtin_amdgcn_s_barrier();

    f32x4 acc2[4][4] = {};
    #pragma unroll
    for (int ks = 0; ks < 4; ++ks) {
        uint4 bw[4];
        #pragma unroll
        for (int ni = 0; ni < 4; ++ni)
            bw[ni] = ep.W3f[(size_t)(ks * 8 + nh * 4 + ni) * 64 + l];
        bf16x8 a[4];
        #pragma unroll
        for (int mi = 0; mi < 4; ++mi) {
            int rl = (mh * 4 + mi) * 16 + (l & 15);
            int c0 = ks * 32 + (l >> 4) * 8;
            int sx = rl & 7;
            U16x8 u; u.u = *(const uint4*)&bn[rl * 128 + (((c0 >> 3) ^ sx) << 3)];
            a[mi] = u.v;
        }
        #pragma unroll
        for (int mi = 0; mi < 4; ++mi)
            #pragma unroll
            for (int ni = 0; ni < 4; ++ni) {
                U16x8 u; u.u = bw[ni];
                acc2[mi][ni] = __builtin_amdgcn_mfma_f32_16x16x32_bf16(a[mi], u.v, acc2[mi][ni], 0, 0, 0);
            }
    }

    float bc3[4];
    #pragma unroll
    for (int ni = 0; ni < 4; ++ni) bc3[ni] = ep.b3[nh * 64 + ni * 16 + (l & 15)];
    #pragma unroll
    for (int mi = 0; mi < 4; ++mi) {
        int rt4 = mh * 64 + mi * 16 + (l >> 4) * 4;
        int nd[4];
        #pragma unroll
        for (int r = 0; r < 4; ++r)
            nd[r] = (base + rt4 + r < NE) ? sidx[0][rt4 + r] : -1;
        #pragma unroll
        for (int ni = 0; ni < 4; ++ni) {
            int col = nh * 64 + ni * 16 + (l & 15);
            float mv = 0.f; int cg = -1;
            #pragma unroll
            for (int r = 0; r < 4; ++r) {
                float v = fmaxf(acc2[mi][ni][r] + bc3[ni], 0.f);
                if (nd[r] != cg) {
                    if (cg >= 0) atomicAdd(ep.agg + (size_t)cg * 128 + col, mv);
                    cg = nd[r]; mv = v;
                } else mv += v;
            }
            if (cg >= 0) atomicAdd(ep.agg + (size_t)cg * 128 + col, mv);
        }
    }
}

// ---------------------------------------------------------------------------
// Fused counting sort, both keys (parent=dst, child=src).
// ---------------------------------------------------------------------------
__global__ void hist2_kernel(const int* __restrict__ dstI, const int* __restrict__ srcI,
                             int* __restrict__ hist)
{
    int i = blockIdx.x * 256 + threadIdx.x;
    if (i < NE) atomicAdd(&hist[dstI[i]], 1);
    else if (i < 2 * NE) atomicAdd(&hist[NBINS + srcI[i - NE]], 1);
}
__global__ void chunk_sum(const int* __restrict__ h, int* __restrict__ part)
{
    __shared__ int sh[256];
    int t = threadIdx.x, b = blockIdx.x;
    sh[t] = h[b * 256 + t];
    __syncthreads();
    for (int o = 128; o > 0; o >>= 1) { if (t < o) sh[t] += sh[t + o]; __syncthreads(); }
    if (t == 0) part[b] = sh[0];
}
__global__ void scan_part2(int* part)
{
    __shared__ int sh[256];
    int t = threadIdx.x, b = blockIdx.x;
    int* p = part + b * NPART;
    sh[t] = (t < NPART) ? p[t] : 0;
    __syncthreads();
    for (int o = 1; o < 256; o <<= 1) {
        int x = (t >= o) ? sh[t - o] : 0;
        __syncthreads(); sh[t] += x; __syncthreads();
    }
    if (t < NPART) p[t] = (t ? sh[t - 1] : 0) + b * NE;
}
__global__ void mk_cursor(const int* __restrict__ h, const int* __restrict__ part,
                          int* __restrict__ cur)
{
    __shared__ int sh[256];
    int t = threadIdx.x, b = blockIdx.x;
    int v = h[b * 256 + t];
    sh[t] = v;
    __syncthreads();
    for (int o = 1; o < 256; o <<= 1) {
        int x = (t >= o) ? sh[t - o] : 0;
        __syncthreads(); sh[t] += x; __syncthreads();
    }
    cur[b * 256 + t] = part[b] + sh[t] - v;
}
__global__ void sort_scatter2(const int* __restrict__ dstI, const int* __restrict__ srcI,
                              const int* __restrict__ at, int* __restrict__ cur,
                              int* __restrict__ oA, int* __restrict__ oB, int* __restrict__ oC)
{
    int i = blockIdx.x * 256 + threadIdx.x;
    if (i < NE) {
        int k = dstI[i];
        int p = atomicAdd(&cur[k], 1);
        oA[p] = k; oB[p] = srcI[i]; oC[p] = at[i];
    } else if (i < 2 * NE) {
        int e = i - NE;
        int k = srcI[e];
        int p = atomicAdd(&cur[NBINS + k], 1);
        oA[p] = k; oB[p] = dstI[e]; oC[p] = at[e];
    }
}

// ---------------------------------------------------------------------------
// Mega weight packer: all 15 pack jobs in one launch.
// ---------------------------------------------------------------------------
struct PackPtrs { const float* p[13]; };

__global__ void pack_all(PackPtrs pp, uint4* __restrict__ frag)
{
    int tid = blockIdx.x * 256 + threadIdx.x;
    if (tid >= 126976) return;
    constexpr int NJ = 15;
    const int   start[NJ] = {0,4096,6144,10240,14336,18432,22528,26624,28672,32768,34816,47104,51200,53248,61440};
    const int   fbase[NJ] = {0,4096,6144,6144,14336,14336,22528,26624,28672,32768,34816,47104,51200,53248,61440};
    const short wsel [NJ] = {0,1,2,2,3,3,4,5,6,7,8,9,10,11,12};
    const short ldt  [NJ] = {128,128,256,256,256,256,128,128,128,128,256,128,128,512,1024};
    const short rot  [NJ] = {0,0,0,128,0,128,0,0,0,0,0,0,0,0,0};
    const short cot  [NJ] = {0,0,0,-256,0,-256,0,0,0,0,0,0,0,0,0};
    const short nbst [NJ] = {0,0,0,2,0,2,0,0,0,0,0,0,0,0,0};
    const short kst  [NJ] = {8,4,4,4,4,4,8,4,8,4,12,8,4,4,16};
    int j = 0;
    for (int i = NJ - 1; i >= 1; --i) if (tid >= start[i]) { j = i; break; }
    int rem = tid - start[j];
    int KS = kst[j];
    int nbrel = rem / (KS * 512);
    int r1 = rem % (KS * 512);
    int ks = r1 >> 9;
    int r2 = r1 & 511;
    int nt = r2 >> 6, l = r2 & 63;
    int nb = nbst[j] + nbrel;
    int k  = ks * 32 + (l >> 4) * 8;
    int ld = ldt[j];
    int col = nb * 128 + nt * 16 + (l & 15) + cot[j];
    const float* W = pp.p[wsel[j]];
    U16x8 u;
    #pragma unroll
    for (int jj = 0; jj < 8; ++jj) u.s[jj] = f2b(W[(size_t)(rot[j] + k + jj) * ld + col]);
    frag[fbase[j] + ((size_t)(nb * KS + ks) * 8 + nt) * 64 + l] = u.u;
}

// ---------------------------------------------------------------------------
// Edge-type tables, fused.
// ---------------------------------------------------------------------------
__global__ void enc_tab_kernel(const float* __restrict__ emb_edge,
                               const float* __restrict__ We1, const float* __restrict__ be1,
                               const float* __restrict__ We2, const float* __restrict__ be2,
                               const float* __restrict__ Wp1, const float* __restrict__ bp1,
                               const float* __restrict__ Wc1, const float* __restrict__ bc1,
                               float* __restrict__ Tp, float* __restrict__ Tc)
{
    __shared__ float h1[3][128];
    __shared__ float ea[3][128];
    const int t = threadIdx.x;   // 256
    if (t < 128) {
        for (int a = 0; a < 3; ++a) {
            float s = be1[t];
            for (int k = 0; k < 256; ++k) s = fmaf(emb_edge[a * 256 + k], We1[k * 128 + t], s);
            h1[a][t] = fmaxf(s, 0.f);
        }
    }
    __syncthreads();
    if (t < 128) {
        for (int a = 0; a < 3; ++a) {
            float s = be2[t];
            for (int k = 0; k < 128; ++k) s = fmaf(h1[a][k], We2[k * 128 + t], s);
            ea[a][t] = fmaxf(s, 0.f);
        }
    }
    __syncthreads();
    for (int a = 0; a < 3; ++a) {
        float sp = bp1[t], sc = bc1[t];
        for (int k = 0; k < 128; ++k) {
            float e = ea[a][k];
            sp = fmaf(e, Wp1[(size_t)(256 + k) * 256 + t], sp);
            sc = fmaf(e, Wc1[(size_t)(256 + k) * 256 + t], sc);
        }
        Tp[a * 256 + t] = sp;
        Tc[a * 256 + t] = sc;
    }
}

// ---------------------------------------------------------------------------
extern "C" void kernel_launch(void* const* d_in, const int* in_sizes, int n_in,
                              void* d_out, int out_size, void* d_ws, size_t ws_size,
                              hipStream_t stream)
{
    const int*   x          = (const int*)d_in[0];
    const int*   edge_index = (const int*)d_in[1];
    const int*   edge_attr  = (const int*)d_in[2];
    const int*   batch_vec  = (const int*)d_in[3];
    const float* emb_node   = (const float*)d_in[4];
    const float* Wn1 = (const float*)d_in[5];  const float* bn1 = (const float*)d_in[6];
    const float* Wn2 = (const float*)d_in[7];  const float* bn2 = (const float*)d_in[8];
    const float* emb_edge = (const float*)d_in[9];
    const float* We1 = (const float*)d_in[10]; const float* be1 = (const float*)d_in[11];
    const float* We2 = (const float*)d_in[12]; const float* be2 = (const float*)d_in[13];
    const float* Wp1 = (const float*)d_in[14]; const float* bp1 = (const float*)d_in[15];
    const float* Wp2 = (const float*)d_in[16]; const float* bp2 = (const float*)d_in[17];
    const float* Wp3 = (const float*)d_in[18]; const float* bp3 = (const float*)d_in[19];
    const float* Wc1 = (const float*)d_in[20]; const float* bc1 = (const float*)d_in[21];
    const float* Wc2 = (const float*)d_in[22]; const float* bc2 = (const float*)d_in[23];
    const float* Wc3 = (const float*)d_in[24]; const float* bc3 = (const float*)d_in[25];
    const float* Wf1 = (const float*)d_in[26]; const float* bf1 = (const float*)d_in[27];
    const float* Wf2 = (const float*)d_in[28]; const float* bf2 = (const float*)d_in[29];
    const float* Wf3 = (const float*)d_in[30]; const float* bf3 = (const float*)d_in[31];
    const float* Wo1 = (const float*)d_in[32]; const float* bo1 = (const float*)d_in[33];
    const float* Wo2 = (const float*)d_in[34]; const float* bo2 = (const float*)d_in[35];

    float* out = (float*)d_out;

    auto al = [](size_t b) { return (b + 255) & ~(size_t)255; };
    size_t fixed = al((size_t)NN*DD*4) + al((size_t)NN*DD*2) + al((size_t)NN*DD*4)
                 + al((size_t)NN*DD*4) + al((size_t)NN*256*2) + 2*al(3*256*4)
                 + al((size_t)126976*16) + 2*al((size_t)2*NBINS*4) + al((size_t)2*NPART*4)
                 + 3*al((size_t)2*NE*4);
    const bool wide = ws_size >= fixed + al((size_t)NN * 1024 * 2);

    char* w = (char*)d_ws;
    auto alloc = [&](size_t bytes) { char* p = w; w += (bytes + 255) & ~(size_t)255; return p; };
    float* nodes   = (float*)alloc((size_t)NN * DD * 4);
    u16*   nodesbf = (u16*)  alloc((size_t)NN * DD * 2);
    float* fi      = (float*)alloc((size_t)NN * DD * 4);
    float* fo      = (float*)alloc((size_t)NN * DD * 4);   // contiguous after fi
    u16*   P       = (u16*)  alloc((size_t)NN * (wide ? 1024 : 512) * 2);
    u16*   h2      = (u16*)  alloc((size_t)NN * 256 * 2);  // He / U1
    float* Tp      = (float*)alloc(3 * 256 * 4);
    float* Tc      = (float*)alloc(3 * 256 * 4);
    uint4* frag    = (uint4*)alloc((size_t)126976 * 16);
    int* hist = (int*)alloc((size_t)2 * NBINS * 4);        // [dst | src]; src half = deg
    int* part = (int*)alloc((size_t)2 * NPART * 4);
    int* cur  = (int*)alloc((size_t)2 * NBINS * 4);
    int* sA   = (int*)alloc((size_t)2 * NE * 4);           // [parent | child]
    int* sB   = (int*)alloc((size_t)2 * NE * 4);
    int* sC   = (int*)alloc((size_t)2 * NE * 4);

    u16* He = h2;                      // [50k][128]
    u16* U1 = h2;                      // [50k][256]
    u16* Hout1 = P;                    // [50k][512] (P contents dead by then)
    const int* degS = hist + NBINS;    // deg(src) as int

    uint4* Wn1f = frag;                // K256 N128
    uint4* Wn2f = Wn1f + 4096;         // K128 N128
    uint4* PWp  = Wn2f + 2048;         // K128 N512
    uint4* PWc  = PWp  + 8192;         // (contiguous after PWp)
    uint4* W2p  = PWc  + 8192;         // K256 N128
    uint4* W3p  = W2p  + 4096;         // K128 N128
    uint4* W2c  = W3p  + 2048;
    uint4* W3c  = W2c  + 4096;
    uint4* Wf1f = W3c  + 2048;         // K384 N256
    uint4* Wf2f = Wf1f + 12288;        // K256 N128
    uint4* Wf3f = Wf2f + 4096;         // K128 N128
    uint4* Wo1f = Wf3f + 2048;         // K128 N512
    uint4* Wo2f = Wo1f + 8192;         // K512 N1024

    const int* srcI = edge_index;
    const int* dstI = edge_index + NE;

    const int MB50 = (NN + 127) / 128;   // 391
    const int MBE  = (NE + 127) / 128;   // 1563

    // ---- prep --------------------------------------------------------------
    (void)hipMemsetAsync(d_out, 0, (size_t)out_size * 4, stream);
    (void)hipMemsetAsync(hist, 0, (size_t)2 * NBINS * 4, stream);

    PackPtrs pp;
    pp.p[0]=Wn1; pp.p[1]=Wn2; pp.p[2]=Wp1; pp.p[3]=Wc1; pp.p[4]=Wp2; pp.p[5]=Wp3;
    pp.p[6]=Wc2; pp.p[7]=Wc3; pp.p[8]=Wf1; pp.p[9]=Wf2; pp.p[10]=Wf3; pp.p[11]=Wo1; pp.p[12]=Wo2;
    pack_all<<<(126976 + 255) / 256, 256, 0, stream>>>(pp, frag);

    enc_tab_kernel<<<1, 256, 0, stream>>>(emb_edge, We1, be1, We2, be2,
                                          Wp1, bp1, Wc1, bc1, Tp, Tc);

    hist2_kernel<<<(2 * NE + 255) / 256, 256, 0, stream>>>(dstI, srcI, hist);
    chunk_sum<<<2 * NPART, 256, 0, stream>>>(hist, part);
    scan_part2<<<2, 256, 0, stream>>>(part);
    mk_cursor<<<2 * NPART, 256, 0, stream>>>(hist, part, cur);
    sort_scatter2<<<(2 * NE + 255) / 256, 256, 0, stream>>>(dstI, srcI, edge_attr, cur, sA, sB, sC);

    // ---- node encoder ------------------------------------------------------
    gemm_k<256, 1, 0, true, SrcEnc><<<MB50, 256, 0, stream>>>(
        SrcEnc{emb_node, x}, Wn1f, bn1, EpiArgs{nullptr, He, nullptr, 128}, NN);
    expand_k<128, 1, 1, true, 128><<<dim3(MB50, 1), 256, 0, stream>>>(
        He, Wn2f, bn2, nodes, nodesbf, nullptr, NN);

    EdgePar epP = { Tp, W2p, bp2, W3p, bp3, sA,      sB,      sC,      fi, 0 };
    EdgePar epC = { Tc, W2c, bc2, W3c, bc3, sA + NE, sB + NE, sC + NE, fo, wide ? 512 : 0 };

    // ---- message-passing iterations ---------------------------------------
    for (int it = 0; it < NITERS; ++it) {
        if (wide) {
            expand_k<128, 8, 0, false, 1024><<<dim3(MB50, 8), 256, 0, stream>>>(
                nodesbf, PWp, nullptr, nullptr, P, fi, NN);
            edge_fused<<<dim3(MBE, 2), 256, 0, stream>>>(P, 1024, epP, epC);
        } else {
            expand_k<128, 4, 0, false, 512><<<dim3(MB50, 4), 256, 0, stream>>>(
                nodesbf, PWp, nullptr, nullptr, P, fi, NN);
            edge_fused<<<dim3(MBE, 1), 256, 0, stream>>>(P, 512, epP, epP);
            expand_k<128, 4, 0, false, 512><<<dim3(MB50, 4), 256, 0, stream>>>(
                nodesbf, PWc, nullptr, nullptr, P, fo, NN);
            EdgePar epC2 = epC;
            edge_fused<<<dim3(MBE, 1), 256, 0, stream>>>(P, 512, epC2, epC2);
        }

        gemm_k<384, 2, 0, true, SrcUpd><<<MB50 * 2, 256, 0, stream>>>(
            SrcUpd{nodes, fi, fo, degS}, Wf1f, bf1, EpiArgs{nullptr, U1, nullptr, 256}, NN);
        upd23<<<MB50, 256, 0, stream>>>(U1, Wf2f, bf2, Wf3f, bf3, nodes, nodesbf, NN);
    }

    // ---- output head + global max pool -------------------------------------
    expand_k<128, 4, 0, true, 512><<<dim3(MB50, 4), 256, 0, stream>>>(
        nodesbf, Wo1f, bo1, nullptr, Hout1, nullptr, NN);
    gemm_k<512, 8, 3, true, SrcBf16><<<MB50 * 8, 256, 0, stream>>>(
        SrcBf16{Hout1, 512}, Wo2f, bo2, EpiArgs{out, nullptr, batch_vec, 1024}, NN);
}

// Round 15
// 783.452 us; speedup vs baseline: 1.2534x; 1.0281x over previous
//
#include <hip/hip_runtime.h>

#define NN 50000
#define NE 200000
#define DD 128
#define GG 256
#define NITERS 2
#define NBINS 50176          // 196 * 256, >= NN
#define NPART 196

typedef unsigned short u16;
typedef unsigned int u32;
typedef __bf16 bf16x8 __attribute__((ext_vector_type(8)));
typedef float f32x4 __attribute__((ext_vector_type(4)));

union U16x8 { uint4 u; bf16x8 v; u16 s[8]; };

__device__ __forceinline__ u16 f2b(float f) {             // f32 -> bf16 bits, RNE (manual)
    u32 u = __float_as_uint(f);
    return (u16)((u + 0x7FFFu + ((u >> 16) & 1u)) >> 16);
}
__device__ __forceinline__ u16 f2bn(float f) {            // native HW cvt (RNE)
    union { __bf16 b; u16 s; } u; u.b = (__bf16)f; return u.s;
}
__device__ __forceinline__ float b2f(u16 s) { return __uint_as_float(((u32)s) << 16); }

__device__ __forceinline__ uint2 pack4(const float* v) {
    uint2 r;
    r.x = (u32)f2bn(v[0]) | ((u32)f2bn(v[1]) << 16);
    r.y = (u32)f2bn(v[2]) | ((u32)f2bn(v[3]) << 16);
    return r;
}

// async global -> LDS, 16B per lane; lds must be the wave-uniform base slot
__device__ __forceinline__ void gload_lds16(const void* g, void* lds) {
    __builtin_amdgcn_global_load_lds((const __attribute__((address_space(1))) void*)g,
                                     (__attribute__((address_space(3))) void*)lds, 16, 0, 0);
}

// XCD-chunked bijective block swizzle (m204 form)
__device__ __forceinline__ int xcd_swz(int orig, int nwg) {
    int q = nwg >> 3, r = nwg & 7;
    int x = orig & 7, loc = orig >> 3;
    return (x < r ? x * (q + 1) : r * (q + 1) + (x - r) * q) + loc;
}

// ---------------------------------------------------------------------------
// expand_k: OUT[128 rows][cols c*128..] = epi(A[128][K] @ W + bias), c = blockIdx.y
// ---------------------------------------------------------------------------
template<int K, int NL, int EPI, bool RELU, int LDN>
__global__ __launch_bounds__(256) void expand_k(
    const u16* __restrict__ A, const uint4* __restrict__ wfrag,
    const float* __restrict__ bias, float* __restrict__ of, u16* __restrict__ ob,
    float* __restrict__ zf, int M)
{
    constexpr int KS = K / 32;
    __shared__ uint4 smem[K * 16];
    const int t = threadIdx.x, l = t & 63, wv = t >> 6;
    const int mh = wv >> 1, nh = wv & 1;
    const int mblk = blockIdx.x;
    const int c = blockIdx.y;

    #pragma unroll
    for (int i = 0; i < K / 16; ++i) {           // stage A once
        int s = t + 256 * i;
        int ln = s & 63, mt = (s >> 6) & 7, ksl = s >> 9;
        int row = mblk * 128 + mt * 16 + (ln & 15);
        if (row >= M) row = M - 1;
        int kk = ksl * 32 + (ln >> 4) * 8;
        gload_lds16(A + (size_t)row * K + kk, &smem[s - ln]);
    }
    if (zf) {                                    // zero-fill slice (overlaps staging)
        float* zb = zf;
        int cz = c;
        if (cz >= 4) { zb += (size_t)NN * 128; cz -= 4; }
        #pragma unroll
        for (int i = 0; i < 4; ++i) {
            int f = t + 256 * i;                 // float4 idx in [0,1024)
            int row = f >> 3, c4 = f & 7;
            int grow = mblk * 128 + row;
            if (grow < M) {
                float4 z; z.x = 0.f; z.y = 0.f; z.z = 0.f; z.w = 0.f;
                *(float4*)(zb + (size_t)grow * 128 + cz * 32 + c4 * 4) = z;
            }
        }
    }
    __syncthreads();

    f32x4 acc[4][4] = {};
    #pragma unroll
    for (int ksl = 0; ksl < KS; ++ksl) {
        uint4 wa[4];
        #pragma unroll
        for (int mi = 0; mi < 4; ++mi)
            wa[mi] = wfrag[(size_t)((c * KS + ksl) * 8 + mh * 4 + mi) * 64 + l];
        bf16x8 bn[4];
        #pragma unroll
        for (int ni = 0; ni < 4; ++ni) { U16x8 u; u.u = smem[(ksl * 8 + nh * 4 + ni) * 64 + l]; bn[ni] = u.v; }
        #pragma unroll
        for (int mi = 0; mi < 4; ++mi) {
            U16x8 u; u.u = wa[mi];
            #pragma unroll
            for (int ni = 0; ni < 4; ++ni)
                acc[mi][ni] = __builtin_amdgcn_mfma_f32_16x16x32_bf16(u.v, bn[ni], acc[mi][ni], 0, 0, 0);
        }
    }
    float4 bb[4];
    #pragma unroll
    for (int mi = 0; mi < 4; ++mi) {
        if (bias) bb[mi] = *(const float4*)(bias + c * 128 + mh * 64 + mi * 16 + 4 * (l >> 4));
        else { bb[mi].x = 0.f; bb[mi].y = 0.f; bb[mi].z = 0.f; bb[mi].w = 0.f; }
    }
    #pragma unroll
    for (int ni = 0; ni < 4; ++ni) {
        int node = mblk * 128 + nh * 64 + ni * 16 + (l & 15);
        if (node >= M) continue;
        #pragma unroll
        for (int mi = 0; mi < 4; ++mi) {
            int col = c * 128 + mh * 64 + mi * 16 + 4 * (l >> 4);
            float v[4];
            const float* bf = &bb[mi].x;
            #pragma unroll
            for (int r = 0; r < 4; ++r) {
                v[r] = acc[mi][ni][r] + bf[r];
                if (RELU) v[r] = fmaxf(v[r], 0.f);
            }
            if (EPI == 0) {
                *(uint2*)(ob + (size_t)node * LDN + col) = pack4(v);
            } else {
                size_t a = (size_t)node * 128 + col;
                if (EPI == 2) {
                    float4 old = *(const float4*)(of + a);
                    v[0] += old.x; v[1] += old.y; v[2] += old.z; v[3] += old.w;
                }
                float4 s4; s4.x = v[0]; s4.y = v[1]; s4.z = v[2]; s4.w = v[3];
                *(float4*)(of + a) = s4;
                *(uint2*)(ob + a) = pack4(v);
            }
        }
    }
}

// ---------------------------------------------------------------------------
// Source functors for A-operand staging (gemm_k).
// ---------------------------------------------------------------------------
struct SrcBf16 {            // plain bf16 row-major [M][K], async-staged
    static constexpr bool DIRECT = true;
    const u16* A; int K;
    __device__ const void* gaddr(int row, int kk) const { return A + (size_t)row * K + kk; }
    __device__ bf16x8 operator()(int row, int kk) const {
        U16x8 u; u.u = *(const uint4*)(A + (size_t)row * K + kk); return u.v;
    }
};
struct SrcEnc {             // node encoder input: emb_node[x[row]] (f32 -> bf16)
    static constexpr bool DIRECT = false;
    const float* emb; const int* xids;
    __device__ const void* gaddr(int, int) const { return nullptr; }
    __device__ bf16x8 operator()(int row, int kk) const {
        int n = xids[row];
        const float* p = emb + (size_t)n * 256 + kk;
        float4 f0 = *(const float4*)p, f1 = *(const float4*)(p + 4);
        U16x8 r;
        r.s[0]=f2bn(f0.x); r.s[1]=f2bn(f0.y); r.s[2]=f2bn(f0.z); r.s[3]=f2bn(f0.w);
        r.s[4]=f2bn(f1.x); r.s[5]=f2bn(f1.y); r.s[6]=f2bn(f1.z); r.s[7]=f2bn(f1.w);
        return r.v;
    }
};
struct SrcUpd {             // [nodes | fi/deg | fo/deg] (f32 -> bf16), K=384
    static constexpr bool DIRECT = false;
    const float* nodes; const float* fi; const float* fo; const int* deg;
    __device__ const void* gaddr(int, int) const { return nullptr; }
    __device__ bf16x8 operator()(int row, int kk) const {
        const float* s; float sc = 1.f;
        if (kk < 128) s = nodes + (size_t)row * 128 + kk;
        else {
            int d = deg[row];
            sc = d > 0 ? 1.f / (float)d : 0.f;
            s = (kk < 256) ? fi + (size_t)row * 128 + (kk - 128)
                           : fo + (size_t)row * 128 + (kk - 256);
        }
        float4 f0 = *(const float4*)s, f1 = *(const float4*)(s + 4);
        U16x8 r;
        r.s[0]=f2bn(f0.x*sc); r.s[1]=f2bn(f0.y*sc); r.s[2]=f2bn(f0.z*sc); r.s[3]=f2bn(f0.w*sc);
        r.s[4]=f2bn(f1.x*sc); r.s[5]=f2bn(f1.y*sc); r.s[6]=f2bn(f1.z*sc); r.s[7]=f2bn(f1.w*sc);
        return r.v;
    }
};

struct EpiArgs { float* of; u16* ob; const int* idx; int ldN; };

// ---------------------------------------------------------------------------
// gemm_k: non-swapped MFMA (C rows register-resident); A + W staged to LDS.
// ---------------------------------------------------------------------------
template<int KDIM, int NBLK, int EPI, bool RELU, class SRC>
__global__ __launch_bounds__(256) void gemm_k(SRC src, const uint4* __restrict__ wfrag,
                                              const float* __restrict__ bias,
                                              EpiArgs ea, int M)
{
    constexpr int KS = KDIM / 32;
    constexpr int NPANEL = KDIM / 64;
    __shared__ uint4 smem[2048];
    const int t = threadIdx.x;
    const int l = t & 63;
    const int wv = t >> 6;
    const int mh = wv >> 1, nh = wv & 1;
    const int ell = xcd_swz(blockIdx.x, gridDim.x);
    const int mblk = ell / NBLK, nblk = ell % NBLK;

    f32x4 acc[4][4] = {};

    for (int p = 0; p < NPANEL; ++p) {
        __syncthreads();
        if constexpr (SRC::DIRECT) {
            #pragma unroll
            for (int i = 0; i < 4; ++i) {          // async A panel
                int s = t + 256 * i;
                int ln = s & 63, mt = (s >> 6) & 7, ksl = s >> 9;
                int row = mblk * 128 + mt * 16 + (ln & 15);
                if (row >= M) row = M - 1;
                int kk = p * 64 + ksl * 32 + (ln >> 4) * 8;
                gload_lds16(src.gaddr(row, kk), &smem[s - ln]);
            }
        } else {
            #pragma unroll
            for (int i = 0; i < 4; ++i) {          // computed A panel
                int s = t + 256 * i;
                int ln = s & 63, mt = (s >> 6) & 7, ksl = s >> 9;
                int row = mblk * 128 + mt * 16 + (ln & 15);
                if (row >= M) row = M - 1;
                int kk = p * 64 + ksl * 32 + (ln >> 4) * 8;
                U16x8 u; u.v = src(row, kk);
                smem[s] = u.u;
            }
        }
        {                                           // async W panel
            const uint4* wp = wfrag + (size_t)(nblk * KS + 2 * p) * 512;
            #pragma unroll
            for (int i = 0; i < 4; ++i) {
                int s = t + 256 * i;
                gload_lds16(wp + s, &smem[1024 + (s - (s & 63))]);
            }
        }
        __syncthreads();
        #pragma unroll
        for (int ksl = 0; ksl < 2; ++ksl) {
            bf16x8 a[4], b[4];
            #pragma unroll
            for (int mi = 0; mi < 4; ++mi) { U16x8 u; u.u = smem[(ksl*8 + mh*4 + mi)*64 + l]; a[mi] = u.v; }
            #pragma unroll
            for (int ni = 0; ni < 4; ++ni) { U16x8 u; u.u = smem[1024 + (ksl*8 + nh*4 + ni)*64 + l]; b[ni] = u.v; }
            #pragma unroll
            for (int mi = 0; mi < 4; ++mi)
                #pragma unroll
                for (int ni = 0; ni < 4; ++ni)
                    acc[mi][ni] = __builtin_amdgcn_mfma_f32_16x16x32_bf16(a[mi], b[ni], acc[mi][ni], 0, 0, 0);
        }
    }

    float bcol[4];
    #pragma unroll
    for (int ni = 0; ni < 4; ++ni)
        bcol[ni] = bias ? bias[nblk * 128 + nh * 64 + ni * 16 + (l & 15)] : 0.f;

    if constexpr (EPI == 0) {
        // bf16 store via XOR-swizzled LDS bounce
        __syncthreads();
        u16* bn = (u16*)smem;
        #pragma unroll
        for (int mi = 0; mi < 4; ++mi)
            #pragma unroll
            for (int ni = 0; ni < 4; ++ni)
                #pragma unroll
                for (int r = 0; r < 4; ++r) {
                    int rl = mh * 64 + mi * 16 + (l >> 4) * 4 + r;
                    int cl = nh * 64 + ni * 16 + (l & 15);
                    float v = acc[mi][ni][r] + bcol[ni];
                    if (RELU) v = fmaxf(v, 0.f);
                    int sx = (rl >> 2) & 7;
                    bn[rl * 128 + ((((cl >> 3) ^ sx)) << 3) + (cl & 7)] = f2b(v);
                }
        __syncthreads();
        int row = t >> 1, half = t & 1;
        int grow = mblk * 128 + row;
        if (grow < M) {
            int sx = (row >> 2) & 7;
            uint4* dst = (uint4*)(ea.ob + (size_t)grow * ea.ldN + nblk * 128 + half * 64);
            const uint4* sp = ((const uint4*)bn) + row * 16;
            #pragma unroll
            for (int i = 0; i < 8; ++i) dst[i] = sp[(half * 8 + i) ^ sx];
        }
    } else if constexpr (EPI == 3) {
        // segment-max: batch ids for this lane's 16 rows (within 64-row window)
        int g16[4][4];
        #pragma unroll
        for (int mi = 0; mi < 4; ++mi) {
            int rb = mblk * 128 + mh * 64 + mi * 16 + (l >> 4) * 4;
            #pragma unroll
            for (int r = 0; r < 4; ++r)
                g16[mi][r] = (rb + r < M) ? ea.idx[rb + r] : -1;
        }
        #pragma unroll
        for (int ni = 0; ni < 4; ++ni) {
            int colg = nblk * 128 + nh * 64 + ni * 16 + (l & 15);
            float mv = 0.f; int cg = -1;
            #pragma unroll
            for (int mi = 0; mi < 4; ++mi)
                #pragma unroll
                for (int r = 0; r < 4; ++r) {
                    float v = acc[mi][ni][r] + bcol[ni];
                    if (RELU) v = fmaxf(v, 0.f);
                    int g = g16[mi][r];
                    if (g != cg) {
                        if (cg >= 0) atomicMax((u32*)(ea.of + (size_t)cg * 1024 + colg), __float_as_uint(mv));
                        cg = g; mv = v;
                    } else mv = fmaxf(mv, v);
                }
            if (cg >= 0) atomicMax((u32*)(ea.of + (size_t)cg * 1024 + colg), __float_as_uint(mv));
        }
    }
}

// ---------------------------------------------------------------------------
// upd23: fused Wf2+Wf3 (conflict-free bounce swizzle, native bf16 casts).
// ---------------------------------------------------------------------------
__global__ __launch_bounds__(256) void upd23(
    const u16* __restrict__ U1, const uint4* __restrict__ W2f,
    const float* __restrict__ b2, const uint4* __restrict__ W3f,
    const float* __restrict__ b3, float* __restrict__ nodes,
    u16* __restrict__ nodesbf, int M)
{
    __shared__ uint4 smem[2048];   // 32 KB
    const int t = threadIdx.x, l = t & 63, wv = t >> 6;
    const int mh = wv >> 1, nh = wv & 1;
    const int mblk = xcd_swz(blockIdx.x, gridDim.x);

    f32x4 acc[4][4] = {};
    for (int p = 0; p < 4; ++p) {              // K=256: 4 panels
        __syncthreads();
        #pragma unroll
        for (int i = 0; i < 4; ++i) {          // async A panel from U1
            int s = t + 256 * i;
            int ln = s & 63, mt = (s >> 6) & 7, ksl = s >> 9;
            int row = mblk * 128 + mt * 16 + (ln & 15);
            if (row >= M) row = M - 1;
            int kk = p * 64 + ksl * 32 + (ln >> 4) * 8;
            gload_lds16(U1 + (size_t)row * 256 + kk, &smem[s - ln]);
        }
        {                                       // async W2 panel
            const uint4* wp = W2f + (size_t)(2 * p) * 512;
            #pragma unroll
            for (int i = 0; i < 4; ++i) {
                int s = t + 256 * i;
                gload_lds16(wp + s, &smem[1024 + (s - (s & 63))]);
            }
        }
        __syncthreads();
        #pragma unroll
        for (int ksl = 0; ksl < 2; ++ksl) {
            bf16x8 a[4], b[4];
            #pragma unroll
            for (int mi = 0; mi < 4; ++mi) { U16x8 u; u.u = smem[(ksl*8 + mh*4 + mi)*64 + l]; a[mi] = u.v; }
            #pragma unroll
            for (int ni = 0; ni < 4; ++ni) { U16x8 u; u.u = smem[1024 + (ksl*8 + nh*4 + ni)*64 + l]; b[ni] = u.v; }
            #pragma unroll
            for (int mi = 0; mi < 4; ++mi)
                #pragma unroll
                for (int ni = 0; ni < 4; ++ni)
                    acc[mi][ni] = __builtin_amdgcn_mfma_f32_16x16x32_bf16(a[mi], b[ni], acc[mi][ni], 0, 0, 0);
        }
    }

    // bounce h2 = relu(acc + b2), swizzled row-major bf16 [128][128], sx=rl&7
    float bc2[4];
    #pragma unroll
    for (int ni = 0; ni < 4; ++ni) bc2[ni] = b2[nh * 64 + ni * 16 + (l & 15)];
    __syncthreads();
    u16* bn = (u16*)smem;
    #pragma unroll
    for (int mi = 0; mi < 4; ++mi)
        #pragma unroll
        for (int ni = 0; ni < 4; ++ni)
            #pragma unroll
            for (int r = 0; r < 4; ++r) {
                int rl = mh * 64 + mi * 16 + (l >> 4) * 4 + r;
                int cl = nh * 64 + ni * 16 + (l & 15);
                float v = fmaxf(acc[mi][ni][r] + bc2[ni], 0.f);
                int sx = rl & 7;
                bn[rl * 128 + (((cl >> 3) ^ sx) << 3) + (cl & 7)] = f2bn(v);
            }
    __syncthreads();

    // K=128 phase: W3 per-lane direct (no barriers -> loads hoist)
    f32x4 acc2[4][4] = {};
    #pragma unroll
    for (int ks = 0; ks < 4; ++ks) {
        uint4 bw[4];
        #pragma unroll
        for (int ni = 0; ni < 4; ++ni)
            bw[ni] = W3f[(size_t)(ks * 8 + nh * 4 + ni) * 64 + l];
        bf16x8 a[4];
        #pragma unroll
        for (int mi = 0; mi < 4; ++mi) {
            int rl = (mh * 4 + mi) * 16 + (l & 15);
            int c0 = ks * 32 + (l >> 4) * 8;
            int sx = rl & 7;
            U16x8 u; u.u = *(const uint4*)&bn[rl * 128 + (((c0 >> 3) ^ sx) << 3)];
            a[mi] = u.v;
        }
        #pragma unroll
        for (int mi = 0; mi < 4; ++mi)
            #pragma unroll
            for (int ni = 0; ni < 4; ++ni) {
                U16x8 u; u.u = bw[ni];
                acc2[mi][ni] = __builtin_amdgcn_mfma_f32_16x16x32_bf16(a[mi], u.v, acc2[mi][ni], 0, 0, 0);
            }
    }

    // residual epilogue: nodes += relu(acc2 + b3); nodesbf mirror
    float bc3[4];
    #pragma unroll
    for (int ni = 0; ni < 4; ++ni) bc3[ni] = b3[nh * 64 + ni * 16 + (l & 15)];
    #pragma unroll
    for (int mi = 0; mi < 4; ++mi)
        #pragma unroll
        for (int r = 0; r < 4; ++r) {
            int row = mblk * 128 + mh * 64 + mi * 16 + (l >> 4) * 4 + r;
            if (row >= M) continue;
            #pragma unroll
            for (int ni = 0; ni < 4; ++ni) {
                int col = nh * 64 + ni * 16 + (l & 15);
                size_t a = (size_t)row * 128 + col;
                float v = nodes[a] + fmaxf(acc2[mi][ni][r] + bc3[ni], 0.f);
                nodes[a] = v;
                nodesbf[a] = f2bn(v);
            }
        }
}

// ---------------------------------------------------------------------------
// Fused per-edge pipeline. W2 fragment loads hoisted ABOVE the panel barrier
// (LDS-independent -> latency hidden under the assemble drain + barrier).
// ---------------------------------------------------------------------------
struct EdgePar {
    const float* T; const uint4* W2f; const float* b2;
    const uint4* W3f; const float* b3;
    const int* iA; const int* iB; const int* iC;
    float* agg; int base;
};

__global__ __launch_bounds__(256) void edge_fused(
    const u16* __restrict__ P, int ldP, EdgePar e0, EdgePar e1)
{
    __shared__ uint4 smA[2048];
    __shared__ int   sidx[3][128];
    __shared__ float sT[792];          // 3 x 264 (stride-264 pads banks)
    const int t = threadIdx.x;
    const int l = t & 63;
    const int wv = t >> 6;
    const int mh = wv >> 1, nh = wv & 1;
    const int base = xcd_swz(blockIdx.x, gridDim.x) * 128;
    const EdgePar ep = (blockIdx.y == 0) ? e0 : e1;

    if (t < 128) {
        int e = (base + t < NE) ? base + t : NE - 1;
        sidx[0][t] = ep.iA[e];
        sidx[1][t] = ep.iB[e];
        sidx[2][t] = ep.iC[e];
    }
    for (int i = t; i < 792; i += 256) {
        int a = i / 264, j = i - a * 264;
        sT[i] = (j < 256) ? ep.T[a * 256 + j] : 0.f;
    }
    __syncthreads();

    const int rt0 = wv * 16 + (l & 15);
    const int rt1 = (wv + 4) * 16 + (l & 15);
    const int klo = (l >> 4) * 8;
    const u16* pA[2] = { P + (size_t)sidx[0][rt0] * ldP + ep.base,
                         P + (size_t)sidx[0][rt1] * ldP + ep.base };
    const u16* pB[2] = { P + (size_t)sidx[1][rt0] * ldP + ep.base + 256,
                         P + (size_t)sidx[1][rt1] * ldP + ep.base + 256 };
    const float* pT[2] = { sT + sidx[2][rt0] * 264, sT + sidx[2][rt1] * 264 };

    uint4 ra[4], rb[4];
    #pragma unroll
    for (int i = 0; i < 4; ++i) {
        int kk = (i >> 1) * 32 + klo;
        ra[i] = *(const uint4*)(pA[i & 1] + kk);
        rb[i] = *(const uint4*)(pB[i & 1] + kk);
    }

    f32x4 acc[4][4] = {};
    #pragma unroll
    for (int p = 0; p < 4; ++p) {
        // W2 b-frags for this panel: issue FIRST (global, LDS-independent);
        // they ride out the assemble + lgkmcnt + barrier in flight.
        uint4 bw[2][4];
        #pragma unroll
        for (int ksl = 0; ksl < 2; ++ksl)
            #pragma unroll
            for (int ni = 0; ni < 4; ++ni)
                bw[ksl][ni] = ep.W2f[(size_t)((p * 2 + ksl) * 8 + nh * 4 + ni) * 64 + l];
        #pragma unroll
        for (int i = 0; i < 4; ++i) {
            int kk = (i >> 1) * 32 + klo;
            U16x8 ua, ub, r;
            ua.u = ra[i]; ub.u = rb[i];
            const float* tb = pT[i & 1] + p * 64 + kk;
            #pragma unroll
            for (int j = 0; j < 8; ++j) {
                float v = b2f(ua.s[j]) + b2f(ub.s[j]) + tb[j];
                r.v[j] = (__bf16)fmaxf(v, 0.f);
            }
            smA[(p & 1) * 1024 + t + 256 * i] = r.u;
            if (p < 3) {                          // prefetch panel p+1 gathers
                int kn = (p + 1) * 64 + kk;
                ra[i] = *(const uint4*)(pA[i & 1] + kn);
                rb[i] = *(const uint4*)(pB[i & 1] + kn);
            }
        }
        asm volatile("s_waitcnt lgkmcnt(0)" ::: "memory");
        __builtin_amdgcn_s_barrier();
        #pragma unroll
        for (int ksl = 0; ksl < 2; ++ksl) {
            bf16x8 a[4];
            #pragma unroll
            for (int mi = 0; mi < 4; ++mi) { U16x8 u; u.u = smA[(p & 1) * 1024 + (ksl*8 + mh*4 + mi)*64 + l]; a[mi] = u.v; }
            #pragma unroll
            for (int mi = 0; mi < 4; ++mi)
                #pragma unroll
                for (int ni = 0; ni < 4; ++ni) {
                    U16x8 u; u.u = bw[ksl][ni];
                    acc[mi][ni] = __builtin_amdgcn_mfma_f32_16x16x32_bf16(a[mi], u.v, acc[mi][ni], 0, 0, 0);
                }
        }
    }

    // W3 frags for ks=0: issue before the bounce drains (latency overlap)
    uint4 bw0[4];
    #pragma unroll
    for (int ni = 0; ni < 4; ++ni)
        bw0[ni] = ep.W3f[(size_t)(nh * 4 + ni) * 64 + l];

    float bc2[4];
    #pragma unroll
    for (int ni = 0; ni < 4; ++ni) bc2[ni] = ep.b2[nh * 64 + ni * 16 + (l & 15)];
    __builtin_amdgcn_s_barrier();
    u16* bn = (u16*)smA;
    #pragma unroll
    for (int mi = 0; mi < 4; ++mi)
        #pragma unroll
        for (int ni = 0; ni < 4; ++ni)
            #pragma unroll
            for (int r = 0; r < 4; ++r) {
                int rl = mh * 64 + mi * 16 + (l >> 4) * 4 + r;
                int cl = nh * 64 + ni * 16 + (l & 15);
                float v = fmaxf(acc[mi][ni][r] + bc2[ni], 0.f);
                int sx = rl & 7;
                bn[rl * 128 + (((cl >> 3) ^ sx) << 3) + (cl & 7)] = f2bn(v);
            }
    asm volatile("s_waitcnt lgkmcnt(0)" ::: "memory");
    __builtin_amdgcn_s_barrier();

    f32x4 acc2[4][4] = {};
    #pragma unroll
    for (int ks = 0; ks < 4; ++ks) {
        uint4 bw[4];
        if (ks == 0) {
            #pragma unroll
            for (int ni = 0; ni < 4; ++ni) bw[ni] = bw0[ni];
        } else {
            #pragma unroll
            for (int ni = 0; ni < 4; ++ni)
                bw[ni] = ep.W3f[(size_t)(ks * 8 + nh * 4 + ni) * 64 + l];
        }
        bf16x8 a[4];
        #pragma unroll
        for (int mi = 0; mi < 4; ++mi) {
            int rl = (mh * 4 + mi) * 16 + (l & 15);
            int c0 = ks * 32 + (l >> 4) * 8;
            int sx = rl & 7;
            U16x8 u; u.u = *(const uint4*)&bn[rl * 128 + (((c0 >> 3) ^ sx) << 3)];
            a[mi] = u.v;
        }
        #pragma unroll
        for (int mi = 0; mi < 4; ++mi)
            #pragma unroll
            for (int ni = 0; ni < 4; ++ni) {
                U16x8 u; u.u = bw[ni];
                acc2[mi][ni] = __builtin_amdgcn_mfma_f32_16x16x32_bf16(a[mi], u.v, acc2[mi][ni], 0, 0, 0);
            }
    }

    float bc3[4];
    #pragma unroll
    for (int ni = 0; ni < 4; ++ni) bc3[ni] = ep.b3[nh * 64 + ni * 16 + (l & 15)];
    #pragma unroll
    for (int mi = 0; mi < 4; ++mi) {
        int rt4 = mh * 64 + mi * 16 + (l >> 4) * 4;
        int nd[4];
        #pragma unroll
        for (int r = 0; r < 4; ++r)
            nd[r] = (base + rt4 + r < NE) ? sidx[0][rt4 + r] : -1;
        #pragma unroll
        for (int ni = 0; ni < 4; ++ni) {
            int col = nh * 64 + ni * 16 + (l & 15);
            float mv = 0.f; int cg = -1;
            #pragma unroll
            for (int r = 0; r < 4; ++r) {
                float v = fmaxf(acc2[mi][ni][r] + bc3[ni], 0.f);
                if (nd[r] != cg) {
                    if (cg >= 0) atomicAdd(ep.agg + (size_t)cg * 128 + col, mv);
                    cg = nd[r]; mv = v;
                } else mv += v;
            }
            if (cg >= 0) atomicAdd(ep.agg + (size_t)cg * 128 + col, mv);
        }
    }
}

// ---------------------------------------------------------------------------
// Fused counting sort, both keys (parent=dst, child=src).
// ---------------------------------------------------------------------------
__global__ void hist2_kernel(const int* __restrict__ dstI, const int* __restrict__ srcI,
                             int* __restrict__ hist)
{
    int i = blockIdx.x * 256 + threadIdx.x;
    if (i < NE) atomicAdd(&hist[dstI[i]], 1);
    else if (i < 2 * NE) atomicAdd(&hist[NBINS + srcI[i - NE]], 1);
}
__global__ void chunk_sum(const int* __restrict__ h, int* __restrict__ part)
{
    __shared__ int sh[256];
    int t = threadIdx.x, b = blockIdx.x;
    sh[t] = h[b * 256 + t];
    __syncthreads();
    for (int o = 128; o > 0; o >>= 1) { if (t < o) sh[t] += sh[t + o]; __syncthreads(); }
    if (t == 0) part[b] = sh[0];
}
__global__ void scan_part2(int* part)
{
    __shared__ int sh[256];
    int t = threadIdx.x, b = blockIdx.x;
    int* p = part + b * NPART;
    sh[t] = (t < NPART) ? p[t] : 0;
    __syncthreads();
    for (int o = 1; o < 256; o <<= 1) {
        int x = (t >= o) ? sh[t - o] : 0;
        __syncthreads(); sh[t] += x; __syncthreads();
    }
    if (t < NPART) p[t] = (t ? sh[t - 1] : 0) + b * NE;
}
__global__ void mk_cursor(const int* __restrict__ h, const int* __restrict__ part,
                          int* __restrict__ cur)
{
    __shared__ int sh[256];
    int t = threadIdx.x, b = blockIdx.x;
    int v = h[b * 256 + t];
    sh[t] = v;
    __syncthreads();
    for (int o = 1; o < 256; o <<= 1) {
        int x = (t >= o) ? sh[t - o] : 0;
        __syncthreads(); sh[t] += x; __syncthreads();
    }
    cur[b * 256 + t] = part[b] + sh[t] - v;
}
__global__ void sort_scatter2(const int* __restrict__ dstI, const int* __restrict__ srcI,
                              const int* __restrict__ at, int* __restrict__ cur,
                              int* __restrict__ oA, int* __restrict__ oB, int* __restrict__ oC)
{
    int i = blockIdx.x * 256 + threadIdx.x;
    if (i < NE) {
        int k = dstI[i];
        int p = atomicAdd(&cur[k], 1);
        oA[p] = k; oB[p] = srcI[i]; oC[p] = at[i];
    } else if (i < 2 * NE) {
        int e = i - NE;
        int k = srcI[e];
        int p = atomicAdd(&cur[NBINS + k], 1);
        oA[p] = k; oB[p] = dstI[e]; oC[p] = at[e];
    }
}

// ---------------------------------------------------------------------------
// Mega weight packer: all 15 pack jobs in one launch.
// ---------------------------------------------------------------------------
struct PackPtrs { const float* p[13]; };

__global__ void pack_all(PackPtrs pp, uint4* __restrict__ frag)
{
    int tid = blockIdx.x * 256 + threadIdx.x;
    if (tid >= 126976) return;
    constexpr int NJ = 15;
    const int   start[NJ] = {0,4096,6144,10240,14336,18432,22528,26624,28672,32768,34816,47104,51200,53248,61440};
    const int   fbase[NJ] = {0,4096,6144,6144,14336,14336,22528,26624,28672,32768,34816,47104,51200,53248,61440};
    const short wsel [NJ] = {0,1,2,2,3,3,4,5,6,7,8,9,10,11,12};
    const short ldt  [NJ] = {128,128,256,256,256,256,128,128,128,128,256,128,128,512,1024};
    const short rot  [NJ] = {0,0,0,128,0,128,0,0,0,0,0,0,0,0,0};
    const short cot  [NJ] = {0,0,0,-256,0,-256,0,0,0,0,0,0,0,0,0};
    const short nbst [NJ] = {0,0,0,2,0,2,0,0,0,0,0,0,0,0,0};
    const short kst  [NJ] = {8,4,4,4,4,4,8,4,8,4,12,8,4,4,16};
    int j = 0;
    for (int i = NJ - 1; i >= 1; --i) if (tid >= start[i]) { j = i; break; }
    int rem = tid - start[j];
    int KS = kst[j];
    int nbrel = rem / (KS * 512);
    int r1 = rem % (KS * 512);
    int ks = r1 >> 9;
    int r2 = r1 & 511;
    int nt = r2 >> 6, l = r2 & 63;
    int nb = nbst[j] + nbrel;
    int k  = ks * 32 + (l >> 4) * 8;
    int ld = ldt[j];
    int col = nb * 128 + nt * 16 + (l & 15) + cot[j];
    const float* W = pp.p[wsel[j]];
    U16x8 u;
    #pragma unroll
    for (int jj = 0; jj < 8; ++jj) u.s[jj] = f2b(W[(size_t)(rot[j] + k + jj) * ld + col]);
    frag[fbase[j] + ((size_t)(nb * KS + ks) * 8 + nt) * 64 + l] = u.u;
}

// ---------------------------------------------------------------------------
// Edge-type tables, fused.
// ---------------------------------------------------------------------------
__global__ void enc_tab_kernel(const float* __restrict__ emb_edge,
                               const float* __restrict__ We1, const float* __restrict__ be1,
                               const float* __restrict__ We2, const float* __restrict__ be2,
                               const float* __restrict__ Wp1, const float* __restrict__ bp1,
                               const float* __restrict__ Wc1, const float* __restrict__ bc1,
                               float* __restrict__ Tp, float* __restrict__ Tc)
{
    __shared__ float h1[3][128];
    __shared__ float ea[3][128];
    const int t = threadIdx.x;   // 256
    if (t < 128) {
        for (int a = 0; a < 3; ++a) {
            float s = be1[t];
            for (int k = 0; k < 256; ++k) s = fmaf(emb_edge[a * 256 + k], We1[k * 128 + t], s);
            h1[a][t] = fmaxf(s, 0.f);
        }
    }
    __syncthreads();
    if (t < 128) {
        for (int a = 0; a < 3; ++a) {
            float s = be2[t];
            for (int k = 0; k < 128; ++k) s = fmaf(h1[a][k], We2[k * 128 + t], s);
            ea[a][t] = fmaxf(s, 0.f);
        }
    }
    __syncthreads();
    for (int a = 0; a < 3; ++a) {
        float sp = bp1[t], sc = bc1[t];
        for (int k = 0; k < 128; ++k) {
            float e = ea[a][k];
            sp = fmaf(e, Wp1[(size_t)(256 + k) * 256 + t], sp);
            sc = fmaf(e, Wc1[(size_t)(256 + k) * 256 + t], sc);
        }
        Tp[a * 256 + t] = sp;
        Tc[a * 256 + t] = sc;
    }
}

// ---------------------------------------------------------------------------
extern "C" void kernel_launch(void* const* d_in, const int* in_sizes, int n_in,
                              void* d_out, int out_size, void* d_ws, size_t ws_size,
                              hipStream_t stream)
{
    const int*   x          = (const int*)d_in[0];
    const int*   edge_index = (const int*)d_in[1];
    const int*   edge_attr  = (const int*)d_in[2];
    const int*   batch_vec  = (const int*)d_in[3];
    const float* emb_node   = (const float*)d_in[4];
    const float* Wn1 = (const float*)d_in[5];  const float* bn1 = (const float*)d_in[6];
    const float* Wn2 = (const float*)d_in[7];  const float* bn2 = (const float*)d_in[8];
    const float* emb_edge = (const float*)d_in[9];
    const float* We1 = (const float*)d_in[10]; const float* be1 = (const float*)d_in[11];
    const float* We2 = (const float*)d_in[12]; const float* be2 = (const float*)d_in[13];
    const float* Wp1 = (const float*)d_in[14]; const float* bp1 = (const float*)d_in[15];
    const float* Wp2 = (const float*)d_in[16]; const float* bp2 = (const float*)d_in[17];
    const float* Wp3 = (const float*)d_in[18]; const float* bp3 = (const float*)d_in[19];
    const float* Wc1 = (const float*)d_in[20]; const float* bc1 = (const float*)d_in[21];
    const float* Wc2 = (const float*)d_in[22]; const float* bc2 = (const float*)d_in[23];
    const float* Wc3 = (const float*)d_in[24]; const float* bc3 = (const float*)d_in[25];
    const float* Wf1 = (const float*)d_in[26]; const float* bf1 = (const float*)d_in[27];
    const float* Wf2 = (const float*)d_in[28]; const float* bf2 = (const float*)d_in[29];
    const float* Wf3 = (const float*)d_in[30]; const float* bf3 = (const float*)d_in[31];
    const float* Wo1 = (const float*)d_in[32]; const float* bo1 = (const float*)d_in[33];
    const float* Wo2 = (const float*)d_in[34]; const float* bo2 = (const float*)d_in[35];

    float* out = (float*)d_out;

    auto al = [](size_t b) { return (b + 255) & ~(size_t)255; };
    size_t fixed = al((size_t)NN*DD*4) + al((size_t)NN*DD*2) + al((size_t)NN*DD*4)
                 + al((size_t)NN*DD*4) + al((size_t)NN*256*2) + 2*al(3*256*4)
                 + al((size_t)126976*16) + 2*al((size_t)2*NBINS*4) + al((size_t)2*NPART*4)
                 + 3*al((size_t)2*NE*4);
    const bool wide = ws_size >= fixed + al((size_t)NN * 1024 * 2);

    char* w = (char*)d_ws;
    auto alloc = [&](size_t bytes) { char* p = w; w += (bytes + 255) & ~(size_t)255; return p; };
    float* nodes   = (float*)alloc((size_t)NN * DD * 4);
    u16*   nodesbf = (u16*)  alloc((size_t)NN * DD * 2);
    float* fi      = (float*)alloc((size_t)NN * DD * 4);
    float* fo      = (float*)alloc((size_t)NN * DD * 4);   // contiguous after fi
    u16*   P       = (u16*)  alloc((size_t)NN * (wide ? 1024 : 512) * 2);
    u16*   h2      = (u16*)  alloc((size_t)NN * 256 * 2);  // He / U1
    float* Tp      = (float*)alloc(3 * 256 * 4);
    float* Tc      = (float*)alloc(3 * 256 * 4);
    uint4* frag    = (uint4*)alloc((size_t)126976 * 16);
    int* hist = (int*)alloc((size_t)2 * NBINS * 4);        // [dst | src]; src half = deg
    int* part = (int*)alloc((size_t)2 * NPART * 4);
    int* cur  = (int*)alloc((size_t)2 * NBINS * 4);
    int* sA   = (int*)alloc((size_t)2 * NE * 4);           // [parent | child]
    int* sB   = (int*)alloc((size_t)2 * NE * 4);
    int* sC   = (int*)alloc((size_t)2 * NE * 4);

    u16* He = h2;                      // [50k][128]
    u16* U1 = h2;                      // [50k][256]
    u16* Hout1 = P;                    // [50k][512] (P contents dead by then)
    const int* degS = hist + NBINS;    // deg(src) as int

    uint4* Wn1f = frag;                // K256 N128
    uint4* Wn2f = Wn1f + 4096;         // K128 N128
    uint4* PWp  = Wn2f + 2048;         // K128 N512
    uint4* PWc  = PWp  + 8192;         // (contiguous after PWp)
    uint4* W2p  = PWc  + 8192;         // K256 N128
    uint4* W3p  = W2p  + 4096;         // K128 N128
    uint4* W2c  = W3p  + 2048;
    uint4* W3c  = W2c  + 4096;
    uint4* Wf1f = W3c  + 2048;         // K384 N256
    uint4* Wf2f = Wf1f + 12288;        // K256 N128
    uint4* Wf3f = Wf2f + 4096;         // K128 N128
    uint4* Wo1f = Wf3f + 2048;         // K128 N512
    uint4* Wo2f = Wo1f + 8192;         // K512 N1024

    const int* srcI = edge_index;
    const int* dstI = edge_index + NE;

    const int MB50 = (NN + 127) / 128;   // 391
    const int MBE  = (NE + 127) / 128;   // 1563

    // ---- prep --------------------------------------------------------------
    (void)hipMemsetAsync(d_out, 0, (size_t)out_size * 4, stream);
    (void)hipMemsetAsync(hist, 0, (size_t)2 * NBINS * 4, stream);

    PackPtrs pp;
    pp.p[0]=Wn1; pp.p[1]=Wn2; pp.p[2]=Wp1; pp.p[3]=Wc1; pp.p[4]=Wp2; pp.p[5]=Wp3;
    pp.p[6]=Wc2; pp.p[7]=Wc3; pp.p[8]=Wf1; pp.p[9]=Wf2; pp.p[10]=Wf3; pp.p[11]=Wo1; pp.p[12]=Wo2;
    pack_all<<<(126976 + 255) / 256, 256, 0, stream>>>(pp, frag);

    enc_tab_kernel<<<1, 256, 0, stream>>>(emb_edge, We1, be1, We2, be2,
                                          Wp1, bp1, Wc1, bc1, Tp, Tc);

    hist2_kernel<<<(2 * NE + 255) / 256, 256, 0, stream>>>(dstI, srcI, hist);
    chunk_sum<<<2 * NPART, 256, 0, stream>>>(hist, part);
    scan_part2<<<2, 256, 0, stream>>>(part);
    mk_cursor<<<2 * NPART, 256, 0, stream>>>(hist, part, cur);
    sort_scatter2<<<(2 * NE + 255) / 256, 256, 0, stream>>>(dstI, srcI, edge_attr, cur, sA, sB, sC);

    // ---- node encoder ------------------------------------------------------
    gemm_k<256, 1, 0, true, SrcEnc><<<MB50, 256, 0, stream>>>(
        SrcEnc{emb_node, x}, Wn1f, bn1, EpiArgs{nullptr, He, nullptr, 128}, NN);
    expand_k<128, 1, 1, true, 128><<<dim3(MB50, 1), 256, 0, stream>>>(
        He, Wn2f, bn2, nodes, nodesbf, nullptr, NN);

    EdgePar epP = { Tp, W2p, bp2, W3p, bp3, sA,      sB,      sC,      fi, 0 };
    EdgePar epC = { Tc, W2c, bc2, W3c, bc3, sA + NE, sB + NE, sC + NE, fo, wide ? 512 : 0 };

    // ---- message-passing iterations ---------------------------------------
    for (int it = 0; it < NITERS; ++it) {
        if (wide) {
            expand_k<128, 8, 0, false, 1024><<<dim3(MB50, 8), 256, 0, stream>>>(
                nodesbf, PWp, nullptr, nullptr, P, fi, NN);
            edge_fused<<<dim3(MBE, 2), 256, 0, stream>>>(P, 1024, epP, epC);
        } else {
            expand_k<128, 4, 0, false, 512><<<dim3(MB50, 4), 256, 0, stream>>>(
                nodesbf, PWp, nullptr, nullptr, P, fi, NN);
            edge_fused<<<dim3(MBE, 1), 256, 0, stream>>>(P, 512, epP, epP);
            expand_k<128, 4, 0, false, 512><<<dim3(MB50, 4), 256, 0, stream>>>(
                nodesbf, PWc, nullptr, nullptr, P, fo, NN);
            EdgePar epC2 = epC;
            edge_fused<<<dim3(MBE, 1), 256, 0, stream>>>(P, 512, epC2, epC2);
        }

        gemm_k<384, 2, 0, true, SrcUpd><<<MB50 * 2, 256, 0, stream>>>(
            SrcUpd{nodes, fi, fo, degS}, Wf1f, bf1, EpiArgs{nullptr, U1, nullptr, 256}, NN);
        upd23<<<MB50, 256, 0, stream>>>(U1, Wf2f, bf2, Wf3f, bf3, nodes, nodesbf, NN);
    }

    // ---- output head + global max pool -------------------------------------
    expand_k<128, 4, 0, true, 512><<<dim3(MB50, 4), 256, 0, stream>>>(
        nodesbf, Wo1f, bo1, nullptr, Hout1, nullptr, NN);
    gemm_k<512, 8, 3, true, SrcBf16><<<MB50 * 8, 256, 0, stream>>>(
        SrcBf16{Hout1, 512}, Wo2f, bo2, EpiArgs{out, nullptr, batch_vec, 1024}, NN);
}